// Round 3
// baseline (641.637 us; speedup 1.0000x reference)
//
#include <hip/hip_runtime.h>

// ---------------------------------------------------------------------------
// GCN with edge sampling, fp32.
//   build CSR by dst (hist -> scan -> fill packed int2(src,eid))
//   h0 = x@w0 computed ONCE, reused by both passes
//   pass1: agg(h0,coefF) relu -> gemm w1 -> agg relu -> gemm w2 -> agg64 -> tz
//   mask = sigmoid(tz[src].tz[dst]) > er ; degm
//   pass2: agg(h0,coefM) relu -> gemm w1 -> agg relu -> gemm w2 -> agg64(full) -> out
// conv: out[v] = dinv[v]*(sum_e h[src]*coef[e] + h[v]*dinv[v]) + b
// ---------------------------------------------------------------------------

__global__ void k_hist(const int* __restrict__ dst, int* __restrict__ indeg, int E) {
    int e = blockIdx.x * blockDim.x + threadIdx.x;
    if (e < E) atomicAdd(&indeg[dst[e]], 1);
}

__global__ void k_scan1(const int* __restrict__ in, int* __restrict__ out,
                        int* __restrict__ bsums, int N) {
    __shared__ int tmp[256];
    int i = blockIdx.x * 256 + threadIdx.x;
    int v = (i < N) ? in[i] : 0;
    tmp[threadIdx.x] = v;
    __syncthreads();
    for (int off = 1; off < 256; off <<= 1) {
        int t = (threadIdx.x >= off) ? tmp[threadIdx.x - off] : 0;
        __syncthreads();
        tmp[threadIdx.x] += t;
        __syncthreads();
    }
    if (i < N) out[i] = tmp[threadIdx.x] - v;   // exclusive
    if (threadIdx.x == 255) bsums[blockIdx.x] = tmp[255];
}

__global__ void k_scan2(int* __restrict__ bsums, int nb) {
    __shared__ int tmp[256];
    int v = (threadIdx.x < nb) ? bsums[threadIdx.x] : 0;
    tmp[threadIdx.x] = v;
    __syncthreads();
    for (int off = 1; off < 256; off <<= 1) {
        int t = (threadIdx.x >= off) ? tmp[threadIdx.x - off] : 0;
        __syncthreads();
        tmp[threadIdx.x] += t;
        __syncthreads();
    }
    if (threadIdx.x < nb) bsums[threadIdx.x] = tmp[threadIdx.x] - v;  // exclusive
}

__global__ void k_scan3(int* __restrict__ out, const int* __restrict__ bsums, int N, int E) {
    int i = blockIdx.x * 256 + threadIdx.x;
    if (i < N) out[i] += bsums[blockIdx.x];
    if (i == 0) out[N] = E;
}

__global__ void k_fill(const int* __restrict__ src, const int* __restrict__ dst,
                       const int* __restrict__ csr_off, int* __restrict__ cursor,
                       int2* __restrict__ csr_se, int E) {
    int e = blockIdx.x * blockDim.x + threadIdx.x;
    if (e < E) {
        int d = dst[e];
        int pos = csr_off[d] + atomicAdd(&cursor[d], 1);
        csr_se[pos] = make_int2(src[e], e);
    }
}

__global__ void k_dinv(const int* __restrict__ deg, float* __restrict__ dinv, int N) {
    int i = blockIdx.x * blockDim.x + threadIdx.x;
    if (i < N) dinv[i] = 1.0f / sqrtf((float)deg[i] + 1.0f);
}

__global__ void k_coef_full(const int2* __restrict__ csr_se, const float* __restrict__ dinv,
                            float* __restrict__ coef, int E) {
    int i = blockIdx.x * blockDim.x + threadIdx.x;
    if (i < E) coef[i] = dinv[csr_se[i].x];
}

__global__ void k_coef_mask(const int2* __restrict__ csr_se, const float* __restrict__ dinv,
                            const float* __restrict__ mask, float* __restrict__ coef, int E) {
    int i = blockIdx.x * blockDim.x + threadIdx.x;
    if (i < E) {
        int2 se = csr_se[i];
        coef[i] = dinv[se.x] * mask[se.y];
    }
}

// edge dot-product over 64 features, 16 lanes per edge
__global__ __launch_bounds__(256) void k_mask(const float* __restrict__ tz,
                                              const int* __restrict__ src,
                                              const int* __restrict__ dstv,
                                              const float* __restrict__ er,
                                              float* __restrict__ mask,
                                              int* __restrict__ degm, int E) {
    int gid = blockIdx.x * 256 + threadIdx.x;
    int e = gid >> 4;
    int l = gid & 15;
    if (e >= E) return;
    int s = src[e], d = dstv[e];
    const float4 a = *(const float4*)&tz[(size_t)s * 64 + l * 4];
    const float4 b = *(const float4*)&tz[(size_t)d * 64 + l * 4];
    float p = a.x * b.x + a.y * b.y + a.z * b.z + a.w * b.w;
    p += __shfl_xor(p, 1, 16);
    p += __shfl_xor(p, 2, 16);
    p += __shfl_xor(p, 4, 16);
    p += __shfl_xor(p, 8, 16);
    if (l == 0) {
        float sg = 1.0f / (1.0f + expf(-p));
        float m = (sg > er[e]) ? 1.0f : 0.0f;
        mask[e] = m;
        if (m != 0.0f) atomicAdd(&degm[d], 1);
    }
}

// C[N][OUTC] = A[N][128] x W[128][OUTC], fp32.
// W fully in LDS (loaded once); A streamed global->reg (16-lane broadcast
// dedup keeps A traffic exact); 64-row blocks, thread = 4 rows x (OUTC/16) cols.
template <int OUTC>
__global__ __launch_bounds__(256) void k_gemm2(const float* __restrict__ A,
                                               const float* __restrict__ W,
                                               float* __restrict__ Cout, int N) {
    constexpr int TC = OUTC / 16;  // 8 (OUTC=128) or 4 (OUTC=64)
    __shared__ float Ws[128 * OUTC];
    const int tid = threadIdx.x;
    for (int idx = tid; idx < 128 * OUTC / 4; idx += 256) {
        *(float4*)&Ws[idx * 4] = *(const float4*)&W[idx * 4];
    }
    __syncthreads();

    const int tc = tid & 15;   // col group
    const int tr = tid >> 4;   // row group of 4 (0..15)
    const int r0 = blockIdx.x * 64;
    int gr[4];
#pragma unroll
    for (int i = 0; i < 4; i++) {
        int r = r0 + tr * 4 + i;
        gr[i] = (r < N) ? r : (N - 1);
    }
    float acc[4][TC];
#pragma unroll
    for (int i = 0; i < 4; i++)
#pragma unroll
        for (int j = 0; j < TC; j++) acc[i][j] = 0.0f;

    for (int k0 = 0; k0 < 128; k0 += 4) {
        float4 av[4];
#pragma unroll
        for (int i = 0; i < 4; i++) av[i] = *(const float4*)&A[(size_t)gr[i] * 128 + k0];
#pragma unroll
        for (int kk = 0; kk < 4; kk++) {
            float b[TC];
#pragma unroll
            for (int j = 0; j < TC; j += 4) {
                float4 bv = *(const float4*)&Ws[(k0 + kk) * OUTC + tc * TC + j];
                b[j] = bv.x; b[j + 1] = bv.y; b[j + 2] = bv.z; b[j + 3] = bv.w;
            }
#pragma unroll
            for (int i = 0; i < 4; i++) {
                float a = (kk == 0) ? av[i].x : (kk == 1) ? av[i].y
                        : (kk == 2) ? av[i].z : av[i].w;
#pragma unroll
                for (int j = 0; j < TC; j++) acc[i][j] = fmaf(a, b[j], acc[i][j]);
            }
        }
    }
#pragma unroll
    for (int i = 0; i < 4; i++) {
        int r = r0 + tr * 4 + i;
        if (r < N) {
#pragma unroll
            for (int j = 0; j < TC; j += 4) {
                *(float4*)&Cout[(size_t)r * OUTC + tc * TC + j] =
                    make_float4(acc[i][j], acc[i][j + 1], acc[i][j + 2], acc[i][j + 3]);
            }
        }
    }
}

// C=128 aggregation: block=128 thr; 32 lanes (float4) x 4 edge slots, unroll 4
template <bool RELU>
__global__ __launch_bounds__(128) void k_agg128(const float* __restrict__ h,
                                                const int* __restrict__ csr_off,
                                                const int2* __restrict__ csr_se,
                                                const float* __restrict__ coef,
                                                const float* __restrict__ dinv,
                                                const float* __restrict__ bias,
                                                float* __restrict__ out, int N) {
    const int v = blockIdx.x;
    const int l = threadIdx.x & 31;
    const int s = threadIdx.x >> 5;  // 0..3
    const int e0 = csr_off[v];
    const int e1 = csr_off[v + 1];
    float4 acc = make_float4(0.f, 0.f, 0.f, 0.f);
    int i = e0 + s;
    for (; i + 12 < e1; i += 16) {
        int s0 = csr_se[i].x;      float w0 = coef[i];
        int s1 = csr_se[i + 4].x;  float w1 = coef[i + 4];
        int s2 = csr_se[i + 8].x;  float w2 = coef[i + 8];
        int s3 = csr_se[i + 12].x; float w3 = coef[i + 12];
        float4 a = *(const float4*)&h[(size_t)s0 * 128 + l * 4];
        float4 b = *(const float4*)&h[(size_t)s1 * 128 + l * 4];
        float4 c = *(const float4*)&h[(size_t)s2 * 128 + l * 4];
        float4 d = *(const float4*)&h[(size_t)s3 * 128 + l * 4];
        acc.x = fmaf(a.x, w0, acc.x); acc.y = fmaf(a.y, w0, acc.y);
        acc.z = fmaf(a.z, w0, acc.z); acc.w = fmaf(a.w, w0, acc.w);
        acc.x = fmaf(b.x, w1, acc.x); acc.y = fmaf(b.y, w1, acc.y);
        acc.z = fmaf(b.z, w1, acc.z); acc.w = fmaf(b.w, w1, acc.w);
        acc.x = fmaf(c.x, w2, acc.x); acc.y = fmaf(c.y, w2, acc.y);
        acc.z = fmaf(c.z, w2, acc.z); acc.w = fmaf(c.w, w2, acc.w);
        acc.x = fmaf(d.x, w3, acc.x); acc.y = fmaf(d.y, w3, acc.y);
        acc.z = fmaf(d.z, w3, acc.z); acc.w = fmaf(d.w, w3, acc.w);
    }
    for (; i < e1; i += 4) {
        int sa = csr_se[i].x;
        float wa = coef[i];
        float4 a = *(const float4*)&h[(size_t)sa * 128 + l * 4];
        acc.x = fmaf(a.x, wa, acc.x); acc.y = fmaf(a.y, wa, acc.y);
        acc.z = fmaf(a.z, wa, acc.z); acc.w = fmaf(a.w, wa, acc.w);
    }
    __shared__ float4 red[4][32];
    red[s][l] = acc;
    __syncthreads();
    if (threadIdx.x < 32) {
        float4 r0 = red[0][l], r1 = red[1][l], r2 = red[2][l], r3 = red[3][l];
        float dv = dinv[v];
        float4 hv = *(const float4*)&h[(size_t)v * 128 + l * 4];
        float4 bb = *(const float4*)&bias[l * 4];
        float4 o;
        o.x = dv * ((r0.x + r1.x + r2.x + r3.x) + hv.x * dv) + bb.x;
        o.y = dv * ((r0.y + r1.y + r2.y + r3.y) + hv.y * dv) + bb.y;
        o.z = dv * ((r0.z + r1.z + r2.z + r3.z) + hv.z * dv) + bb.z;
        o.w = dv * ((r0.w + r1.w + r2.w + r3.w) + hv.w * dv) + bb.w;
        if (RELU) {
            o.x = fmaxf(o.x, 0.f); o.y = fmaxf(o.y, 0.f);
            o.z = fmaxf(o.z, 0.f); o.w = fmaxf(o.w, 0.f);
        }
        *(float4*)&out[(size_t)v * 128 + l * 4] = o;
    }
}

// C=64 aggregation: block=128 thr; 16 lanes (float4) x 8 edge slots, unroll 2
__global__ __launch_bounds__(128) void k_agg64(const float* __restrict__ h,
                                               const int* __restrict__ csr_off,
                                               const int2* __restrict__ csr_se,
                                               const float* __restrict__ coef,
                                               const float* __restrict__ dinv,
                                               const float* __restrict__ bias,
                                               float* __restrict__ out, int N) {
    const int v = blockIdx.x;
    const int l = threadIdx.x & 15;
    const int s = threadIdx.x >> 4;  // 0..7
    const int e0 = csr_off[v];
    const int e1 = csr_off[v + 1];
    float4 acc = make_float4(0.f, 0.f, 0.f, 0.f);
    int i = e0 + s;
    for (; i + 8 < e1; i += 16) {
        int sa = csr_se[i].x;
        float wa = coef[i];
        int sb = csr_se[i + 8].x;
        float wb = coef[i + 8];
        float4 a = *(const float4*)&h[(size_t)sa * 64 + l * 4];
        float4 b = *(const float4*)&h[(size_t)sb * 64 + l * 4];
        acc.x = fmaf(a.x, wa, acc.x); acc.y = fmaf(a.y, wa, acc.y);
        acc.z = fmaf(a.z, wa, acc.z); acc.w = fmaf(a.w, wa, acc.w);
        acc.x = fmaf(b.x, wb, acc.x); acc.y = fmaf(b.y, wb, acc.y);
        acc.z = fmaf(b.z, wb, acc.z); acc.w = fmaf(b.w, wb, acc.w);
    }
    if (i < e1) {
        int sa = csr_se[i].x;
        float wa = coef[i];
        float4 a = *(const float4*)&h[(size_t)sa * 64 + l * 4];
        acc.x = fmaf(a.x, wa, acc.x); acc.y = fmaf(a.y, wa, acc.y);
        acc.z = fmaf(a.z, wa, acc.z); acc.w = fmaf(a.w, wa, acc.w);
    }
    __shared__ float4 red[8][16];
    red[s][l] = acc;
    __syncthreads();
    if (threadIdx.x < 16) {
        float4 aa = make_float4(0.f, 0.f, 0.f, 0.f);
#pragma unroll
        for (int k = 0; k < 8; ++k) {
            float4 r = red[k][l];
            aa.x += r.x; aa.y += r.y; aa.z += r.z; aa.w += r.w;
        }
        float dv = dinv[v];
        float4 hv = *(const float4*)&h[(size_t)v * 64 + l * 4];
        float4 bb = *(const float4*)&bias[l * 4];
        float4 o;
        o.x = dv * (aa.x + hv.x * dv) + bb.x;
        o.y = dv * (aa.y + hv.y * dv) + bb.y;
        o.z = dv * (aa.z + hv.z * dv) + bb.z;
        o.w = dv * (aa.w + hv.w * dv) + bb.w;
        *(float4*)&out[(size_t)v * 64 + l * 4] = o;
    }
}

extern "C" void kernel_launch(void* const* d_in, const int* in_sizes, int n_in,
                              void* d_out, int out_size, void* d_ws, size_t ws_size,
                              hipStream_t stream) {
    const float* x  = (const float*)d_in[0];
    const int*   ei = (const int*)d_in[1];
    const float* er = (const float*)d_in[2];
    const float* w0 = (const float*)d_in[3];
    const float* b0 = (const float*)d_in[4];
    const float* w1 = (const float*)d_in[5];
    const float* b1 = (const float*)d_in[6];
    const float* w2 = (const float*)d_in[7];
    const float* b2 = (const float*)d_in[8];
    const int N = in_sizes[0] / 128;
    const int E = in_sizes[2];
    const int* src  = ei;
    const int* dstv = ei + E;
    float* out = (float*)d_out;

    // workspace carve
    char* p = (char*)d_ws;
    auto alloc = [&](size_t bytes) {
        char* r = p;
        p += (bytes + 255) & ~(size_t)255;
        return r;
    };
    int* indeg     = (int*)alloc((size_t)N * 4);
    int* cursor    = (int*)alloc((size_t)N * 4);
    int* degm      = (int*)alloc((size_t)N * 4);
    int* csr_off   = (int*)alloc((size_t)(N + 1) * 4);
    int* bsums     = (int*)alloc(1024);
    int2* csr_se   = (int2*)alloc((size_t)E * 8);
    float* coefF   = (float*)alloc((size_t)E * 4);
    float* coefM   = (float*)alloc((size_t)E * 4);
    float* maskA   = (float*)alloc((size_t)E * 4);
    float* dinvF   = (float*)alloc((size_t)N * 4);
    float* dinvM   = (float*)alloc((size_t)N * 4);
    float* hx      = (float*)alloc((size_t)N * 128 * 4);  // x@w0, reused
    float* wk1     = (float*)alloc((size_t)N * 128 * 4);
    float* wk2     = (float*)alloc((size_t)N * 128 * 4);
    float* tz      = (float*)alloc((size_t)N * 64 * 4);

    hipMemsetAsync(indeg, 0, (size_t)N * 4, stream);
    hipMemsetAsync(cursor, 0, (size_t)N * 4, stream);
    hipMemsetAsync(degm, 0, (size_t)N * 4, stream);

    const int TB = 256;
    const int ebk = (E + TB - 1) / TB;
    const int nbk = (N + TB - 1) / TB;
    const int nb = (N + 255) / 256;

    // CSR build
    k_hist<<<ebk, TB, 0, stream>>>(dstv, indeg, E);
    k_scan1<<<nb, 256, 0, stream>>>(indeg, csr_off, bsums, N);
    k_scan2<<<1, 256, 0, stream>>>(bsums, nb);
    k_scan3<<<nb, 256, 0, stream>>>(csr_off, bsums, N, E);
    k_fill<<<ebk, TB, 0, stream>>>(src, dstv, csr_off, cursor, csr_se, E);
    k_dinv<<<nbk, TB, 0, stream>>>(indeg, dinvF, N);
    k_coef_full<<<ebk, TB, 0, stream>>>(csr_se, dinvF, coefF, E);

    const int gb2 = (N + 63) / 64;

    // shared first GEMM
    k_gemm2<128><<<gb2, 256, 0, stream>>>(x, w0, hx, N);

    // pass 1 (full graph)
    k_agg128<true><<<N, 128, 0, stream>>>(hx, csr_off, csr_se, coefF, dinvF, b0, wk1, N);
    k_gemm2<128><<<gb2, 256, 0, stream>>>(wk1, w1, wk2, N);
    k_agg128<true><<<N, 128, 0, stream>>>(wk2, csr_off, csr_se, coefF, dinvF, b1, wk1, N);
    k_gemm2<64><<<gb2, 256, 0, stream>>>(wk1, w2, wk2, N);
    k_agg64<<<N, 128, 0, stream>>>(wk2, csr_off, csr_se, coefF, dinvF, b2, tz, N);

    // edge sampling
    k_mask<<<(int)(((size_t)E * 16 + 255) / 256), 256, 0, stream>>>(tz, src, dstv, er, maskA, degm, E);
    k_dinv<<<nbk, TB, 0, stream>>>(degm, dinvM, N);
    k_coef_mask<<<ebk, TB, 0, stream>>>(csr_se, dinvM, maskA, coefM, E);

    // pass 2 (sampled for layers 0/1, full for layer 2)
    k_agg128<true><<<N, 128, 0, stream>>>(hx, csr_off, csr_se, coefM, dinvM, b0, wk1, N);
    k_gemm2<128><<<gb2, 256, 0, stream>>>(wk1, w1, wk2, N);
    k_agg128<true><<<N, 128, 0, stream>>>(wk2, csr_off, csr_se, coefM, dinvM, b1, wk1, N);
    k_gemm2<64><<<gb2, 256, 0, stream>>>(wk1, w2, wk2, N);
    k_agg64<<<N, 128, 0, stream>>>(wk2, csr_off, csr_se, coefF, dinvF, b2, out, N);
}

// Round 4
// 572.119 us; speedup vs baseline: 1.1215x; 1.1215x over previous
//
#include <hip/hip_runtime.h>

// ---------------------------------------------------------------------------
// GCN with edge sampling. Pass 1 (produces tz -> mask) is exact fp32 so the
// sampling mask is bit-stable. Pass 2 (post-mask) gathers bf16 feature rows
// (half the L2-miss traffic of the BW-bound aggregation), f32 accumulate.
// conv: out[v] = dinv[v]*(sum_e h[src]*coef[e] + h[v]*dinv[v]) + b
// ---------------------------------------------------------------------------

__device__ inline unsigned bfpair(float lo, float hi) {   // pack 2 f32 -> bf16x2 RNE
    unsigned a = __float_as_uint(lo), b = __float_as_uint(hi);
    a = (a + 0x7FFFu + ((a >> 16) & 1u)) >> 16;
    b = (b + 0x7FFFu + ((b >> 16) & 1u)) & 0xFFFF0000u;
    return a | b;
}
__device__ inline void unpack2(unsigned u, float& f0, float& f1) {
    f0 = __uint_as_float(u << 16);
    f1 = __uint_as_float(u & 0xFFFF0000u);
}

__global__ void k_hist(const int* __restrict__ dst, int* __restrict__ indeg, int E) {
    int e = blockIdx.x * blockDim.x + threadIdx.x;
    if (e < E) atomicAdd(&indeg[dst[e]], 1);
}

__global__ void k_scan1(const int* __restrict__ in, int* __restrict__ out,
                        int* __restrict__ bsums, int N) {
    __shared__ int tmp[256];
    int i = blockIdx.x * 256 + threadIdx.x;
    int v = (i < N) ? in[i] : 0;
    tmp[threadIdx.x] = v;
    __syncthreads();
    for (int off = 1; off < 256; off <<= 1) {
        int t = (threadIdx.x >= off) ? tmp[threadIdx.x - off] : 0;
        __syncthreads();
        tmp[threadIdx.x] += t;
        __syncthreads();
    }
    if (i < N) out[i] = tmp[threadIdx.x] - v;   // exclusive
    if (threadIdx.x == 255) bsums[blockIdx.x] = tmp[255];
}

__global__ void k_scan2(int* __restrict__ bsums, int nb) {
    __shared__ int tmp[256];
    int v = (threadIdx.x < nb) ? bsums[threadIdx.x] : 0;
    tmp[threadIdx.x] = v;
    __syncthreads();
    for (int off = 1; off < 256; off <<= 1) {
        int t = (threadIdx.x >= off) ? tmp[threadIdx.x - off] : 0;
        __syncthreads();
        tmp[threadIdx.x] += t;
        __syncthreads();
    }
    if (threadIdx.x < nb) bsums[threadIdx.x] = tmp[threadIdx.x] - v;  // exclusive
}

__global__ void k_scan3(int* __restrict__ out, const int* __restrict__ bsums, int N, int E) {
    int i = blockIdx.x * 256 + threadIdx.x;
    if (i < N) out[i] += bsums[blockIdx.x];
    if (i == 0) out[N] = E;
}

__global__ void k_fill(const int* __restrict__ src, const int* __restrict__ dst,
                       const int* __restrict__ csr_off, int* __restrict__ cursor,
                       int2* __restrict__ csr_se, int E) {
    int e = blockIdx.x * blockDim.x + threadIdx.x;
    if (e < E) {
        int d = dst[e];
        int pos = csr_off[d] + atomicAdd(&cursor[d], 1);
        csr_se[pos] = make_int2(src[e], e);
    }
}

__global__ void k_dinv(const int* __restrict__ deg, float* __restrict__ dinv, int N) {
    int i = blockIdx.x * blockDim.x + threadIdx.x;
    if (i < N) dinv[i] = 1.0f / sqrtf((float)deg[i] + 1.0f);
}

__global__ void k_coef_full(const int2* __restrict__ csr_se, const float* __restrict__ dinv,
                            float* __restrict__ coef, int E) {
    int i = blockIdx.x * blockDim.x + threadIdx.x;
    if (i < E) coef[i] = dinv[csr_se[i].x];
}

__global__ void k_coef_mask(const int2* __restrict__ csr_se, const float* __restrict__ dinv,
                            const float* __restrict__ mask, float* __restrict__ coef, int E) {
    int i = blockIdx.x * blockDim.x + threadIdx.x;
    if (i < E) {
        int2 se = csr_se[i];
        coef[i] = dinv[se.x] * mask[se.y];
    }
}

// edge dot-product over 64 features, 16 lanes per edge
__global__ __launch_bounds__(256) void k_mask(const float* __restrict__ tz,
                                              const int* __restrict__ src,
                                              const int* __restrict__ dstv,
                                              const float* __restrict__ er,
                                              float* __restrict__ mask,
                                              int* __restrict__ degm, int E) {
    int gid = blockIdx.x * 256 + threadIdx.x;
    int e = gid >> 4;
    int l = gid & 15;
    if (e >= E) return;
    int s = src[e], d = dstv[e];
    const float4 a = *(const float4*)&tz[(size_t)s * 64 + l * 4];
    const float4 b = *(const float4*)&tz[(size_t)d * 64 + l * 4];
    float p = a.x * b.x + a.y * b.y + a.z * b.z + a.w * b.w;
    p += __shfl_xor(p, 1, 16);
    p += __shfl_xor(p, 2, 16);
    p += __shfl_xor(p, 4, 16);
    p += __shfl_xor(p, 8, 16);
    if (l == 0) {
        float sg = 1.0f / (1.0f + expf(-p));
        float m = (sg > er[e]) ? 1.0f : 0.0f;
        mask[e] = m;
        if (m != 0.0f) atomicAdd(&degm[d], 1);
    }
}

// C[N][OUTC] = A[N][128] x W[128][OUTC], fp32, 128-row tiles (R2 version)
// optional f32 and/or bf16 outputs (f32 accumulate always)
template <int OUTC, bool WF32, bool WB16>
__global__ __launch_bounds__(256) void k_gemm(const float* __restrict__ A,
                                              const float* __restrict__ W,
                                              float* __restrict__ Cout,
                                              unsigned short* __restrict__ Cb, int N) {
    constexpr int TN = OUTC / 16;  // 8 or 4 cols per thread
    __shared__ float As[16][136];       // [k][row]
    __shared__ float Ws[16][OUTC + 8];  // [k][col]
    const int tid = threadIdx.x;
    const int tx = tid & 15;
    const int ty = tid >> 4;
    const int r0 = blockIdx.x * 128;

    float acc[8][TN];
#pragma unroll
    for (int i = 0; i < 8; i++)
#pragma unroll
        for (int j = 0; j < TN; j++) acc[i][j] = 0.0f;

    for (int k0 = 0; k0 < 128; k0 += 16) {
        __syncthreads();
#pragma unroll
        for (int l = 0; l < 2; ++l) {
            int idx = tid + l * 256;          // 0..511
            int row = idx >> 2;               // 0..127
            int c4 = idx & 3;                 // 0..3
            int gr = r0 + row;
            if (gr >= N) gr = N - 1;
            const float4 vv = *(const float4*)&A[(size_t)gr * 128 + k0 + c4 * 4];
            As[c4 * 4 + 0][row] = vv.x;
            As[c4 * 4 + 1][row] = vv.y;
            As[c4 * 4 + 2][row] = vv.z;
            As[c4 * 4 + 3][row] = vv.w;
        }
#pragma unroll
        for (int l = 0; l < (16 * OUTC / 4) / 256; ++l) {
            int idx = tid + l * 256;
            int row = idx / (OUTC / 4);
            int c4 = idx % (OUTC / 4);
            const float4 vv = *(const float4*)&W[(k0 + row) * OUTC + c4 * 4];
            *(float4*)&Ws[row][c4 * 4] = vv;
        }
        __syncthreads();
#pragma unroll
        for (int kk = 0; kk < 16; ++kk) {
            float a[8], b[TN];
#pragma unroll
            for (int i = 0; i < 8; i++) a[i] = As[kk][ty * 8 + i];
#pragma unroll
            for (int j = 0; j < TN; j++) b[j] = Ws[kk][tx * TN + j];
#pragma unroll
            for (int i = 0; i < 8; i++)
#pragma unroll
                for (int j = 0; j < TN; j++) acc[i][j] = fmaf(a[i], b[j], acc[i][j]);
        }
    }
#pragma unroll
    for (int i = 0; i < 8; i++) {
        int r = r0 + ty * 8 + i;
        if (r < N) {
            if (WF32) {
#pragma unroll
                for (int j = 0; j < TN; j += 4) {
                    *(float4*)&Cout[(size_t)r * OUTC + tx * TN + j] =
                        make_float4(acc[i][j], acc[i][j + 1], acc[i][j + 2], acc[i][j + 3]);
                }
            }
            if (WB16) {
                unsigned u[TN / 2];
#pragma unroll
                for (int j = 0; j < TN / 2; j++) u[j] = bfpair(acc[i][2 * j], acc[i][2 * j + 1]);
                if (TN == 8)
                    *(uint4*)&Cb[(size_t)r * OUTC + tx * TN] = make_uint4(u[0], u[1], u[2], u[3]);
                else
                    *(uint2*)&Cb[(size_t)r * OUTC + tx * TN] = make_uint2(u[0], u[1]);
            }
        }
    }
}

// ---------------- fp32 aggregations (pass 1, mask-critical) ----------------
template <bool RELU>
__global__ __launch_bounds__(128) void k_agg128(const float* __restrict__ h,
                                                const int* __restrict__ csr_off,
                                                const int2* __restrict__ csr_se,
                                                const float* __restrict__ coef,
                                                const float* __restrict__ dinv,
                                                const float* __restrict__ bias,
                                                float* __restrict__ out, int N) {
    const int v = blockIdx.x;
    const int l = threadIdx.x & 31;
    const int s = threadIdx.x >> 5;  // 0..3
    const int e0 = csr_off[v];
    const int e1 = csr_off[v + 1];
    float4 acc = make_float4(0.f, 0.f, 0.f, 0.f);
    int i = e0 + s;
    for (; i + 4 < e1; i += 8) {
        int sa = csr_se[i].x;      float wa = coef[i];
        int sb = csr_se[i + 4].x;  float wb = coef[i + 4];
        float4 a = *(const float4*)&h[(size_t)sa * 128 + l * 4];
        float4 b = *(const float4*)&h[(size_t)sb * 128 + l * 4];
        acc.x = fmaf(a.x, wa, acc.x); acc.y = fmaf(a.y, wa, acc.y);
        acc.z = fmaf(a.z, wa, acc.z); acc.w = fmaf(a.w, wa, acc.w);
        acc.x = fmaf(b.x, wb, acc.x); acc.y = fmaf(b.y, wb, acc.y);
        acc.z = fmaf(b.z, wb, acc.z); acc.w = fmaf(b.w, wb, acc.w);
    }
    if (i < e1) {
        int sa = csr_se[i].x;
        float wa = coef[i];
        float4 a = *(const float4*)&h[(size_t)sa * 128 + l * 4];
        acc.x = fmaf(a.x, wa, acc.x); acc.y = fmaf(a.y, wa, acc.y);
        acc.z = fmaf(a.z, wa, acc.z); acc.w = fmaf(a.w, wa, acc.w);
    }
    __shared__ float4 red[4][32];
    red[s][l] = acc;
    __syncthreads();
    if (threadIdx.x < 32) {
        float4 r0 = red[0][l], r1 = red[1][l], r2 = red[2][l], r3 = red[3][l];
        float dv = dinv[v];
        float4 hv = *(const float4*)&h[(size_t)v * 128 + l * 4];
        float4 bb = *(const float4*)&bias[l * 4];
        float4 o;
        o.x = dv * ((r0.x + r1.x + r2.x + r3.x) + hv.x * dv) + bb.x;
        o.y = dv * ((r0.y + r1.y + r2.y + r3.y) + hv.y * dv) + bb.y;
        o.z = dv * ((r0.z + r1.z + r2.z + r3.z) + hv.z * dv) + bb.z;
        o.w = dv * ((r0.w + r1.w + r2.w + r3.w) + hv.w * dv) + bb.w;
        if (RELU) {
            o.x = fmaxf(o.x, 0.f); o.y = fmaxf(o.y, 0.f);
            o.z = fmaxf(o.z, 0.f); o.w = fmaxf(o.w, 0.f);
        }
        *(float4*)&out[(size_t)v * 128 + l * 4] = o;
    }
}

__global__ __launch_bounds__(128) void k_agg64(const float* __restrict__ h,
                                               const int* __restrict__ csr_off,
                                               const int2* __restrict__ csr_se,
                                               const float* __restrict__ coef,
                                               const float* __restrict__ dinv,
                                               const float* __restrict__ bias,
                                               float* __restrict__ out, int N) {
    const int v = blockIdx.x;
    const int l = threadIdx.x & 15;
    const int s = threadIdx.x >> 4;  // 0..7
    const int e0 = csr_off[v];
    const int e1 = csr_off[v + 1];
    float4 acc = make_float4(0.f, 0.f, 0.f, 0.f);
    int i = e0 + s;
    for (; i + 8 < e1; i += 16) {
        int sa = csr_se[i].x;      float wa = coef[i];
        int sb = csr_se[i + 8].x;  float wb = coef[i + 8];
        float4 a = *(const float4*)&h[(size_t)sa * 64 + l * 4];
        float4 b = *(const float4*)&h[(size_t)sb * 64 + l * 4];
        acc.x = fmaf(a.x, wa, acc.x); acc.y = fmaf(a.y, wa, acc.y);
        acc.z = fmaf(a.z, wa, acc.z); acc.w = fmaf(a.w, wa, acc.w);
        acc.x = fmaf(b.x, wb, acc.x); acc.y = fmaf(b.y, wb, acc.y);
        acc.z = fmaf(b.z, wb, acc.z); acc.w = fmaf(b.w, wb, acc.w);
    }
    if (i < e1) {
        int sa = csr_se[i].x;
        float wa = coef[i];
        float4 a = *(const float4*)&h[(size_t)sa * 64 + l * 4];
        acc.x = fmaf(a.x, wa, acc.x); acc.y = fmaf(a.y, wa, acc.y);
        acc.z = fmaf(a.z, wa, acc.z); acc.w = fmaf(a.w, wa, acc.w);
    }
    __shared__ float4 red[8][16];
    red[s][l] = acc;
    __syncthreads();
    if (threadIdx.x < 16) {
        float4 aa = make_float4(0.f, 0.f, 0.f, 0.f);
#pragma unroll
        for (int k = 0; k < 8; ++k) {
            float4 r = red[k][l];
            aa.x += r.x; aa.y += r.y; aa.z += r.z; aa.w += r.w;
        }
        float dv = dinv[v];
        float4 hv = *(const float4*)&h[(size_t)v * 64 + l * 4];
        float4 bb = *(const float4*)&bias[l * 4];
        float4 o;
        o.x = dv * (aa.x + hv.x * dv) + bb.x;
        o.y = dv * (aa.y + hv.y * dv) + bb.y;
        o.z = dv * (aa.z + hv.z * dv) + bb.z;
        o.w = dv * (aa.w + hv.w * dv) + bb.w;
        *(float4*)&out[(size_t)v * 64 + l * 4] = o;
    }
}

// ---------------- bf16-gather aggregations (pass 2, post-mask) -------------
// rows stored bf16: 128 feats = 256B. 16 lanes x 8 feats, 8 edge slots.
template <bool RELU>
__global__ __launch_bounds__(128) void k_agg128b(const unsigned short* __restrict__ h,
                                                 const int* __restrict__ csr_off,
                                                 const int2* __restrict__ csr_se,
                                                 const float* __restrict__ coef,
                                                 const float* __restrict__ dinv,
                                                 const float* __restrict__ bias,
                                                 float* __restrict__ out, int N) {
    const int v = blockIdx.x;
    const int l = threadIdx.x & 15;  // 8-feature group
    const int s = threadIdx.x >> 4;  // 0..7 edge slot
    const int e0 = csr_off[v];
    const int e1 = csr_off[v + 1];
    float acc[8];
#pragma unroll
    for (int j = 0; j < 8; j++) acc[j] = 0.f;
    int i = e0 + s;
    for (; i + 8 < e1; i += 16) {
        int sa = csr_se[i].x;      float wa = coef[i];
        int sb = csr_se[i + 8].x;  float wb = coef[i + 8];
        uint4 ua = *(const uint4*)&h[(size_t)sa * 128 + l * 8];
        uint4 ub = *(const uint4*)&h[(size_t)sb * 128 + l * 8];
        float f0, f1;
        unpack2(ua.x, f0, f1); acc[0] = fmaf(f0, wa, acc[0]); acc[1] = fmaf(f1, wa, acc[1]);
        unpack2(ua.y, f0, f1); acc[2] = fmaf(f0, wa, acc[2]); acc[3] = fmaf(f1, wa, acc[3]);
        unpack2(ua.z, f0, f1); acc[4] = fmaf(f0, wa, acc[4]); acc[5] = fmaf(f1, wa, acc[5]);
        unpack2(ua.w, f0, f1); acc[6] = fmaf(f0, wa, acc[6]); acc[7] = fmaf(f1, wa, acc[7]);
        unpack2(ub.x, f0, f1); acc[0] = fmaf(f0, wb, acc[0]); acc[1] = fmaf(f1, wb, acc[1]);
        unpack2(ub.y, f0, f1); acc[2] = fmaf(f0, wb, acc[2]); acc[3] = fmaf(f1, wb, acc[3]);
        unpack2(ub.z, f0, f1); acc[4] = fmaf(f0, wb, acc[4]); acc[5] = fmaf(f1, wb, acc[5]);
        unpack2(ub.w, f0, f1); acc[6] = fmaf(f0, wb, acc[6]); acc[7] = fmaf(f1, wb, acc[7]);
    }
    if (i < e1) {
        int sa = csr_se[i].x;
        float wa = coef[i];
        uint4 ua = *(const uint4*)&h[(size_t)sa * 128 + l * 8];
        float f0, f1;
        unpack2(ua.x, f0, f1); acc[0] = fmaf(f0, wa, acc[0]); acc[1] = fmaf(f1, wa, acc[1]);
        unpack2(ua.y, f0, f1); acc[2] = fmaf(f0, wa, acc[2]); acc[3] = fmaf(f1, wa, acc[3]);
        unpack2(ua.z, f0, f1); acc[4] = fmaf(f0, wa, acc[4]); acc[5] = fmaf(f1, wa, acc[5]);
        unpack2(ua.w, f0, f1); acc[6] = fmaf(f0, wa, acc[6]); acc[7] = fmaf(f1, wa, acc[7]);
    }
    __shared__ float red[8][16][8];
#pragma unroll
    for (int j = 0; j < 8; j += 4)
        *(float4*)&red[s][l][j] = make_float4(acc[j], acc[j + 1], acc[j + 2], acc[j + 3]);
    __syncthreads();
    if (threadIdx.x < 16) {
        int ll = threadIdx.x;
        float rr[8];
#pragma unroll
        for (int j = 0; j < 8; j++) rr[j] = 0.f;
#pragma unroll
        for (int k = 0; k < 8; ++k)
#pragma unroll
            for (int j = 0; j < 8; j++) rr[j] += red[k][ll][j];
        float dv = dinv[v];
        uint4 uh = *(const uint4*)&h[(size_t)v * 128 + ll * 8];
        float hv[8];
        unpack2(uh.x, hv[0], hv[1]); unpack2(uh.y, hv[2], hv[3]);
        unpack2(uh.z, hv[4], hv[5]); unpack2(uh.w, hv[6], hv[7]);
        float o[8];
#pragma unroll
        for (int j = 0; j < 8; j++) {
            o[j] = dv * (rr[j] + hv[j] * dv) + bias[ll * 8 + j];
            if (RELU) o[j] = fmaxf(o[j], 0.f);
        }
        *(float4*)&out[(size_t)v * 128 + ll * 8 + 0] = make_float4(o[0], o[1], o[2], o[3]);
        *(float4*)&out[(size_t)v * 128 + ll * 8 + 4] = make_float4(o[4], o[5], o[6], o[7]);
    }
}

// 64 feats bf16 = 128B. 8 lanes x 8 feats, 16 edge slots. out f32.
__global__ __launch_bounds__(128) void k_agg64b(const unsigned short* __restrict__ h,
                                                const int* __restrict__ csr_off,
                                                const int2* __restrict__ csr_se,
                                                const float* __restrict__ coef,
                                                const float* __restrict__ dinv,
                                                const float* __restrict__ bias,
                                                float* __restrict__ out, int N) {
    const int v = blockIdx.x;
    const int l = threadIdx.x & 7;   // 8-feature group
    const int s = threadIdx.x >> 3;  // 0..15 edge slot
    const int e0 = csr_off[v];
    const int e1 = csr_off[v + 1];
    float acc[8];
#pragma unroll
    for (int j = 0; j < 8; j++) acc[j] = 0.f;
    for (int i = e0 + s; i < e1; i += 16) {
        int sa = csr_se[i].x;
        float wa = coef[i];
        uint4 ua = *(const uint4*)&h[(size_t)sa * 64 + l * 8];
        float f0, f1;
        unpack2(ua.x, f0, f1); acc[0] = fmaf(f0, wa, acc[0]); acc[1] = fmaf(f1, wa, acc[1]);
        unpack2(ua.y, f0, f1); acc[2] = fmaf(f0, wa, acc[2]); acc[3] = fmaf(f1, wa, acc[3]);
        unpack2(ua.z, f0, f1); acc[4] = fmaf(f0, wa, acc[4]); acc[5] = fmaf(f1, wa, acc[5]);
        unpack2(ua.w, f0, f1); acc[6] = fmaf(f0, wa, acc[6]); acc[7] = fmaf(f1, wa, acc[7]);
    }
    __shared__ float red[16][8][8];
#pragma unroll
    for (int j = 0; j < 8; j += 4)
        *(float4*)&red[s][l][j] = make_float4(acc[j], acc[j + 1], acc[j + 2], acc[j + 3]);
    __syncthreads();
    if (threadIdx.x < 8) {
        int ll = threadIdx.x;
        float rr[8];
#pragma unroll
        for (int j = 0; j < 8; j++) rr[j] = 0.f;
#pragma unroll
        for (int k = 0; k < 16; ++k)
#pragma unroll
            for (int j = 0; j < 8; j++) rr[j] += red[k][ll][j];
        float dv = dinv[v];
        uint4 uh = *(const uint4*)&h[(size_t)v * 64 + ll * 8];
        float hv[8];
        unpack2(uh.x, hv[0], hv[1]); unpack2(uh.y, hv[2], hv[3]);
        unpack2(uh.z, hv[4], hv[5]); unpack2(uh.w, hv[6], hv[7]);
        float o[8];
#pragma unroll
        for (int j = 0; j < 8; j++) o[j] = dv * (rr[j] + hv[j] * dv) + bias[ll * 8 + j];
        *(float4*)&out[(size_t)v * 64 + ll * 8 + 0] = make_float4(o[0], o[1], o[2], o[3]);
        *(float4*)&out[(size_t)v * 64 + ll * 8 + 4] = make_float4(o[4], o[5], o[6], o[7]);
    }
}

extern "C" void kernel_launch(void* const* d_in, const int* in_sizes, int n_in,
                              void* d_out, int out_size, void* d_ws, size_t ws_size,
                              hipStream_t stream) {
    const float* x  = (const float*)d_in[0];
    const int*   ei = (const int*)d_in[1];
    const float* er = (const float*)d_in[2];
    const float* w0 = (const float*)d_in[3];
    const float* b0 = (const float*)d_in[4];
    const float* w1 = (const float*)d_in[5];
    const float* b1 = (const float*)d_in[6];
    const float* w2 = (const float*)d_in[7];
    const float* b2 = (const float*)d_in[8];
    const int N = in_sizes[0] / 128;
    const int E = in_sizes[2];
    const int* src  = ei;
    const int* dstv = ei + E;
    float* out = (float*)d_out;

    // workspace carve
    char* p = (char*)d_ws;
    auto alloc = [&](size_t bytes) {
        char* r = p;
        p += (bytes + 255) & ~(size_t)255;
        return r;
    };
    int* indeg     = (int*)alloc((size_t)N * 4);
    int* cursor    = (int*)alloc((size_t)N * 4);
    int* degm      = (int*)alloc((size_t)N * 4);
    int* csr_off   = (int*)alloc((size_t)(N + 1) * 4);
    int* bsums     = (int*)alloc(1024);
    int2* csr_se   = (int2*)alloc((size_t)E * 8);
    float* coefF   = (float*)alloc((size_t)E * 4);
    float* coefM   = (float*)alloc((size_t)E * 4);
    float* maskA   = (float*)alloc((size_t)E * 4);
    float* dinvF   = (float*)alloc((size_t)N * 4);
    float* dinvM   = (float*)alloc((size_t)N * 4);
    float* hx      = (float*)alloc((size_t)N * 128 * 4);  // x@w0 f32 (pass1)
    unsigned short* hxb = (unsigned short*)alloc((size_t)N * 128 * 2);  // x@w0 bf16 (pass2)
    float* wk1     = (float*)alloc((size_t)N * 128 * 4);
    float* wk2     = (float*)alloc((size_t)N * 128 * 4);
    float* tz      = (float*)alloc((size_t)N * 64 * 4);
    unsigned short* wk2b = (unsigned short*)wk2;  // alias: pass2 wk2 only used as bf16

    hipMemsetAsync(indeg, 0, (size_t)N * 4, stream);
    hipMemsetAsync(cursor, 0, (size_t)N * 4, stream);
    hipMemsetAsync(degm, 0, (size_t)N * 4, stream);

    const int TB = 256;
    const int ebk = (E + TB - 1) / TB;
    const int nbk = (N + TB - 1) / TB;
    const int nb = (N + 255) / 256;

    // CSR build
    k_hist<<<ebk, TB, 0, stream>>>(dstv, indeg, E);
    k_scan1<<<nb, 256, 0, stream>>>(indeg, csr_off, bsums, N);
    k_scan2<<<1, 256, 0, stream>>>(bsums, nb);
    k_scan3<<<nb, 256, 0, stream>>>(csr_off, bsums, N, E);
    k_fill<<<ebk, TB, 0, stream>>>(src, dstv, csr_off, cursor, csr_se, E);
    k_dinv<<<nbk, TB, 0, stream>>>(indeg, dinvF, N);
    k_coef_full<<<ebk, TB, 0, stream>>>(csr_se, dinvF, coefF, E);

    const int gb = (N + 127) / 128;

    // shared first GEMM: f32 for pass1, bf16 for pass2
    k_gemm<128, true, true><<<gb, 256, 0, stream>>>(x, w0, hx, hxb, N);

    // pass 1 (full graph, exact fp32 -> tz -> mask)
    k_agg128<true><<<N, 128, 0, stream>>>(hx, csr_off, csr_se, coefF, dinvF, b0, wk1, N);
    k_gemm<128, true, false><<<gb, 256, 0, stream>>>(wk1, w1, wk2, nullptr, N);
    k_agg128<true><<<N, 128, 0, stream>>>(wk2, csr_off, csr_se, coefF, dinvF, b1, wk1, N);
    k_gemm<64, true, false><<<gb, 256, 0, stream>>>(wk1, w2, wk2, nullptr, N);
    k_agg64<<<N, 128, 0, stream>>>(wk2, csr_off, csr_se, coefF, dinvF, b2, tz, N);

    // edge sampling
    k_mask<<<(int)(((size_t)E * 16 + 255) / 256), 256, 0, stream>>>(tz, src, dstv, er, maskA, degm, E);
    k_dinv<<<nbk, TB, 0, stream>>>(degm, dinvM, N);
    k_coef_mask<<<ebk, TB, 0, stream>>>(csr_se, dinvM, maskA, coefM, E);

    // pass 2 (post-mask: bf16 gathers, f32 accumulate)
    k_agg128b<true><<<N, 128, 0, stream>>>(hxb, csr_off, csr_se, coefM, dinvM, b0, wk1, N);
    k_gemm<128, false, true><<<gb, 256, 0, stream>>>(wk1, w1, nullptr, wk2b, N);
    k_agg128b<true><<<N, 128, 0, stream>>>(wk2b, csr_off, csr_se, coefM, dinvM, b1, wk1, N);
    k_gemm<64, false, true><<<gb, 256, 0, stream>>>(wk1, w2, nullptr, wk2b, N);
    k_agg64b<<<N, 128, 0, stream>>>(wk2b, csr_off, csr_se, coefF, dinvF, b2, out, N);
}

// Round 5
// 538.484 us; speedup vs baseline: 1.1916x; 1.0625x over previous
//
#include <hip/hip_runtime.h>

// ---------------------------------------------------------------------------
// GCN with edge sampling. Pass 1 (produces tz -> mask) is exact fp32 so the
// sampling mask is bit-stable. Pass 2 (post-mask) is bf16: bf16 gathers,
// bf16 MFMA GEMMs (f32 accumulate), bf16 intermediates.
// conv: out[v] = dinv[v]*(sum_e h[src]*coef[e] + h[v]*dinv[v]) + b
// ---------------------------------------------------------------------------

typedef __attribute__((ext_vector_type(8))) short bf16x8;
typedef __attribute__((ext_vector_type(4))) float f32x4;

__device__ inline unsigned bfpair(float lo, float hi) {   // pack 2 f32 -> bf16x2 RNE
    unsigned a = __float_as_uint(lo), b = __float_as_uint(hi);
    a = (a + 0x7FFFu + ((a >> 16) & 1u)) >> 16;
    b = (b + 0x7FFFu + ((b >> 16) & 1u)) & 0xFFFF0000u;
    return a | b;
}
__device__ inline unsigned short bf1(float v) {
    unsigned u = __float_as_uint(v);
    return (unsigned short)((u + 0x7FFFu + ((u >> 16) & 1u)) >> 16);
}
__device__ inline void unpack2(unsigned u, float& f0, float& f1) {
    f0 = __uint_as_float(u << 16);
    f1 = __uint_as_float(u & 0xFFFF0000u);
}

__global__ void k_hist(const int* __restrict__ dst, int* __restrict__ indeg, int E) {
    int e = blockIdx.x * blockDim.x + threadIdx.x;
    if (e < E) atomicAdd(&indeg[dst[e]], 1);
}

__global__ void k_scan1(const int* __restrict__ in, int* __restrict__ out,
                        int* __restrict__ bsums, int N) {
    __shared__ int tmp[256];
    int i = blockIdx.x * 256 + threadIdx.x;
    int v = (i < N) ? in[i] : 0;
    tmp[threadIdx.x] = v;
    __syncthreads();
    for (int off = 1; off < 256; off <<= 1) {
        int t = (threadIdx.x >= off) ? tmp[threadIdx.x - off] : 0;
        __syncthreads();
        tmp[threadIdx.x] += t;
        __syncthreads();
    }
    if (i < N) out[i] = tmp[threadIdx.x] - v;   // exclusive
    if (threadIdx.x == 255) bsums[blockIdx.x] = tmp[255];
}

__global__ void k_scan2(int* __restrict__ bsums, int nb) {
    __shared__ int tmp[256];
    int v = (threadIdx.x < nb) ? bsums[threadIdx.x] : 0;
    tmp[threadIdx.x] = v;
    __syncthreads();
    for (int off = 1; off < 256; off <<= 1) {
        int t = (threadIdx.x >= off) ? tmp[threadIdx.x - off] : 0;
        __syncthreads();
        tmp[threadIdx.x] += t;
        __syncthreads();
    }
    if (threadIdx.x < nb) bsums[threadIdx.x] = tmp[threadIdx.x] - v;  // exclusive
}

__global__ void k_scan3(int* __restrict__ out, const int* __restrict__ bsums, int N, int E) {
    int i = blockIdx.x * 256 + threadIdx.x;
    if (i < N) out[i] += bsums[blockIdx.x];
    if (i == 0) out[N] = E;
}

__global__ void k_fill(const int* __restrict__ src, const int* __restrict__ dst,
                       const int* __restrict__ csr_off, int* __restrict__ cursor,
                       int2* __restrict__ csr_se, int E) {
    int e = blockIdx.x * blockDim.x + threadIdx.x;
    if (e < E) {
        int d = dst[e];
        int pos = csr_off[d] + atomicAdd(&cursor[d], 1);
        csr_se[pos] = make_int2(src[e], e);
    }
}

__global__ void k_dinv(const int* __restrict__ deg, float* __restrict__ dinv, int N) {
    int i = blockIdx.x * blockDim.x + threadIdx.x;
    if (i < N) dinv[i] = 1.0f / sqrtf((float)deg[i] + 1.0f);
}

__global__ void k_coef_full(const int2* __restrict__ csr_se, const float* __restrict__ dinv,
                            float* __restrict__ coef, int E) {
    int i = blockIdx.x * blockDim.x + threadIdx.x;
    if (i < E) coef[i] = dinv[csr_se[i].x];
}

__global__ void k_coef_mask(const int2* __restrict__ csr_se, const float* __restrict__ dinv,
                            const float* __restrict__ mask, float* __restrict__ coef, int E) {
    int i = blockIdx.x * blockDim.x + threadIdx.x;
    if (i < E) {
        int2 se = csr_se[i];
        coef[i] = dinv[se.x] * mask[se.y];
    }
}

// edge dot-product over 64 features, 16 lanes per edge
__global__ __launch_bounds__(256) void k_mask(const float* __restrict__ tz,
                                              const int* __restrict__ src,
                                              const int* __restrict__ dstv,
                                              const float* __restrict__ er,
                                              float* __restrict__ mask,
                                              int* __restrict__ degm, int E) {
    int gid = blockIdx.x * 256 + threadIdx.x;
    int e = gid >> 4;
    int l = gid & 15;
    if (e >= E) return;
    int s = src[e], d = dstv[e];
    const float4 a = *(const float4*)&tz[(size_t)s * 64 + l * 4];
    const float4 b = *(const float4*)&tz[(size_t)d * 64 + l * 4];
    float p = a.x * b.x + a.y * b.y + a.z * b.z + a.w * b.w;
    p += __shfl_xor(p, 1, 16);
    p += __shfl_xor(p, 2, 16);
    p += __shfl_xor(p, 4, 16);
    p += __shfl_xor(p, 8, 16);
    if (l == 0) {
        float sg = 1.0f / (1.0f + expf(-p));
        float m = (sg > er[e]) ? 1.0f : 0.0f;
        mask[e] = m;
        if (m != 0.0f) atomicAdd(&degm[d], 1);
    }
}

// pack W [128][OUTC] f32 -> MFMA B-fragment layout bf16:
// Wpk[(ct*4+kb)*64 + l][i] = W[kb*32 + (l>>4)*8 + i][ct*16 + (l&15)]
__global__ void k_packw(const float* __restrict__ W, unsigned short* __restrict__ Wpk,
                        int OUTC, int total) {
    int idx = blockIdx.x * 256 + threadIdx.x;   // (ct*4+kb)*64 + l
    if (idx >= total) return;
    int l = idx & 63;
    int tk = idx >> 6;
    int kb = tk & 3;
    int ct = tk >> 2;
    unsigned u[4];
#pragma unroll
    for (int i2 = 0; i2 < 4; i2++) {
        float v0 = W[(kb * 32 + ((l >> 4) * 8) + 2 * i2 + 0) * OUTC + ct * 16 + (l & 15)];
        float v1 = W[(kb * 32 + ((l >> 4) * 8) + 2 * i2 + 1) * OUTC + ct * 16 + (l & 15)];
        u[i2] = bfpair(v0, v1);
    }
    *(uint4*)&Wpk[(size_t)idx * 8] = make_uint4(u[0], u[1], u[2], u[3]);
}

// bf16 MFMA GEMM: C[N][OUTC] = A[N][128] x W, A bf16, Wpk pre-packed bf16,
// f32 accumulate, bf16 output. Block = 4 waves x 16 rows = 64 rows.
template <int OUTC>
__global__ __launch_bounds__(256) void k_gemm_mfma(const unsigned short* __restrict__ A,
                                                   const unsigned short* __restrict__ Wpk,
                                                   unsigned short* __restrict__ C, int N) {
    constexpr int CT = OUTC / 16;
    __shared__ unsigned short eps[64 * OUTC];
    const int w = threadIdx.x >> 6;
    const int l = threadIdx.x & 63;
    const int rowl = (w * 16) + (l & 15);
    int row = blockIdx.x * 64 + rowl;
    int rowc = (row < N) ? row : (N - 1);

    bf16x8 a[4];
#pragma unroll
    for (int kb = 0; kb < 4; kb++)
        a[kb] = *(const bf16x8*)&A[(size_t)rowc * 128 + kb * 32 + ((l >> 4) * 8)];

#pragma unroll
    for (int ct = 0; ct < CT; ct++) {
        f32x4 acc = {0.f, 0.f, 0.f, 0.f};
#pragma unroll
        for (int kb = 0; kb < 4; kb++) {
            bf16x8 b = *(const bf16x8*)&Wpk[((size_t)(ct * 4 + kb) * 64 + l) * 8];
            acc = __builtin_amdgcn_mfma_f32_16x16x32_bf16(a[kb], b, acc, 0, 0, 0);
        }
        // C/D map: col = lane&15, row = (lane>>4)*4 + r  [HW-verified]
#pragma unroll
        for (int r = 0; r < 4; r++) {
            int rr = w * 16 + (l >> 4) * 4 + r;
            eps[rr * OUTC + ct * 16 + (l & 15)] = bf1(acc[r]);
        }
    }
    __syncthreads();
    // coalesced bf16 write-out
    constexpr int NU4 = 64 * OUTC / 8;
    for (int idx = threadIdx.x; idx < NU4; idx += 256) {
        int rl = idx / (OUTC / 8);
        int cg = idx % (OUTC / 8);
        int grow = blockIdx.x * 64 + rl;
        if (grow < N)
            *(uint4*)&C[(size_t)grow * OUTC + cg * 8] = *(const uint4*)&eps[rl * OUTC + cg * 8];
    }
}

// fp32 GEMM (pass-1, exact): C[N][OUTC] = A[N][128] x W[128][OUTC]
// thread cols remapped to {tx*4..+3} (+ {64+tx*4..+3} when TN=8): 2-way LDS
// bank aliasing on ds_read_b128 (free) instead of 4-way.
template <int OUTC, bool WF32, bool WB16>
__global__ __launch_bounds__(256) void k_gemm(const float* __restrict__ A,
                                              const float* __restrict__ W,
                                              float* __restrict__ Cout,
                                              unsigned short* __restrict__ Cb, int N) {
    constexpr int TN = OUTC / 16;  // 8 or 4 cols per thread
    __shared__ float As[16][136];       // [k][row]
    __shared__ float Ws[16][OUTC + 8];  // [k][col]
    const int tid = threadIdx.x;
    const int tx = tid & 15;
    const int ty = tid >> 4;
    const int r0 = blockIdx.x * 128;
    const int c0 = tx * 4;          // first col group
    const int c1 = 64 + tx * 4;     // second col group (TN==8 only)

    float acc[8][TN];
#pragma unroll
    for (int i = 0; i < 8; i++)
#pragma unroll
        for (int j = 0; j < TN; j++) acc[i][j] = 0.0f;

    for (int k0 = 0; k0 < 128; k0 += 16) {
        __syncthreads();
#pragma unroll
        for (int l = 0; l < 2; ++l) {
            int idx = tid + l * 256;          // 0..511
            int row = idx >> 2;               // 0..127
            int c4 = idx & 3;                 // 0..3
            int gr = r0 + row;
            if (gr >= N) gr = N - 1;
            const float4 vv = *(const float4*)&A[(size_t)gr * 128 + k0 + c4 * 4];
            As[c4 * 4 + 0][row] = vv.x;
            As[c4 * 4 + 1][row] = vv.y;
            As[c4 * 4 + 2][row] = vv.z;
            As[c4 * 4 + 3][row] = vv.w;
        }
#pragma unroll
        for (int l = 0; l < (16 * OUTC / 4) / 256; ++l) {
            int idx = tid + l * 256;
            int row = idx / (OUTC / 4);
            int c4 = idx % (OUTC / 4);
            const float4 vv = *(const float4*)&W[(k0 + row) * OUTC + c4 * 4];
            *(float4*)&Ws[row][c4 * 4] = vv;
        }
        __syncthreads();
#pragma unroll
        for (int kk = 0; kk < 16; ++kk) {
            float a[8], b[TN];
#pragma unroll
            for (int i = 0; i < 8; i++) a[i] = As[kk][ty * 8 + i];
#pragma unroll
            for (int j = 0; j < 4; j++) b[j] = Ws[kk][c0 + j];
            if (TN == 8) {
#pragma unroll
                for (int j = 4; j < TN; j++) b[j] = Ws[kk][c1 + (j - 4)];
            }
#pragma unroll
            for (int i = 0; i < 8; i++)
#pragma unroll
                for (int j = 0; j < TN; j++) acc[i][j] = fmaf(a[i], b[j], acc[i][j]);
        }
    }
#pragma unroll
    for (int i = 0; i < 8; i++) {
        int r = r0 + ty * 8 + i;
        if (r < N) {
            if (WF32) {
                *(float4*)&Cout[(size_t)r * OUTC + c0] =
                    make_float4(acc[i][0], acc[i][1], acc[i][2], acc[i][3]);
                if (TN == 8)
                    *(float4*)&Cout[(size_t)r * OUTC + c1] =
                        make_float4(acc[i][4], acc[i][5], acc[i][6], acc[i][7]);
            }
            if (WB16) {
                *(uint2*)&Cb[(size_t)r * OUTC + c0] =
                    make_uint2(bfpair(acc[i][0], acc[i][1]), bfpair(acc[i][2], acc[i][3]));
                if (TN == 8)
                    *(uint2*)&Cb[(size_t)r * OUTC + c1] =
                        make_uint2(bfpair(acc[i][4], acc[i][5]), bfpair(acc[i][6], acc[i][7]));
            }
        }
    }
}

// ---------------- fp32 aggregations (pass 1, mask-critical) ----------------
template <bool RELU>
__global__ __launch_bounds__(128) void k_agg128(const float* __restrict__ h,
                                                const int* __restrict__ csr_off,
                                                const int2* __restrict__ csr_se,
                                                const float* __restrict__ coef,
                                                const float* __restrict__ dinv,
                                                const float* __restrict__ bias,
                                                float* __restrict__ out, int N) {
    const int v = blockIdx.x;
    const int l = threadIdx.x & 31;
    const int s = threadIdx.x >> 5;  // 0..3
    const int e0 = csr_off[v];
    const int e1 = csr_off[v + 1];
    float4 acc = make_float4(0.f, 0.f, 0.f, 0.f);
    int i = e0 + s;
    for (; i + 4 < e1; i += 8) {
        int sa = csr_se[i].x;      float wa = coef[i];
        int sb = csr_se[i + 4].x;  float wb = coef[i + 4];
        float4 a = *(const float4*)&h[(size_t)sa * 128 + l * 4];
        float4 b = *(const float4*)&h[(size_t)sb * 128 + l * 4];
        acc.x = fmaf(a.x, wa, acc.x); acc.y = fmaf(a.y, wa, acc.y);
        acc.z = fmaf(a.z, wa, acc.z); acc.w = fmaf(a.w, wa, acc.w);
        acc.x = fmaf(b.x, wb, acc.x); acc.y = fmaf(b.y, wb, acc.y);
        acc.z = fmaf(b.z, wb, acc.z); acc.w = fmaf(b.w, wb, acc.w);
    }
    if (i < e1) {
        int sa = csr_se[i].x;
        float wa = coef[i];
        float4 a = *(const float4*)&h[(size_t)sa * 128 + l * 4];
        acc.x = fmaf(a.x, wa, acc.x); acc.y = fmaf(a.y, wa, acc.y);
        acc.z = fmaf(a.z, wa, acc.z); acc.w = fmaf(a.w, wa, acc.w);
    }
    __shared__ float4 red[4][32];
    red[s][l] = acc;
    __syncthreads();
    if (threadIdx.x < 32) {
        float4 r0 = red[0][l], r1 = red[1][l], r2 = red[2][l], r3 = red[3][l];
        float dv = dinv[v];
        float4 hv = *(const float4*)&h[(size_t)v * 128 + l * 4];
        float4 bb = *(const float4*)&bias[l * 4];
        float4 o;
        o.x = dv * ((r0.x + r1.x + r2.x + r3.x) + hv.x * dv) + bb.x;
        o.y = dv * ((r0.y + r1.y + r2.y + r3.y) + hv.y * dv) + bb.y;
        o.z = dv * ((r0.z + r1.z + r2.z + r3.z) + hv.z * dv) + bb.z;
        o.w = dv * ((r0.w + r1.w + r2.w + r3.w) + hv.w * dv) + bb.w;
        if (RELU) {
            o.x = fmaxf(o.x, 0.f); o.y = fmaxf(o.y, 0.f);
            o.z = fmaxf(o.z, 0.f); o.w = fmaxf(o.w, 0.f);
        }
        *(float4*)&out[(size_t)v * 128 + l * 4] = o;
    }
}

__global__ __launch_bounds__(128) void k_agg64(const float* __restrict__ h,
                                               const int* __restrict__ csr_off,
                                               const int2* __restrict__ csr_se,
                                               const float* __restrict__ coef,
                                               const float* __restrict__ dinv,
                                               const float* __restrict__ bias,
                                               float* __restrict__ out, int N) {
    const int v = blockIdx.x;
    const int l = threadIdx.x & 15;
    const int s = threadIdx.x >> 4;  // 0..7
    const int e0 = csr_off[v];
    const int e1 = csr_off[v + 1];
    float4 acc = make_float4(0.f, 0.f, 0.f, 0.f);
    int i = e0 + s;
    for (; i + 8 < e1; i += 16) {
        int sa = csr_se[i].x;      float wa = coef[i];
        int sb = csr_se[i + 8].x;  float wb = coef[i + 8];
        float4 a = *(const float4*)&h[(size_t)sa * 64 + l * 4];
        float4 b = *(const float4*)&h[(size_t)sb * 64 + l * 4];
        acc.x = fmaf(a.x, wa, acc.x); acc.y = fmaf(a.y, wa, acc.y);
        acc.z = fmaf(a.z, wa, acc.z); acc.w = fmaf(a.w, wa, acc.w);
        acc.x = fmaf(b.x, wb, acc.x); acc.y = fmaf(b.y, wb, acc.y);
        acc.z = fmaf(b.z, wb, acc.z); acc.w = fmaf(b.w, wb, acc.w);
    }
    if (i < e1) {
        int sa = csr_se[i].x;
        float wa = coef[i];
        float4 a = *(const float4*)&h[(size_t)sa * 64 + l * 4];
        acc.x = fmaf(a.x, wa, acc.x); acc.y = fmaf(a.y, wa, acc.y);
        acc.z = fmaf(a.z, wa, acc.z); acc.w = fmaf(a.w, wa, acc.w);
    }
    __shared__ float4 red[8][16];
    red[s][l] = acc;
    __syncthreads();
    if (threadIdx.x < 16) {
        float4 aa = make_float4(0.f, 0.f, 0.f, 0.f);
#pragma unroll
        for (int k = 0; k < 8; ++k) {
            float4 r = red[k][l];
            aa.x += r.x; aa.y += r.y; aa.z += r.z; aa.w += r.w;
        }
        float dv = dinv[v];
        float4 hv = *(const float4*)&h[(size_t)v * 64 + l * 4];
        float4 bb = *(const float4*)&bias[l * 4];
        float4 o;
        o.x = dv * (aa.x + hv.x * dv) + bb.x;
        o.y = dv * (aa.y + hv.y * dv) + bb.y;
        o.z = dv * (aa.z + hv.z * dv) + bb.z;
        o.w = dv * (aa.w + hv.w * dv) + bb.w;
        *(float4*)&out[(size_t)v * 64 + l * 4] = o;
    }
}

// ---------------- bf16-gather aggregations (pass 2, post-mask) -------------
// rows bf16: 128 feats = 256B. 16 lanes x 8 feats, 8 edge slots. bf16 output.
template <bool RELU>
__global__ __launch_bounds__(128) void k_agg128b(const unsigned short* __restrict__ h,
                                                 const int* __restrict__ csr_off,
                                                 const int2* __restrict__ csr_se,
                                                 const float* __restrict__ coef,
                                                 const float* __restrict__ dinv,
                                                 const float* __restrict__ bias,
                                                 unsigned short* __restrict__ out, int N) {
    const int v = blockIdx.x;
    const int l = threadIdx.x & 15;  // 8-feature group
    const int s = threadIdx.x >> 4;  // 0..7 edge slot
    const int e0 = csr_off[v];
    const int e1 = csr_off[v + 1];
    float acc[8];
#pragma unroll
    for (int j = 0; j < 8; j++) acc[j] = 0.f;
    int i = e0 + s;
    for (; i + 8 < e1; i += 16) {
        int sa = csr_se[i].x;      float wa = coef[i];
        int sb = csr_se[i + 8].x;  float wb = coef[i + 8];
        uint4 ua = *(const uint4*)&h[(size_t)sa * 128 + l * 8];
        uint4 ub = *(const uint4*)&h[(size_t)sb * 128 + l * 8];
        float f0, f1;
        unpack2(ua.x, f0, f1); acc[0] = fmaf(f0, wa, acc[0]); acc[1] = fmaf(f1, wa, acc[1]);
        unpack2(ua.y, f0, f1); acc[2] = fmaf(f0, wa, acc[2]); acc[3] = fmaf(f1, wa, acc[3]);
        unpack2(ua.z, f0, f1); acc[4] = fmaf(f0, wa, acc[4]); acc[5] = fmaf(f1, wa, acc[5]);
        unpack2(ua.w, f0, f1); acc[6] = fmaf(f0, wa, acc[6]); acc[7] = fmaf(f1, wa, acc[7]);
        unpack2(ub.x, f0, f1); acc[0] = fmaf(f0, wb, acc[0]); acc[1] = fmaf(f1, wb, acc[1]);
        unpack2(ub.y, f0, f1); acc[2] = fmaf(f0, wb, acc[2]); acc[3] = fmaf(f1, wb, acc[3]);
        unpack2(ub.z, f0, f1); acc[4] = fmaf(f0, wb, acc[4]); acc[5] = fmaf(f1, wb, acc[5]);
        unpack2(ub.w, f0, f1); acc[6] = fmaf(f0, wb, acc[6]); acc[7] = fmaf(f1, wb, acc[7]);
    }
    if (i < e1) {
        int sa = csr_se[i].x;
        float wa = coef[i];
        uint4 ua = *(const uint4*)&h[(size_t)sa * 128 + l * 8];
        float f0, f1;
        unpack2(ua.x, f0, f1); acc[0] = fmaf(f0, wa, acc[0]); acc[1] = fmaf(f1, wa, acc[1]);
        unpack2(ua.y, f0, f1); acc[2] = fmaf(f0, wa, acc[2]); acc[3] = fmaf(f1, wa, acc[3]);
        unpack2(ua.z, f0, f1); acc[4] = fmaf(f0, wa, acc[4]); acc[5] = fmaf(f1, wa, acc[5]);
        unpack2(ua.w, f0, f1); acc[6] = fmaf(f0, wa, acc[6]); acc[7] = fmaf(f1, wa, acc[7]);
    }
    __shared__ float red[8][16][8];
#pragma unroll
    for (int j = 0; j < 8; j += 4)
        *(float4*)&red[s][l][j] = make_float4(acc[j], acc[j + 1], acc[j + 2], acc[j + 3]);
    __syncthreads();
    if (threadIdx.x < 16) {
        int ll = threadIdx.x;
        float rr[8];
#pragma unroll
        for (int j = 0; j < 8; j++) rr[j] = 0.f;
#pragma unroll
        for (int k = 0; k < 8; ++k)
#pragma unroll
            for (int j = 0; j < 8; j++) rr[j] += red[k][ll][j];
        float dv = dinv[v];
        uint4 uh = *(const uint4*)&h[(size_t)v * 128 + ll * 8];
        float hv[8];
        unpack2(uh.x, hv[0], hv[1]); unpack2(uh.y, hv[2], hv[3]);
        unpack2(uh.z, hv[4], hv[5]); unpack2(uh.w, hv[6], hv[7]);
        unsigned u[4];
#pragma unroll
        for (int j2 = 0; j2 < 4; j2++) {
            float o0 = dv * (rr[2 * j2 + 0] + hv[2 * j2 + 0] * dv) + bias[ll * 8 + 2 * j2 + 0];
            float o1 = dv * (rr[2 * j2 + 1] + hv[2 * j2 + 1] * dv) + bias[ll * 8 + 2 * j2 + 1];
            if (RELU) { o0 = fmaxf(o0, 0.f); o1 = fmaxf(o1, 0.f); }
            u[j2] = bfpair(o0, o1);
        }
        *(uint4*)&out[(size_t)v * 128 + ll * 8] = make_uint4(u[0], u[1], u[2], u[3]);
    }
}

// 64 feats bf16 = 128B. 8 lanes x 8 feats, 16 edge slots. out f32.
__global__ __launch_bounds__(128) void k_agg64b(const unsigned short* __restrict__ h,
                                                const int* __restrict__ csr_off,
                                                const int2* __restrict__ csr_se,
                                                const float* __restrict__ coef,
                                                const float* __restrict__ dinv,
                                                const float* __restrict__ bias,
                                                float* __restrict__ out, int N) {
    const int v = blockIdx.x;
    const int l = threadIdx.x & 7;   // 8-feature group
    const int s = threadIdx.x >> 3;  // 0..15 edge slot
    const int e0 = csr_off[v];
    const int e1 = csr_off[v + 1];
    float acc[8];
#pragma unroll
    for (int j = 0; j < 8; j++) acc[j] = 0.f;
    for (int i = e0 + s; i < e1; i += 16) {
        int sa = csr_se[i].x;
        float wa = coef[i];
        uint4 ua = *(const uint4*)&h[(size_t)sa * 64 + l * 8];
        float f0, f1;
        unpack2(ua.x, f0, f1); acc[0] = fmaf(f0, wa, acc[0]); acc[1] = fmaf(f1, wa, acc[1]);
        unpack2(ua.y, f0, f1); acc[2] = fmaf(f0, wa, acc[2]); acc[3] = fmaf(f1, wa, acc[3]);
        unpack2(ua.z, f0, f1); acc[4] = fmaf(f0, wa, acc[4]); acc[5] = fmaf(f1, wa, acc[5]);
        unpack2(ua.w, f0, f1); acc[6] = fmaf(f0, wa, acc[6]); acc[7] = fmaf(f1, wa, acc[7]);
    }
    __shared__ float red[16][8][8];
#pragma unroll
    for (int j = 0; j < 8; j += 4)
        *(float4*)&red[s][l][j] = make_float4(acc[j], acc[j + 1], acc[j + 2], acc[j + 3]);
    __syncthreads();
    if (threadIdx.x < 8) {
        int ll = threadIdx.x;
        float rr[8];
#pragma unroll
        for (int j = 0; j < 8; j++) rr[j] = 0.f;
#pragma unroll
        for (int k = 0; k < 16; ++k)
#pragma unroll
            for (int j = 0; j < 8; j++) rr[j] += red[k][ll][j];
        float dv = dinv[v];
        uint4 uh = *(const uint4*)&h[(size_t)v * 64 + ll * 8];
        float hv[8];
        unpack2(uh.x, hv[0], hv[1]); unpack2(uh.y, hv[2], hv[3]);
        unpack2(uh.z, hv[4], hv[5]); unpack2(uh.w, hv[6], hv[7]);
        float o[8];
#pragma unroll
        for (int j = 0; j < 8; j++) o[j] = dv * (rr[j] + hv[j] * dv) + bias[ll * 8 + j];
        *(float4*)&out[(size_t)v * 64 + ll * 8 + 0] = make_float4(o[0], o[1], o[2], o[3]);
        *(float4*)&out[(size_t)v * 64 + ll * 8 + 4] = make_float4(o[4], o[5], o[6], o[7]);
    }
}

extern "C" void kernel_launch(void* const* d_in, const int* in_sizes, int n_in,
                              void* d_out, int out_size, void* d_ws, size_t ws_size,
                              hipStream_t stream) {
    const float* x  = (const float*)d_in[0];
    const int*   ei = (const int*)d_in[1];
    const float* er = (const float*)d_in[2];
    const float* w0 = (const float*)d_in[3];
    const float* b0 = (const float*)d_in[4];
    const float* w1 = (const float*)d_in[5];
    const float* b1 = (const float*)d_in[6];
    const float* w2 = (const float*)d_in[7];
    const float* b2 = (const float*)d_in[8];
    const int N = in_sizes[0] / 128;
    const int E = in_sizes[2];
    const int* src  = ei;
    const int* dstv = ei + E;
    float* out = (float*)d_out;

    // workspace carve
    char* p = (char*)d_ws;
    auto alloc = [&](size_t bytes) {
        char* r = p;
        p += (bytes + 255) & ~(size_t)255;
        return r;
    };
    int* indeg     = (int*)alloc((size_t)N * 4);
    int* cursor    = (int*)alloc((size_t)N * 4);
    int* degm      = (int*)alloc((size_t)N * 4);
    int* csr_off   = (int*)alloc((size_t)(N + 1) * 4);
    int* bsums     = (int*)alloc(1024);
    int2* csr_se   = (int2*)alloc((size_t)E * 8);
    float* coefF   = (float*)alloc((size_t)E * 4);
    float* coefM   = (float*)alloc((size_t)E * 4);
    float* maskA   = (float*)alloc((size_t)E * 4);
    float* dinvF   = (float*)alloc((size_t)N * 4);
    float* dinvM   = (float*)alloc((size_t)N * 4);
    float* hx      = (float*)alloc((size_t)N * 128 * 4);  // x@w0 f32 (pass1)
    unsigned short* hxb = (unsigned short*)alloc((size_t)N * 128 * 2);  // x@w0 bf16 (pass2)
    float* wk1     = (float*)alloc((size_t)N * 128 * 4);
    float* wk2     = (float*)alloc((size_t)N * 128 * 4);
    float* tz      = (float*)alloc((size_t)N * 64 * 4);
    unsigned short* w1pk = (unsigned short*)alloc((size_t)128 * 128 * 2);
    unsigned short* w2pk = (unsigned short*)alloc((size_t)128 * 64 * 2);
    unsigned short* wk1b = (unsigned short*)wk1;  // pass2 alias
    unsigned short* wk2b = (unsigned short*)wk2;  // pass2 alias

    hipMemsetAsync(indeg, 0, (size_t)N * 4, stream);
    hipMemsetAsync(cursor, 0, (size_t)N * 4, stream);
    hipMemsetAsync(degm, 0, (size_t)N * 4, stream);

    const int TB = 256;
    const int ebk = (E + TB - 1) / TB;
    const int nbk = (N + TB - 1) / TB;
    const int nb = (N + 255) / 256;

    // weight packs for MFMA (pass 2)
    k_packw<<<8, 256, 0, stream>>>(w1, w1pk, 128, 2048);
    k_packw<<<4, 256, 0, stream>>>(w2, w2pk, 64, 1024);

    // CSR build
    k_hist<<<ebk, TB, 0, stream>>>(dstv, indeg, E);
    k_scan1<<<nb, 256, 0, stream>>>(indeg, csr_off, bsums, N);
    k_scan2<<<1, 256, 0, stream>>>(bsums, nb);
    k_scan3<<<nb, 256, 0, stream>>>(csr_off, bsums, N, E);
    k_fill<<<ebk, TB, 0, stream>>>(src, dstv, csr_off, cursor, csr_se, E);
    k_dinv<<<nbk, TB, 0, stream>>>(indeg, dinvF, N);
    k_coef_full<<<ebk, TB, 0, stream>>>(csr_se, dinvF, coefF, E);

    const int gb = (N + 127) / 128;
    const int gbm = (N + 63) / 64;

    // shared first GEMM: f32 for pass1, bf16 for pass2
    k_gemm<128, true, true><<<gb, 256, 0, stream>>>(x, w0, hx, hxb, N);

    // pass 1 (full graph, exact fp32 -> tz -> mask)
    k_agg128<true><<<N, 128, 0, stream>>>(hx, csr_off, csr_se, coefF, dinvF, b0, wk1, N);
    k_gemm<128, true, false><<<gb, 256, 0, stream>>>(wk1, w1, wk2, nullptr, N);
    k_agg128<true><<<N, 128, 0, stream>>>(wk2, csr_off, csr_se, coefF, dinvF, b1, wk1, N);
    k_gemm<64, true, false><<<gb, 256, 0, stream>>>(wk1, w2, wk2, nullptr, N);
    k_agg64<<<N, 128, 0, stream>>>(wk2, csr_off, csr_se, coefF, dinvF, b2, tz, N);

    // edge sampling
    k_mask<<<(int)(((size_t)E * 16 + 255) / 256), 256, 0, stream>>>(tz, src, dstv, er, maskA, degm, E);
    k_dinv<<<nbk, TB, 0, stream>>>(degm, dinvM, N);
    k_coef_mask<<<ebk, TB, 0, stream>>>(csr_se, dinvM, maskA, coefM, E);

    // pass 2 (post-mask: bf16 gathers + bf16 MFMA GEMMs)
    k_agg128b<true><<<N, 128, 0, stream>>>(hxb, csr_off, csr_se, coefM, dinvM, b0, wk1b, N);
    k_gemm_mfma<128><<<gbm, 256, 0, stream>>>(wk1b, w1pk, wk2b, N);
    k_agg128b<true><<<N, 128, 0, stream>>>(wk2b, csr_off, csr_se, coefM, dinvM, b1, wk1b, N);
    k_gemm_mfma<64><<<gbm, 256, 0, stream>>>(wk1b, w2pk, wk2b, N);
    k_agg64b<<<N, 128, 0, stream>>>(wk2b, csr_off, csr_se, coefF, dinvF, b2, out, N);
}

// Round 6
// 525.117 us; speedup vs baseline: 1.2219x; 1.0255x over previous
//
#include <hip/hip_runtime.h>

// ---------------------------------------------------------------------------
// GCN with edge sampling.
//  Pass 1 (-> tz -> mask) uses split-bf16 MFMA GEMMs (3-plane Ozaki split,
//  8 cross terms, error ~2^-25 ~ below f32 order noise) + exact f32 aggs.
//  Pass 2 (post-mask) is bf16 end-to-end (bf16 gathers, bf16 MFMA GEMMs).
//  Mask evaluated in CSR order (k_surv): tz[dst] loaded once per node,
//  no atomics, sequential survive[] writes.
// conv: out[v] = dinv[v]*(sum_e h[src]*coef[e] + h[v]*dinv[v]) + b
// ---------------------------------------------------------------------------

typedef __attribute__((ext_vector_type(8))) short bf16x8;
typedef __attribute__((ext_vector_type(4))) float f32x4;

__device__ inline unsigned bfpair(float lo, float hi) {   // pack 2 f32 -> bf16x2 RNE
    unsigned a = __float_as_uint(lo), b = __float_as_uint(hi);
    a = (a + 0x7FFFu + ((a >> 16) & 1u)) >> 16;
    b = (b + 0x7FFFu + ((b >> 16) & 1u)) & 0xFFFF0000u;
    return a | b;
}
__device__ inline unsigned short bf1(float v) {
    unsigned u = __float_as_uint(v);
    return (unsigned short)((u + 0x7FFFu + ((u >> 16) & 1u)) >> 16);
}
__device__ inline void unpack2(unsigned u, float& f0, float& f1) {
    f0 = __uint_as_float(u << 16);
    f1 = __uint_as_float(u & 0xFFFF0000u);
}

__global__ void k_hist(const int* __restrict__ dst, int* __restrict__ indeg, int E) {
    int e = blockIdx.x * blockDim.x + threadIdx.x;
    if (e < E) atomicAdd(&indeg[dst[e]], 1);
}

__global__ void k_scan1(const int* __restrict__ in, int* __restrict__ out,
                        int* __restrict__ bsums, int N) {
    __shared__ int tmp[256];
    int i = blockIdx.x * 256 + threadIdx.x;
    int v = (i < N) ? in[i] : 0;
    tmp[threadIdx.x] = v;
    __syncthreads();
    for (int off = 1; off < 256; off <<= 1) {
        int t = (threadIdx.x >= off) ? tmp[threadIdx.x - off] : 0;
        __syncthreads();
        tmp[threadIdx.x] += t;
        __syncthreads();
    }
    if (i < N) out[i] = tmp[threadIdx.x] - v;   // exclusive
    if (threadIdx.x == 255) bsums[blockIdx.x] = tmp[255];
}

__global__ void k_scan2(int* __restrict__ bsums, int nb) {
    __shared__ int tmp[256];
    int v = (threadIdx.x < nb) ? bsums[threadIdx.x] : 0;
    tmp[threadIdx.x] = v;
    __syncthreads();
    for (int off = 1; off < 256; off <<= 1) {
        int t = (threadIdx.x >= off) ? tmp[threadIdx.x - off] : 0;
        __syncthreads();
        tmp[threadIdx.x] += t;
        __syncthreads();
    }
    if (threadIdx.x < nb) bsums[threadIdx.x] = tmp[threadIdx.x] - v;  // exclusive
}

__global__ void k_scan3(int* __restrict__ out, const int* __restrict__ bsums, int N, int E) {
    int i = blockIdx.x * 256 + threadIdx.x;
    if (i < N) out[i] += bsums[blockIdx.x];
    if (i == 0) out[N] = E;
}

// CSR fill: payload = (src, er bits)
__global__ void k_fill(const int* __restrict__ src, const int* __restrict__ dst,
                       const float* __restrict__ er,
                       const int* __restrict__ csr_off, int* __restrict__ cursor,
                       int2* __restrict__ csr_se, int E) {
    int e = blockIdx.x * blockDim.x + threadIdx.x;
    if (e < E) {
        int d = dst[e];
        int pos = csr_off[d] + atomicAdd(&cursor[d], 1);
        csr_se[pos] = make_int2(src[e], (int)__float_as_uint(er[e]));
    }
}

__global__ void k_dinv(const int* __restrict__ deg, float* __restrict__ dinv, int N) {
    int i = blockIdx.x * blockDim.x + threadIdx.x;
    if (i < N) dinv[i] = 1.0f / sqrtf((float)deg[i] + 1.0f);
}

__global__ void k_coef_full(const int2* __restrict__ csr_se, const float* __restrict__ dinv,
                            float* __restrict__ coef, int E) {
    int i = blockIdx.x * blockDim.x + threadIdx.x;
    if (i < E) coef[i] = dinv[csr_se[i].x];
}

__global__ void k_coef_mask(const int2* __restrict__ csr_se, const float* __restrict__ dinv,
                            const float* __restrict__ survive, float* __restrict__ coef, int E) {
    int i = blockIdx.x * blockDim.x + threadIdx.x;
    if (i < E) coef[i] = dinv[csr_se[i].x] * survive[i];
}

// mask in CSR order: block per node, 8 edge slots x 16 lanes; tz[v] loaded once.
__global__ __launch_bounds__(128) void k_surv(const float* __restrict__ tz,
                                              const int* __restrict__ csr_off,
                                              const int2* __restrict__ csr_se,
                                              float* __restrict__ survive,
                                              int* __restrict__ degm, int N) {
    const int v = blockIdx.x;
    const int l = threadIdx.x & 15;
    const int s = threadIdx.x >> 4;
    const int e0 = csr_off[v];
    const int e1 = csr_off[v + 1];
    const float4 tv = *(const float4*)&tz[(size_t)v * 64 + l * 4];
    int cnt = 0;
    for (int i = e0 + s; i < e1; i += 8) {
        int2 se = csr_se[i];
        const float4 a = *(const float4*)&tz[(size_t)se.x * 64 + l * 4];
        float p = a.x * tv.x + a.y * tv.y + a.z * tv.z + a.w * tv.w;
        p += __shfl_xor(p, 1, 16);
        p += __shfl_xor(p, 2, 16);
        p += __shfl_xor(p, 4, 16);
        p += __shfl_xor(p, 8, 16);
        float sg = 1.0f / (1.0f + expf(-p));
        float m = (sg > __uint_as_float((unsigned)se.y)) ? 1.0f : 0.0f;
        if (l == 0) {
            survive[i] = m;
            cnt += (m != 0.0f) ? 1 : 0;
        }
    }
    __shared__ int sc[8];
    if (l == 0) sc[s] = cnt;
    __syncthreads();
    if (threadIdx.x == 0) {
        int t = 0;
#pragma unroll
        for (int k = 0; k < 8; k++) t += sc[k];
        degm[v] = t;
    }
}

// pack W [128][OUTC] f32 -> single bf16 plane in MFMA B-frag layout (pass 2)
__global__ void k_packw(const float* __restrict__ W, unsigned short* __restrict__ Wpk,
                        int OUTC, int total) {
    int idx = blockIdx.x * 256 + threadIdx.x;   // (ct*4+kb)*64 + l
    if (idx >= total) return;
    int l = idx & 63;
    int tk = idx >> 6;
    int kb = tk & 3;
    int ct = tk >> 2;
    unsigned u[4];
#pragma unroll
    for (int i2 = 0; i2 < 4; i2++) {
        float v0 = W[(kb * 32 + ((l >> 4) * 8) + 2 * i2 + 0) * OUTC + ct * 16 + (l & 15)];
        float v1 = W[(kb * 32 + ((l >> 4) * 8) + 2 * i2 + 1) * OUTC + ct * 16 + (l & 15)];
        u[i2] = bfpair(v0, v1);
    }
    *(uint4*)&Wpk[(size_t)idx * 8] = make_uint4(u[0], u[1], u[2], u[3]);
}

// pack W -> 3 bf16 split planes (pass-1 split GEMM): W ~ W0 + W1 + W2
__global__ void k_packw3(const float* __restrict__ W, unsigned short* __restrict__ Wp,
                         int OUTC, int total) {
    int idx = blockIdx.x * 256 + threadIdx.x;
    if (idx >= total) return;
    int l = idx & 63;
    int tk = idx >> 6;
    int kb = tk & 3;
    int ct = tk >> 2;
    size_t PL = (size_t)(OUTC / 16) * 4 * 64 * 8;
    unsigned short v0[8], v1[8], v2[8];
#pragma unroll
    for (int i = 0; i < 8; i++) {
        float wv = W[(kb * 32 + ((l >> 4) * 8) + i) * OUTC + ct * 16 + (l & 15)];
        unsigned short h0 = bf1(wv);
        float f0 = __uint_as_float((unsigned)h0 << 16);
        float r1 = wv - f0;
        unsigned short h1 = bf1(r1);
        float f1 = __uint_as_float((unsigned)h1 << 16);
        unsigned short h2 = bf1(r1 - f1);
        v0[i] = h0; v1[i] = h1; v2[i] = h2;
    }
    auto st = [](unsigned short* dst, unsigned short* v) {
        uint4 u;
        u.x = v[0] | ((unsigned)v[1] << 16);
        u.y = v[2] | ((unsigned)v[3] << 16);
        u.z = v[4] | ((unsigned)v[5] << 16);
        u.w = v[6] | ((unsigned)v[7] << 16);
        *(uint4*)dst = u;
    };
    st(&Wp[(size_t)idx * 8], v0);
    st(&Wp[PL + (size_t)idx * 8], v1);
    st(&Wp[2 * PL + (size_t)idx * 8], v2);
}

// split-bf16 MFMA GEMM (pass 1): C[N][OUTC] = A[N][128] x W, A f32 split
// on the fly into 3 bf16 planes; 8 cross-term MFMAs per k-block; f32 out
// (+ optional bf16 copy). Error ~2^-25 (< f32 summation-order noise).
template <int OUTC, bool WB16>
__global__ __launch_bounds__(256) void k_gemm_split(const float* __restrict__ A,
                                                    const unsigned short* __restrict__ Wp,
                                                    float* __restrict__ Cout,
                                                    unsigned short* __restrict__ Cb, int N) {
    constexpr int CT = OUTC / 16;
    constexpr int PL = CT * 4 * 64 * 8;
    constexpr int LDW = OUTC + 4;           // pad: 2-way LDS aliasing only
    __shared__ float eps[64 * LDW];
    const int w = threadIdx.x >> 6;
    const int l = threadIdx.x & 63;
    int row = blockIdx.x * 64 + w * 16 + (l & 15);
    int rowc = (row < N) ? row : (N - 1);

    bf16x8 a0[4], a1[4], a2[4];
#pragma unroll
    for (int kb = 0; kb < 4; kb++) {
        const float* pa = &A[(size_t)rowc * 128 + kb * 32 + ((l >> 4) * 8)];
        float4 x0 = *(const float4*)pa;
        float4 x1 = *(const float4*)(pa + 4);
        float xa[8] = {x0.x, x0.y, x0.z, x0.w, x1.x, x1.y, x1.z, x1.w};
#pragma unroll
        for (int i = 0; i < 8; i++) {
            unsigned short h0 = bf1(xa[i]);
            float f0 = __uint_as_float((unsigned)h0 << 16);
            float r1 = xa[i] - f0;
            unsigned short h1 = bf1(r1);
            float f1 = __uint_as_float((unsigned)h1 << 16);
            unsigned short h2 = bf1(r1 - f1);
            a0[kb][i] = (short)h0;
            a1[kb][i] = (short)h1;
            a2[kb][i] = (short)h2;
        }
    }
#pragma unroll
    for (int ct = 0; ct < CT; ct++) {
        f32x4 accA = {0.f, 0.f, 0.f, 0.f};
        f32x4 accB = {0.f, 0.f, 0.f, 0.f};
#pragma unroll
        for (int kb = 0; kb < 4; kb++) {
            const size_t bo = ((size_t)(ct * 4 + kb) * 64 + l) * 8;
            bf16x8 b0 = *(const bf16x8*)&Wp[bo];
            bf16x8 b1 = *(const bf16x8*)&Wp[PL + bo];
            bf16x8 b2 = *(const bf16x8*)&Wp[2 * PL + bo];
            accA = __builtin_amdgcn_mfma_f32_16x16x32_bf16(a0[kb], b0, accA, 0, 0, 0);
            accB = __builtin_amdgcn_mfma_f32_16x16x32_bf16(a0[kb], b1, accB, 0, 0, 0);
            accA = __builtin_amdgcn_mfma_f32_16x16x32_bf16(a1[kb], b0, accA, 0, 0, 0);
            accB = __builtin_amdgcn_mfma_f32_16x16x32_bf16(a0[kb], b2, accB, 0, 0, 0);
            accA = __builtin_amdgcn_mfma_f32_16x16x32_bf16(a1[kb], b1, accA, 0, 0, 0);
            accB = __builtin_amdgcn_mfma_f32_16x16x32_bf16(a2[kb], b0, accB, 0, 0, 0);
            accA = __builtin_amdgcn_mfma_f32_16x16x32_bf16(a1[kb], b2, accA, 0, 0, 0);
            accB = __builtin_amdgcn_mfma_f32_16x16x32_bf16(a2[kb], b1, accB, 0, 0, 0);
        }
        // C/D map: col = lane&15, row = (lane>>4)*4 + r  [HW-verified]
#pragma unroll
        for (int r = 0; r < 4; r++) {
            int rr = w * 16 + (l >> 4) * 4 + r;
            eps[rr * LDW + ct * 16 + (l & 15)] = accA[r] + accB[r];
        }
    }
    __syncthreads();
    constexpr int NF4 = 64 * OUTC / 4;
    for (int idx = threadIdx.x; idx < NF4; idx += 256) {
        int rl = idx / (OUTC / 4);
        int cg = idx % (OUTC / 4);
        int grow = blockIdx.x * 64 + rl;
        if (grow < N) {
            const float* sp = &eps[rl * LDW + cg * 4];
            float4 vv = make_float4(sp[0], sp[1], sp[2], sp[3]);
            *(float4*)&Cout[(size_t)grow * OUTC + cg * 4] = vv;
            if (WB16)
                *(uint2*)&Cb[(size_t)grow * OUTC + cg * 4] =
                    make_uint2(bfpair(vv.x, vv.y), bfpair(vv.z, vv.w));
        }
    }
}

// plain bf16 MFMA GEMM (pass 2): A bf16, Wpk single plane, bf16 out.
template <int OUTC>
__global__ __launch_bounds__(256) void k_gemm_mfma(const unsigned short* __restrict__ A,
                                                   const unsigned short* __restrict__ Wpk,
                                                   unsigned short* __restrict__ C, int N) {
    constexpr int CT = OUTC / 16;
    __shared__ unsigned short eps[64 * OUTC];
    const int w = threadIdx.x >> 6;
    const int l = threadIdx.x & 63;
    const int rowl = (w * 16) + (l & 15);
    int row = blockIdx.x * 64 + rowl;
    int rowc = (row < N) ? row : (N - 1);

    bf16x8 a[4];
#pragma unroll
    for (int kb = 0; kb < 4; kb++)
        a[kb] = *(const bf16x8*)&A[(size_t)rowc * 128 + kb * 32 + ((l >> 4) * 8)];

#pragma unroll
    for (int ct = 0; ct < CT; ct++) {
        f32x4 acc = {0.f, 0.f, 0.f, 0.f};
#pragma unroll
        for (int kb = 0; kb < 4; kb++) {
            bf16x8 b = *(const bf16x8*)&Wpk[((size_t)(ct * 4 + kb) * 64 + l) * 8];
            acc = __builtin_amdgcn_mfma_f32_16x16x32_bf16(a[kb], b, acc, 0, 0, 0);
        }
#pragma unroll
        for (int r = 0; r < 4; r++) {
            int rr = w * 16 + (l >> 4) * 4 + r;
            eps[rr * OUTC + ct * 16 + (l & 15)] = bf1(acc[r]);
        }
    }
    __syncthreads();
    constexpr int NU4 = 64 * OUTC / 8;
    for (int idx = threadIdx.x; idx < NU4; idx += 256) {
        int rl = idx / (OUTC / 8);
        int cg = idx % (OUTC / 8);
        int grow = blockIdx.x * 64 + rl;
        if (grow < N)
            *(uint4*)&C[(size_t)grow * OUTC + cg * 8] = *(const uint4*)&eps[rl * OUTC + cg * 8];
    }
}

// ---------------- fp32 aggregations (pass 1, mask-critical) ----------------
template <bool RELU>
__global__ __launch_bounds__(128) void k_agg128(const float* __restrict__ h,
                                                const int* __restrict__ csr_off,
                                                const int2* __restrict__ csr_se,
                                                const float* __restrict__ coef,
                                                const float* __restrict__ dinv,
                                                const float* __restrict__ bias,
                                                float* __restrict__ out, int N) {
    const int v = blockIdx.x;
    const int l = threadIdx.x & 31;
    const int s = threadIdx.x >> 5;  // 0..3
    const int e0 = csr_off[v];
    const int e1 = csr_off[v + 1];
    float4 acc = make_float4(0.f, 0.f, 0.f, 0.f);
    int i = e0 + s;
    for (; i + 4 < e1; i += 8) {
        int sa = csr_se[i].x;      float wa = coef[i];
        int sb = csr_se[i + 4].x;  float wb = coef[i + 4];
        float4 a = *(const float4*)&h[(size_t)sa * 128 + l * 4];
        float4 b = *(const float4*)&h[(size_t)sb * 128 + l * 4];
        acc.x = fmaf(a.x, wa, acc.x); acc.y = fmaf(a.y, wa, acc.y);
        acc.z = fmaf(a.z, wa, acc.z); acc.w = fmaf(a.w, wa, acc.w);
        acc.x = fmaf(b.x, wb, acc.x); acc.y = fmaf(b.y, wb, acc.y);
        acc.z = fmaf(b.z, wb, acc.z); acc.w = fmaf(b.w, wb, acc.w);
    }
    if (i < e1) {
        int sa = csr_se[i].x;
        float wa = coef[i];
        float4 a = *(const float4*)&h[(size_t)sa * 128 + l * 4];
        acc.x = fmaf(a.x, wa, acc.x); acc.y = fmaf(a.y, wa, acc.y);
        acc.z = fmaf(a.z, wa, acc.z); acc.w = fmaf(a.w, wa, acc.w);
    }
    __shared__ float4 red[4][32];
    red[s][l] = acc;
    __syncthreads();
    if (threadIdx.x < 32) {
        float4 r0 = red[0][l], r1 = red[1][l], r2 = red[2][l], r3 = red[3][l];
        float dv = dinv[v];
        float4 hv = *(const float4*)&h[(size_t)v * 128 + l * 4];
        float4 bb = *(const float4*)&bias[l * 4];
        float4 o;
        o.x = dv * ((r0.x + r1.x + r2.x + r3.x) + hv.x * dv) + bb.x;
        o.y = dv * ((r0.y + r1.y + r2.y + r3.y) + hv.y * dv) + bb.y;
        o.z = dv * ((r0.z + r1.z + r2.z + r3.z) + hv.z * dv) + bb.z;
        o.w = dv * ((r0.w + r1.w + r2.w + r3.w) + hv.w * dv) + bb.w;
        if (RELU) {
            o.x = fmaxf(o.x, 0.f); o.y = fmaxf(o.y, 0.f);
            o.z = fmaxf(o.z, 0.f); o.w = fmaxf(o.w, 0.f);
        }
        *(float4*)&out[(size_t)v * 128 + l * 4] = o;
    }
}

__global__ __launch_bounds__(128) void k_agg64(const float* __restrict__ h,
                                               const int* __restrict__ csr_off,
                                               const int2* __restrict__ csr_se,
                                               const float* __restrict__ coef,
                                               const float* __restrict__ dinv,
                                               const float* __restrict__ bias,
                                               float* __restrict__ out, int N) {
    const int v = blockIdx.x;
    const int l = threadIdx.x & 15;
    const int s = threadIdx.x >> 4;  // 0..7
    const int e0 = csr_off[v];
    const int e1 = csr_off[v + 1];
    float4 acc = make_float4(0.f, 0.f, 0.f, 0.f);
    int i = e0 + s;
    for (; i + 8 < e1; i += 16) {
        int sa = csr_se[i].x;      float wa = coef[i];
        int sb = csr_se[i + 8].x;  float wb = coef[i + 8];
        float4 a = *(const float4*)&h[(size_t)sa * 64 + l * 4];
        float4 b = *(const float4*)&h[(size_t)sb * 64 + l * 4];
        acc.x = fmaf(a.x, wa, acc.x); acc.y = fmaf(a.y, wa, acc.y);
        acc.z = fmaf(a.z, wa, acc.z); acc.w = fmaf(a.w, wa, acc.w);
        acc.x = fmaf(b.x, wb, acc.x); acc.y = fmaf(b.y, wb, acc.y);
        acc.z = fmaf(b.z, wb, acc.z); acc.w = fmaf(b.w, wb, acc.w);
    }
    if (i < e1) {
        int sa = csr_se[i].x;
        float wa = coef[i];
        float4 a = *(const float4*)&h[(size_t)sa * 64 + l * 4];
        acc.x = fmaf(a.x, wa, acc.x); acc.y = fmaf(a.y, wa, acc.y);
        acc.z = fmaf(a.z, wa, acc.z); acc.w = fmaf(a.w, wa, acc.w);
    }
    __shared__ float4 red[8][16];
    red[s][l] = acc;
    __syncthreads();
    if (threadIdx.x < 16) {
        float4 aa = make_float4(0.f, 0.f, 0.f, 0.f);
#pragma unroll
        for (int k = 0; k < 8; ++k) {
            float4 r = red[k][l];
            aa.x += r.x; aa.y += r.y; aa.z += r.z; aa.w += r.w;
        }
        float dv = dinv[v];
        float4 hv = *(const float4*)&h[(size_t)v * 64 + l * 4];
        float4 bb = *(const float4*)&bias[l * 4];
        float4 o;
        o.x = dv * (aa.x + hv.x * dv) + bb.x;
        o.y = dv * (aa.y + hv.y * dv) + bb.y;
        o.z = dv * (aa.z + hv.z * dv) + bb.z;
        o.w = dv * (aa.w + hv.w * dv) + bb.w;
        *(float4*)&out[(size_t)v * 64 + l * 4] = o;
    }
}

// ---------------- bf16-gather aggregations (pass 2, post-mask) -------------
template <bool RELU>
__global__ __launch_bounds__(128) void k_agg128b(const unsigned short* __restrict__ h,
                                                 const int* __restrict__ csr_off,
                                                 const int2* __restrict__ csr_se,
                                                 const float* __restrict__ coef,
                                                 const float* __restrict__ dinv,
                                                 const float* __restrict__ bias,
                                                 unsigned short* __restrict__ out, int N) {
    const int v = blockIdx.x;
    const int l = threadIdx.x & 15;  // 8-feature group
    const int s = threadIdx.x >> 4;  // 0..7 edge slot
    const int e0 = csr_off[v];
    const int e1 = csr_off[v + 1];
    float acc[8];
#pragma unroll
    for (int j = 0; j < 8; j++) acc[j] = 0.f;
    int i = e0 + s;
    for (; i + 8 < e1; i += 16) {
        int sa = csr_se[i].x;      float wa = coef[i];
        int sb = csr_se[i + 8].x;  float wb = coef[i + 8];
        uint4 ua = *(const uint4*)&h[(size_t)sa * 128 + l * 8];
        uint4 ub = *(const uint4*)&h[(size_t)sb * 128 + l * 8];
        float f0, f1;
        unpack2(ua.x, f0, f1); acc[0] = fmaf(f0, wa, acc[0]); acc[1] = fmaf(f1, wa, acc[1]);
        unpack2(ua.y, f0, f1); acc[2] = fmaf(f0, wa, acc[2]); acc[3] = fmaf(f1, wa, acc[3]);
        unpack2(ua.z, f0, f1); acc[4] = fmaf(f0, wa, acc[4]); acc[5] = fmaf(f1, wa, acc[5]);
        unpack2(ua.w, f0, f1); acc[6] = fmaf(f0, wa, acc[6]); acc[7] = fmaf(f1, wa, acc[7]);
        unpack2(ub.x, f0, f1); acc[0] = fmaf(f0, wb, acc[0]); acc[1] = fmaf(f1, wb, acc[1]);
        unpack2(ub.y, f0, f1); acc[2] = fmaf(f0, wb, acc[2]); acc[3] = fmaf(f1, wb, acc[3]);
        unpack2(ub.z, f0, f1); acc[4] = fmaf(f0, wb, acc[4]); acc[5] = fmaf(f1, wb, acc[5]);
        unpack2(ub.w, f0, f1); acc[6] = fmaf(f0, wb, acc[6]); acc[7] = fmaf(f1, wb, acc[7]);
    }
    if (i < e1) {
        int sa = csr_se[i].x;
        float wa = coef[i];
        uint4 ua = *(const uint4*)&h[(size_t)sa * 128 + l * 8];
        float f0, f1;
        unpack2(ua.x, f0, f1); acc[0] = fmaf(f0, wa, acc[0]); acc[1] = fmaf(f1, wa, acc[1]);
        unpack2(ua.y, f0, f1); acc[2] = fmaf(f0, wa, acc[2]); acc[3] = fmaf(f1, wa, acc[3]);
        unpack2(ua.z, f0, f1); acc[4] = fmaf(f0, wa, acc[4]); acc[5] = fmaf(f1, wa, acc[5]);
        unpack2(ua.w, f0, f1); acc[6] = fmaf(f0, wa, acc[6]); acc[7] = fmaf(f1, wa, acc[7]);
    }
    __shared__ float red[8][16][8];
#pragma unroll
    for (int j = 0; j < 8; j += 4)
        *(float4*)&red[s][l][j] = make_float4(acc[j], acc[j + 1], acc[j + 2], acc[j + 3]);
    __syncthreads();
    if (threadIdx.x < 16) {
        int ll = threadIdx.x;
        float rr[8];
#pragma unroll
        for (int j = 0; j < 8; j++) rr[j] = 0.f;
#pragma unroll
        for (int k = 0; k < 8; ++k)
#pragma unroll
            for (int j = 0; j < 8; j++) rr[j] += red[k][ll][j];
        float dv = dinv[v];
        uint4 uh = *(const uint4*)&h[(size_t)v * 128 + ll * 8];
        float hv[8];
        unpack2(uh.x, hv[0], hv[1]); unpack2(uh.y, hv[2], hv[3]);
        unpack2(uh.z, hv[4], hv[5]); unpack2(uh.w, hv[6], hv[7]);
        unsigned u[4];
#pragma unroll
        for (int j2 = 0; j2 < 4; j2++) {
            float o0 = dv * (rr[2 * j2 + 0] + hv[2 * j2 + 0] * dv) + bias[ll * 8 + 2 * j2 + 0];
            float o1 = dv * (rr[2 * j2 + 1] + hv[2 * j2 + 1] * dv) + bias[ll * 8 + 2 * j2 + 1];
            if (RELU) { o0 = fmaxf(o0, 0.f); o1 = fmaxf(o1, 0.f); }
            u[j2] = bfpair(o0, o1);
        }
        *(uint4*)&out[(size_t)v * 128 + ll * 8] = make_uint4(u[0], u[1], u[2], u[3]);
    }
}

__global__ __launch_bounds__(128) void k_agg64b(const unsigned short* __restrict__ h,
                                                const int* __restrict__ csr_off,
                                                const int2* __restrict__ csr_se,
                                                const float* __restrict__ coef,
                                                const float* __restrict__ dinv,
                                                const float* __restrict__ bias,
                                                float* __restrict__ out, int N) {
    const int v = blockIdx.x;
    const int l = threadIdx.x & 7;   // 8-feature group
    const int s = threadIdx.x >> 3;  // 0..15 edge slot
    const int e0 = csr_off[v];
    const int e1 = csr_off[v + 1];
    float acc[8];
#pragma unroll
    for (int j = 0; j < 8; j++) acc[j] = 0.f;
    for (int i = e0 + s; i < e1; i += 16) {
        int sa = csr_se[i].x;
        float wa = coef[i];
        uint4 ua = *(const uint4*)&h[(size_t)sa * 64 + l * 8];
        float f0, f1;
        unpack2(ua.x, f0, f1); acc[0] = fmaf(f0, wa, acc[0]); acc[1] = fmaf(f1, wa, acc[1]);
        unpack2(ua.y, f0, f1); acc[2] = fmaf(f0, wa, acc[2]); acc[3] = fmaf(f1, wa, acc[3]);
        unpack2(ua.z, f0, f1); acc[4] = fmaf(f0, wa, acc[4]); acc[5] = fmaf(f1, wa, acc[5]);
        unpack2(ua.w, f0, f1); acc[6] = fmaf(f0, wa, acc[6]); acc[7] = fmaf(f1, wa, acc[7]);
    }
    __shared__ float red[16][8][8];
#pragma unroll
    for (int j = 0; j < 8; j += 4)
        *(float4*)&red[s][l][j] = make_float4(acc[j], acc[j + 1], acc[j + 2], acc[j + 3]);
    __syncthreads();
    if (threadIdx.x < 8) {
        int ll = threadIdx.x;
        float rr[8];
#pragma unroll
        for (int j = 0; j < 8; j++) rr[j] = 0.f;
#pragma unroll
        for (int k = 0; k < 16; ++k)
#pragma unroll
            for (int j = 0; j < 8; j++) rr[j] += red[k][ll][j];
        float dv = dinv[v];
        uint4 uh = *(const uint4*)&h[(size_t)v * 64 + ll * 8];
        float hv[8];
        unpack2(uh.x, hv[0], hv[1]); unpack2(uh.y, hv[2], hv[3]);
        unpack2(uh.z, hv[4], hv[5]); unpack2(uh.w, hv[6], hv[7]);
        float o[8];
#pragma unroll
        for (int j = 0; j < 8; j++) o[j] = dv * (rr[j] + hv[j] * dv) + bias[ll * 8 + j];
        *(float4*)&out[(size_t)v * 64 + ll * 8 + 0] = make_float4(o[0], o[1], o[2], o[3]);
        *(float4*)&out[(size_t)v * 64 + ll * 8 + 4] = make_float4(o[4], o[5], o[6], o[7]);
    }
}

extern "C" void kernel_launch(void* const* d_in, const int* in_sizes, int n_in,
                              void* d_out, int out_size, void* d_ws, size_t ws_size,
                              hipStream_t stream) {
    const float* x  = (const float*)d_in[0];
    const int*   ei = (const int*)d_in[1];
    const float* er = (const float*)d_in[2];
    const float* w0 = (const float*)d_in[3];
    const float* b0 = (const float*)d_in[4];
    const float* w1 = (const float*)d_in[5];
    const float* b1 = (const float*)d_in[6];
    const float* w2 = (const float*)d_in[7];
    const float* b2 = (const float*)d_in[8];
    const int N = in_sizes[0] / 128;
    const int E = in_sizes[2];
    const int* src  = ei;
    const int* dstv = ei + E;
    float* out = (float*)d_out;

    // workspace carve
    char* p = (char*)d_ws;
    auto alloc = [&](size_t bytes) {
        char* r = p;
        p += (bytes + 255) & ~(size_t)255;
        return r;
    };
    int* indeg     = (int*)alloc((size_t)N * 4);
    int* cursor    = (int*)alloc((size_t)N * 4);
    int* degm      = (int*)alloc((size_t)N * 4);
    int* csr_off   = (int*)alloc((size_t)(N + 1) * 4);
    int* bsums     = (int*)alloc(1024);
    int2* csr_se   = (int2*)alloc((size_t)E * 8);
    float* coefF   = (float*)alloc((size_t)E * 4);
    float* coefM   = (float*)alloc((size_t)E * 4);
    float* survive = (float*)alloc((size_t)E * 4);
    float* dinvF   = (float*)alloc((size_t)N * 4);
    float* dinvM   = (float*)alloc((size_t)N * 4);
    float* hx      = (float*)alloc((size_t)N * 128 * 4);  // x@w0 f32 (pass1)
    unsigned short* hxb = (unsigned short*)alloc((size_t)N * 128 * 2);  // x@w0 bf16 (pass2)
    float* wk1     = (float*)alloc((size_t)N * 128 * 4);
    float* wk2     = (float*)alloc((size_t)N * 128 * 4);
    float* tz      = (float*)alloc((size_t)N * 64 * 4);
    unsigned short* w0p3 = (unsigned short*)alloc((size_t)3 * 128 * 128 * 2);
    unsigned short* w1p3 = (unsigned short*)alloc((size_t)3 * 128 * 128 * 2);
    unsigned short* w2p3 = (unsigned short*)alloc((size_t)3 * 128 * 64 * 2);
    unsigned short* w1pk = (unsigned short*)alloc((size_t)128 * 128 * 2);
    unsigned short* w2pk = (unsigned short*)alloc((size_t)128 * 64 * 2);
    unsigned short* wk1b = (unsigned short*)wk1;  // pass2 alias
    unsigned short* wk2b = (unsigned short*)wk2;  // pass2 alias

    hipMemsetAsync(indeg, 0, (size_t)N * 4, stream);
    hipMemsetAsync(cursor, 0, (size_t)N * 4, stream);

    const int TB = 256;
    const int ebk = (E + TB - 1) / TB;
    const int nbk = (N + TB - 1) / TB;
    const int nb = (N + 255) / 256;

    // weight packs
    k_packw3<<<8, 256, 0, stream>>>(w0, w0p3, 128, 2048);
    k_packw3<<<8, 256, 0, stream>>>(w1, w1p3, 128, 2048);
    k_packw3<<<4, 256, 0, stream>>>(w2, w2p3, 64, 1024);
    k_packw<<<8, 256, 0, stream>>>(w1, w1pk, 128, 2048);
    k_packw<<<4, 256, 0, stream>>>(w2, w2pk, 64, 1024);

    // CSR build
    k_hist<<<ebk, TB, 0, stream>>>(dstv, indeg, E);
    k_scan1<<<nb, 256, 0, stream>>>(indeg, csr_off, bsums, N);
    k_scan2<<<1, 256, 0, stream>>>(bsums, nb);
    k_scan3<<<nb, 256, 0, stream>>>(csr_off, bsums, N, E);
    k_fill<<<ebk, TB, 0, stream>>>(src, dstv, er, csr_off, cursor, csr_se, E);
    k_dinv<<<nbk, TB, 0, stream>>>(indeg, dinvF, N);
    k_coef_full<<<ebk, TB, 0, stream>>>(csr_se, dinvF, coefF, E);

    const int gbm = (N + 63) / 64;

    // shared first GEMM: f32 (pass1) + bf16 copy (pass2)
    k_gemm_split<128, true><<<gbm, 256, 0, stream>>>(x, w0p3, hx, hxb, N);

    // pass 1 (full graph, near-exact -> tz -> mask)
    k_agg128<true><<<N, 128, 0, stream>>>(hx, csr_off, csr_se, coefF, dinvF, b0, wk1, N);
    k_gemm_split<128, false><<<gbm, 256, 0, stream>>>(wk1, w1p3, wk2, nullptr, N);
    k_agg128<true><<<N, 128, 0, stream>>>(wk2, csr_off, csr_se, coefF, dinvF, b1, wk1, N);
    k_gemm_split<64, false><<<gbm, 256, 0, stream>>>(wk1, w2p3, wk2, nullptr, N);
    k_agg64<<<N, 128, 0, stream>>>(wk2, csr_off, csr_se, coefF, dinvF, b2, tz, N);

    // edge sampling in CSR order (no atomics, sequential survive writes)
    k_surv<<<N, 128, 0, stream>>>(tz, csr_off, csr_se, survive, degm, N);
    k_dinv<<<nbk, TB, 0, stream>>>(degm, dinvM, N);
    k_coef_mask<<<ebk, TB, 0, stream>>>(csr_se, dinvM, survive, coefM, E);

    // pass 2 (post-mask: bf16 gathers + bf16 MFMA GEMMs)
    k_agg128b<true><<<N, 128, 0, stream>>>(hxb, csr_off, csr_se, coefM, dinvM, b0, wk1b, N);
    k_gemm_mfma<128><<<gbm, 256, 0, stream>>>(wk1b, w1pk, wk2b, N);
    k_agg128b<true><<<N, 128, 0, stream>>>(wk2b, csr_off, csr_se, coefM, dinvM, b1, wk1b, N);
    k_gemm_mfma<64><<<gbm, 256, 0, stream>>>(wk1b, w2pk, wk2b, N);
    k_agg64b<<<N, 128, 0, stream>>>(wk2b, csr_off, csr_se, coefF, dinvF, b2, out, N);
}

// Round 7
// 507.984 us; speedup vs baseline: 1.2631x; 1.0337x over previous
//
#include <hip/hip_runtime.h>

// ---------------------------------------------------------------------------
// GCN with edge sampling.
//  Pass 1 (-> tz -> mask) uses split-bf16 MFMA GEMMs (3-plane Ozaki split,
//  8 cross terms, error ~2^-25) + exact f32 aggs -> mask bit-stable.
//  Pass 2 (post-mask) is bf16 end-to-end.
//  CSR build: bucket-radix (bucket = dst>>6), LDS atomics only (no global
//  atomics): count -> scan -> scatter to staging -> per-bucket indeg ->
//  scan -> fill (bucket owns its 64 dsts exclusively). coefF folded in.
// conv: out[v] = dinv[v]*(sum_e h[src]*coef[e] + h[v]*dinv[v]) + b
// ---------------------------------------------------------------------------

typedef __attribute__((ext_vector_type(8))) short bf16x8;
typedef __attribute__((ext_vector_type(4))) float f32x4;

__device__ inline unsigned bfpair(float lo, float hi) {   // pack 2 f32 -> bf16x2 RNE
    unsigned a = __float_as_uint(lo), b = __float_as_uint(hi);
    a = (a + 0x7FFFu + ((a >> 16) & 1u)) >> 16;
    b = (b + 0x7FFFu + ((b >> 16) & 1u)) & 0xFFFF0000u;
    return a | b;
}
__device__ inline unsigned short bf1(float v) {
    unsigned u = __float_as_uint(v);
    return (unsigned short)((u + 0x7FFFu + ((u >> 16) & 1u)) >> 16);
}
__device__ inline void unpack2(unsigned u, float& f0, float& f1) {
    f0 = __uint_as_float(u << 16);
    f1 = __uint_as_float(u & 0xFFFF0000u);
}

// ---------------- scans (generic, 256-wide) ----------------
__global__ void k_scan1(const int* __restrict__ in, int* __restrict__ out,
                        int* __restrict__ bsums, int N) {
    __shared__ int tmp[256];
    int i = blockIdx.x * 256 + threadIdx.x;
    int v = (i < N) ? in[i] : 0;
    tmp[threadIdx.x] = v;
    __syncthreads();
    for (int off = 1; off < 256; off <<= 1) {
        int t = (threadIdx.x >= off) ? tmp[threadIdx.x - off] : 0;
        __syncthreads();
        tmp[threadIdx.x] += t;
        __syncthreads();
    }
    if (i < N) out[i] = tmp[threadIdx.x] - v;   // exclusive
    if (threadIdx.x == 255) bsums[blockIdx.x] = tmp[255];
}

__global__ void k_scan2(int* __restrict__ bsums, int nb) {
    __shared__ int tmp[256];
    int v = (threadIdx.x < nb) ? bsums[threadIdx.x] : 0;
    tmp[threadIdx.x] = v;
    __syncthreads();
    for (int off = 1; off < 256; off <<= 1) {
        int t = (threadIdx.x >= off) ? tmp[threadIdx.x - off] : 0;
        __syncthreads();
        tmp[threadIdx.x] += t;
        __syncthreads();
    }
    if (threadIdx.x < nb) bsums[threadIdx.x] = tmp[threadIdx.x] - v;  // exclusive
}

__global__ void k_scan3(int* __restrict__ out, const int* __restrict__ bsums, int N, int E) {
    int i = blockIdx.x * 256 + threadIdx.x;
    if (i < N) out[i] += bsums[blockIdx.x];
    if (i == 0) out[N] = E;
}

// ---------------- bucket-radix CSR build (no global atomics) ----------------
// bucket = dst >> 6 (1024 buckets); 64 edge-chunk blocks.
__global__ __launch_bounds__(256) void k_bcount(const int* __restrict__ dst,
                                                int* __restrict__ cnt, int E, int chunk) {
    __shared__ int h[1024];
    for (int i = threadIdx.x; i < 1024; i += 256) h[i] = 0;
    __syncthreads();
    int beg = blockIdx.x * chunk, end = min(E, beg + chunk);
    for (int e = beg + threadIdx.x; e < end; e += 256)
        atomicAdd(&h[dst[e] >> 6], 1);
    __syncthreads();
    for (int b = threadIdx.x; b < 1024; b += 256)
        cnt[b * 64 + blockIdx.x] = h[b];
}

// staging payload: .x = src | (dst&63)<<16  (src < 65536), .y = er bits
__global__ __launch_bounds__(256) void k_bscatter(const int* __restrict__ src,
                                                  const int* __restrict__ dst,
                                                  const float* __restrict__ er,
                                                  const int* __restrict__ sbase,
                                                  int2* __restrict__ stg, int E, int chunk) {
    __shared__ int cur[1024];
    for (int i = threadIdx.x; i < 1024; i += 256) cur[i] = 0;
    __syncthreads();
    int beg = blockIdx.x * chunk, end = min(E, beg + chunk);
    for (int e = beg + threadIdx.x; e < end; e += 256) {
        int d = dst[e];
        int b = d >> 6;
        int loc = atomicAdd(&cur[b], 1);
        int pos = sbase[b * 64 + blockIdx.x] + loc;
        stg[pos] = make_int2(src[e] | ((d & 63) << 16), (int)__float_as_uint(er[e]));
    }
}

__global__ __launch_bounds__(256) void k_bindeg(const int2* __restrict__ stg,
                                                const int* __restrict__ sbase,
                                                int* __restrict__ indeg, int N) {
    __shared__ int cnt[64];
    if (threadIdx.x < 64) cnt[threadIdx.x] = 0;
    __syncthreads();
    int b = blockIdx.x;
    int beg = sbase[b * 64], end = sbase[(b + 1) * 64];
    for (int i = beg + threadIdx.x; i < end; i += 256)
        atomicAdd(&cnt[(stg[i].x >> 16) & 63], 1);
    __syncthreads();
    if (threadIdx.x < 64) {
        int node = b * 64 + threadIdx.x;
        if (node < N) indeg[node] = cnt[threadIdx.x];
    }
}

// bucket owns its 64 dst nodes exclusively -> LDS cursors give unique slots.
// also writes coefF = dinvF[src] (k_coef_full folded in).
__global__ __launch_bounds__(256) void k_bfill(const int2* __restrict__ stg,
                                               const int* __restrict__ sbase,
                                               const int* __restrict__ csr_off,
                                               const float* __restrict__ dinvF,
                                               int2* __restrict__ csr_se,
                                               float* __restrict__ coefF, int N) {
    __shared__ int cur[64];
    int b = blockIdx.x;
    if (threadIdx.x < 64) {
        int node = b * 64 + threadIdx.x;
        cur[threadIdx.x] = (node < N) ? csr_off[node] : 0;
    }
    __syncthreads();
    int beg = sbase[b * 64], end = sbase[(b + 1) * 64];
    for (int i = beg + threadIdx.x; i < end; i += 256) {
        int2 se = stg[i];
        int s = se.x & 0xFFFF;
        int j = (se.x >> 16) & 63;
        int pos = atomicAdd(&cur[j], 1);
        csr_se[pos] = make_int2(s, se.y);
        coefF[pos] = dinvF[s];
    }
}

__global__ void k_dinv(const int* __restrict__ deg, float* __restrict__ dinv, int N) {
    int i = blockIdx.x * blockDim.x + threadIdx.x;
    if (i < N) dinv[i] = 1.0f / sqrtf((float)deg[i] + 1.0f);
}

__global__ void k_coef_mask(const int2* __restrict__ csr_se, const float* __restrict__ dinv,
                            const float* __restrict__ survive, float* __restrict__ coef, int E) {
    int i = blockIdx.x * blockDim.x + threadIdx.x;
    if (i < E) coef[i] = dinv[csr_se[i].x] * survive[i];
}

// mask in CSR order: block per node, 8 edge slots x 16 lanes; tz[v] loaded once.
__global__ __launch_bounds__(128) void k_surv(const float* __restrict__ tz,
                                              const int* __restrict__ csr_off,
                                              const int2* __restrict__ csr_se,
                                              float* __restrict__ survive,
                                              int* __restrict__ degm, int N) {
    const int v = blockIdx.x;
    const int l = threadIdx.x & 15;
    const int s = threadIdx.x >> 4;
    const int e0 = csr_off[v];
    const int e1 = csr_off[v + 1];
    const float4 tv = *(const float4*)&tz[(size_t)v * 64 + l * 4];
    int cnt = 0;
    for (int i = e0 + s; i < e1; i += 8) {
        int2 se = csr_se[i];
        const float4 a = *(const float4*)&tz[(size_t)se.x * 64 + l * 4];
        float p = a.x * tv.x + a.y * tv.y + a.z * tv.z + a.w * tv.w;
        p += __shfl_xor(p, 1, 16);
        p += __shfl_xor(p, 2, 16);
        p += __shfl_xor(p, 4, 16);
        p += __shfl_xor(p, 8, 16);
        float sg = 1.0f / (1.0f + expf(-p));
        float m = (sg > __uint_as_float((unsigned)se.y)) ? 1.0f : 0.0f;
        if (l == 0) {
            survive[i] = m;
            cnt += (m != 0.0f) ? 1 : 0;
        }
    }
    __shared__ int sc[8];
    if (l == 0) sc[s] = cnt;
    __syncthreads();
    if (threadIdx.x == 0) {
        int t = 0;
#pragma unroll
        for (int k = 0; k < 8; k++) t += sc[k];
        degm[v] = t;
    }
}

// pack W -> 3 bf16 split planes (plane 0 = bf16(W), reused by pass-2 GEMMs)
__global__ void k_packw3(const float* __restrict__ W, unsigned short* __restrict__ Wp,
                         int OUTC, int total) {
    int idx = blockIdx.x * 256 + threadIdx.x;
    if (idx >= total) return;
    int l = idx & 63;
    int tk = idx >> 6;
    int kb = tk & 3;
    int ct = tk >> 2;
    size_t PL = (size_t)(OUTC / 16) * 4 * 64 * 8;
    unsigned short v0[8], v1[8], v2[8];
#pragma unroll
    for (int i = 0; i < 8; i++) {
        float wv = W[(kb * 32 + ((l >> 4) * 8) + i) * OUTC + ct * 16 + (l & 15)];
        unsigned short h0 = bf1(wv);
        float f0 = __uint_as_float((unsigned)h0 << 16);
        float r1 = wv - f0;
        unsigned short h1 = bf1(r1);
        float f1 = __uint_as_float((unsigned)h1 << 16);
        unsigned short h2 = bf1(r1 - f1);
        v0[i] = h0; v1[i] = h1; v2[i] = h2;
    }
    auto st = [](unsigned short* dst, unsigned short* v) {
        uint4 u;
        u.x = v[0] | ((unsigned)v[1] << 16);
        u.y = v[2] | ((unsigned)v[3] << 16);
        u.z = v[4] | ((unsigned)v[5] << 16);
        u.w = v[6] | ((unsigned)v[7] << 16);
        *(uint4*)dst = u;
    };
    st(&Wp[(size_t)idx * 8], v0);
    st(&Wp[PL + (size_t)idx * 8], v1);
    st(&Wp[2 * PL + (size_t)idx * 8], v2);
}

// split-bf16 MFMA GEMM (pass 1): C[N][OUTC] = A[N][128] x W, A f32 split
// on the fly into 3 bf16 planes; 8 cross-term MFMAs per k-block; f32 out
// (+ optional bf16 copy). Error ~2^-25 (< f32 summation-order noise).
template <int OUTC, bool WB16>
__global__ __launch_bounds__(256) void k_gemm_split(const float* __restrict__ A,
                                                    const unsigned short* __restrict__ Wp,
                                                    float* __restrict__ Cout,
                                                    unsigned short* __restrict__ Cb, int N) {
    constexpr int CT = OUTC / 16;
    constexpr int PL = CT * 4 * 64 * 8;
    constexpr int LDW = OUTC + 4;           // pad: 2-way LDS aliasing only
    __shared__ float eps[64 * LDW];
    const int w = threadIdx.x >> 6;
    const int l = threadIdx.x & 63;
    int row = blockIdx.x * 64 + w * 16 + (l & 15);
    int rowc = (row < N) ? row : (N - 1);

    bf16x8 a0[4], a1[4], a2[4];
#pragma unroll
    for (int kb = 0; kb < 4; kb++) {
        const float* pa = &A[(size_t)rowc * 128 + kb * 32 + ((l >> 4) * 8)];
        float4 x0 = *(const float4*)pa;
        float4 x1 = *(const float4*)(pa + 4);
        float xa[8] = {x0.x, x0.y, x0.z, x0.w, x1.x, x1.y, x1.z, x1.w};
#pragma unroll
        for (int i = 0; i < 8; i++) {
            unsigned short h0 = bf1(xa[i]);
            float f0 = __uint_as_float((unsigned)h0 << 16);
            float r1 = xa[i] - f0;
            unsigned short h1 = bf1(r1);
            float f1 = __uint_as_float((unsigned)h1 << 16);
            unsigned short h2 = bf1(r1 - f1);
            a0[kb][i] = (short)h0;
            a1[kb][i] = (short)h1;
            a2[kb][i] = (short)h2;
        }
    }
#pragma unroll
    for (int ct = 0; ct < CT; ct++) {
        f32x4 accA = {0.f, 0.f, 0.f, 0.f};
        f32x4 accB = {0.f, 0.f, 0.f, 0.f};
#pragma unroll
        for (int kb = 0; kb < 4; kb++) {
            const size_t bo = ((size_t)(ct * 4 + kb) * 64 + l) * 8;
            bf16x8 b0 = *(const bf16x8*)&Wp[bo];
            bf16x8 b1 = *(const bf16x8*)&Wp[PL + bo];
            bf16x8 b2 = *(const bf16x8*)&Wp[2 * PL + bo];
            accA = __builtin_amdgcn_mfma_f32_16x16x32_bf16(a0[kb], b0, accA, 0, 0, 0);
            accB = __builtin_amdgcn_mfma_f32_16x16x32_bf16(a0[kb], b1, accB, 0, 0, 0);
            accA = __builtin_amdgcn_mfma_f32_16x16x32_bf16(a1[kb], b0, accA, 0, 0, 0);
            accB = __builtin_amdgcn_mfma_f32_16x16x32_bf16(a0[kb], b2, accB, 0, 0, 0);
            accA = __builtin_amdgcn_mfma_f32_16x16x32_bf16(a1[kb], b1, accA, 0, 0, 0);
            accB = __builtin_amdgcn_mfma_f32_16x16x32_bf16(a2[kb], b0, accB, 0, 0, 0);
            accA = __builtin_amdgcn_mfma_f32_16x16x32_bf16(a1[kb], b2, accA, 0, 0, 0);
            accB = __builtin_amdgcn_mfma_f32_16x16x32_bf16(a2[kb], b1, accB, 0, 0, 0);
        }
        // C/D map: col = lane&15, row = (lane>>4)*4 + r  [HW-verified]
#pragma unroll
        for (int r = 0; r < 4; r++) {
            int rr = w * 16 + (l >> 4) * 4 + r;
            eps[rr * LDW + ct * 16 + (l & 15)] = accA[r] + accB[r];
        }
    }
    __syncthreads();
    constexpr int NF4 = 64 * OUTC / 4;
    for (int idx = threadIdx.x; idx < NF4; idx += 256) {
        int rl = idx / (OUTC / 4);
        int cg = idx % (OUTC / 4);
        int grow = blockIdx.x * 64 + rl;
        if (grow < N) {
            const float* sp = &eps[rl * LDW + cg * 4];
            float4 vv = make_float4(sp[0], sp[1], sp[2], sp[3]);
            *(float4*)&Cout[(size_t)grow * OUTC + cg * 4] = vv;
            if (WB16)
                *(uint2*)&Cb[(size_t)grow * OUTC + cg * 4] =
                    make_uint2(bfpair(vv.x, vv.y), bfpair(vv.z, vv.w));
        }
    }
}

// plain bf16 MFMA GEMM (pass 2): A bf16, Wpk = plane 0 of packw3, bf16 out.
template <int OUTC>
__global__ __launch_bounds__(256) void k_gemm_mfma(const unsigned short* __restrict__ A,
                                                   const unsigned short* __restrict__ Wpk,
                                                   unsigned short* __restrict__ C, int N) {
    constexpr int CT = OUTC / 16;
    __shared__ unsigned short eps[64 * OUTC];
    const int w = threadIdx.x >> 6;
    const int l = threadIdx.x & 63;
    const int rowl = (w * 16) + (l & 15);
    int row = blockIdx.x * 64 + rowl;
    int rowc = (row < N) ? row : (N - 1);

    bf16x8 a[4];
#pragma unroll
    for (int kb = 0; kb < 4; kb++)
        a[kb] = *(const bf16x8*)&A[(size_t)rowc * 128 + kb * 32 + ((l >> 4) * 8)];

#pragma unroll
    for (int ct = 0; ct < CT; ct++) {
        f32x4 acc = {0.f, 0.f, 0.f, 0.f};
#pragma unroll
        for (int kb = 0; kb < 4; kb++) {
            bf16x8 b = *(const bf16x8*)&Wpk[((size_t)(ct * 4 + kb) * 64 + l) * 8];
            acc = __builtin_amdgcn_mfma_f32_16x16x32_bf16(a[kb], b, acc, 0, 0, 0);
        }
#pragma unroll
        for (int r = 0; r < 4; r++) {
            int rr = w * 16 + (l >> 4) * 4 + r;
            eps[rr * OUTC + ct * 16 + (l & 15)] = bf1(acc[r]);
        }
    }
    __syncthreads();
    constexpr int NU4 = 64 * OUTC / 8;
    for (int idx = threadIdx.x; idx < NU4; idx += 256) {
        int rl = idx / (OUTC / 8);
        int cg = idx % (OUTC / 8);
        int grow = blockIdx.x * 64 + rl;
        if (grow < N)
            *(uint4*)&C[(size_t)grow * OUTC + cg * 8] = *(const uint4*)&eps[rl * OUTC + cg * 8];
    }
}

// ---------------- fp32 aggregations (pass 1, mask-critical) ----------------
template <bool RELU>
__global__ __launch_bounds__(128) void k_agg128(const float* __restrict__ h,
                                                const int* __restrict__ csr_off,
                                                const int2* __restrict__ csr_se,
                                                const float* __restrict__ coef,
                                                const float* __restrict__ dinv,
                                                const float* __restrict__ bias,
                                                float* __restrict__ out, int N) {
    const int v = blockIdx.x;
    const int l = threadIdx.x & 31;
    const int s = threadIdx.x >> 5;  // 0..3
    const int e0 = csr_off[v];
    const int e1 = csr_off[v + 1];
    float4 acc = make_float4(0.f, 0.f, 0.f, 0.f);
    int i = e0 + s;
    for (; i + 4 < e1; i += 8) {
        int sa = csr_se[i].x;      float wa = coef[i];
        int sb = csr_se[i + 4].x;  float wb = coef[i + 4];
        float4 a = *(const float4*)&h[(size_t)sa * 128 + l * 4];
        float4 b = *(const float4*)&h[(size_t)sb * 128 + l * 4];
        acc.x = fmaf(a.x, wa, acc.x); acc.y = fmaf(a.y, wa, acc.y);
        acc.z = fmaf(a.z, wa, acc.z); acc.w = fmaf(a.w, wa, acc.w);
        acc.x = fmaf(b.x, wb, acc.x); acc.y = fmaf(b.y, wb, acc.y);
        acc.z = fmaf(b.z, wb, acc.z); acc.w = fmaf(b.w, wb, acc.w);
    }
    if (i < e1) {
        int sa = csr_se[i].x;
        float wa = coef[i];
        float4 a = *(const float4*)&h[(size_t)sa * 128 + l * 4];
        acc.x = fmaf(a.x, wa, acc.x); acc.y = fmaf(a.y, wa, acc.y);
        acc.z = fmaf(a.z, wa, acc.z); acc.w = fmaf(a.w, wa, acc.w);
    }
    __shared__ float4 red[4][32];
    red[s][l] = acc;
    __syncthreads();
    if (threadIdx.x < 32) {
        float4 r0 = red[0][l], r1 = red[1][l], r2 = red[2][l], r3 = red[3][l];
        float dv = dinv[v];
        float4 hv = *(const float4*)&h[(size_t)v * 128 + l * 4];
        float4 bb = *(const float4*)&bias[l * 4];
        float4 o;
        o.x = dv * ((r0.x + r1.x + r2.x + r3.x) + hv.x * dv) + bb.x;
        o.y = dv * ((r0.y + r1.y + r2.y + r3.y) + hv.y * dv) + bb.y;
        o.z = dv * ((r0.z + r1.z + r2.z + r3.z) + hv.z * dv) + bb.z;
        o.w = dv * ((r0.w + r1.w + r2.w + r3.w) + hv.w * dv) + bb.w;
        if (RELU) {
            o.x = fmaxf(o.x, 0.f); o.y = fmaxf(o.y, 0.f);
            o.z = fmaxf(o.z, 0.f); o.w = fmaxf(o.w, 0.f);
        }
        *(float4*)&out[(size_t)v * 128 + l * 4] = o;
    }
}

__global__ __launch_bounds__(128) void k_agg64(const float* __restrict__ h,
                                               const int* __restrict__ csr_off,
                                               const int2* __restrict__ csr_se,
                                               const float* __restrict__ coef,
                                               const float* __restrict__ dinv,
                                               const float* __restrict__ bias,
                                               float* __restrict__ out, int N) {
    const int v = blockIdx.x;
    const int l = threadIdx.x & 15;
    const int s = threadIdx.x >> 4;  // 0..7
    const int e0 = csr_off[v];
    const int e1 = csr_off[v + 1];
    float4 acc = make_float4(0.f, 0.f, 0.f, 0.f);
    int i = e0 + s;
    for (; i + 8 < e1; i += 16) {
        int sa = csr_se[i].x;      float wa = coef[i];
        int sb = csr_se[i + 8].x;  float wb = coef[i + 8];
        float4 a = *(const float4*)&h[(size_t)sa * 64 + l * 4];
        float4 b = *(const float4*)&h[(size_t)sb * 64 + l * 4];
        acc.x = fmaf(a.x, wa, acc.x); acc.y = fmaf(a.y, wa, acc.y);
        acc.z = fmaf(a.z, wa, acc.z); acc.w = fmaf(a.w, wa, acc.w);
        acc.x = fmaf(b.x, wb, acc.x); acc.y = fmaf(b.y, wb, acc.y);
        acc.z = fmaf(b.z, wb, acc.z); acc.w = fmaf(b.w, wb, acc.w);
    }
    if (i < e1) {
        int sa = csr_se[i].x;
        float wa = coef[i];
        float4 a = *(const float4*)&h[(size_t)sa * 64 + l * 4];
        acc.x = fmaf(a.x, wa, acc.x); acc.y = fmaf(a.y, wa, acc.y);
        acc.z = fmaf(a.z, wa, acc.z); acc.w = fmaf(a.w, wa, acc.w);
    }
    __shared__ float4 red[8][16];
    red[s][l] = acc;
    __syncthreads();
    if (threadIdx.x < 16) {
        float4 aa = make_float4(0.f, 0.f, 0.f, 0.f);
#pragma unroll
        for (int k = 0; k < 8; ++k) {
            float4 r = red[k][l];
            aa.x += r.x; aa.y += r.y; aa.z += r.z; aa.w += r.w;
        }
        float dv = dinv[v];
        float4 hv = *(const float4*)&h[(size_t)v * 64 + l * 4];
        float4 bb = *(const float4*)&bias[l * 4];
        float4 o;
        o.x = dv * (aa.x + hv.x * dv) + bb.x;
        o.y = dv * (aa.y + hv.y * dv) + bb.y;
        o.z = dv * (aa.z + hv.z * dv) + bb.z;
        o.w = dv * (aa.w + hv.w * dv) + bb.w;
        *(float4*)&out[(size_t)v * 64 + l * 4] = o;
    }
}

// ---------------- bf16-gather aggregations (pass 2, post-mask) -------------
template <bool RELU>
__global__ __launch_bounds__(128) void k_agg128b(const unsigned short* __restrict__ h,
                                                 const int* __restrict__ csr_off,
                                                 const int2* __restrict__ csr_se,
                                                 const float* __restrict__ coef,
                                                 const float* __restrict__ dinv,
                                                 const float* __restrict__ bias,
                                                 unsigned short* __restrict__ out, int N) {
    const int v = blockIdx.x;
    const int l = threadIdx.x & 15;  // 8-feature group
    const int s = threadIdx.x >> 4;  // 0..7 edge slot
    const int e0 = csr_off[v];
    const int e1 = csr_off[v + 1];
    float acc[8];
#pragma unroll
    for (int j = 0; j < 8; j++) acc[j] = 0.f;
    int i = e0 + s;
    for (; i + 8 < e1; i += 16) {
        int sa = csr_se[i].x;      float wa = coef[i];
        int sb = csr_se[i + 8].x;  float wb = coef[i + 8];
        uint4 ua = *(const uint4*)&h[(size_t)sa * 128 + l * 8];
        uint4 ub = *(const uint4*)&h[(size_t)sb * 128 + l * 8];
        float f0, f1;
        unpack2(ua.x, f0, f1); acc[0] = fmaf(f0, wa, acc[0]); acc[1] = fmaf(f1, wa, acc[1]);
        unpack2(ua.y, f0, f1); acc[2] = fmaf(f0, wa, acc[2]); acc[3] = fmaf(f1, wa, acc[3]);
        unpack2(ua.z, f0, f1); acc[4] = fmaf(f0, wa, acc[4]); acc[5] = fmaf(f1, wa, acc[5]);
        unpack2(ua.w, f0, f1); acc[6] = fmaf(f0, wa, acc[6]); acc[7] = fmaf(f1, wa, acc[7]);
        unpack2(ub.x, f0, f1); acc[0] = fmaf(f0, wb, acc[0]); acc[1] = fmaf(f1, wb, acc[1]);
        unpack2(ub.y, f0, f1); acc[2] = fmaf(f0, wb, acc[2]); acc[3] = fmaf(f1, wb, acc[3]);
        unpack2(ub.z, f0, f1); acc[4] = fmaf(f0, wb, acc[4]); acc[5] = fmaf(f1, wb, acc[5]);
        unpack2(ub.w, f0, f1); acc[6] = fmaf(f0, wb, acc[6]); acc[7] = fmaf(f1, wb, acc[7]);
    }
    if (i < e1) {
        int sa = csr_se[i].x;
        float wa = coef[i];
        uint4 ua = *(const uint4*)&h[(size_t)sa * 128 + l * 8];
        float f0, f1;
        unpack2(ua.x, f0, f1); acc[0] = fmaf(f0, wa, acc[0]); acc[1] = fmaf(f1, wa, acc[1]);
        unpack2(ua.y, f0, f1); acc[2] = fmaf(f0, wa, acc[2]); acc[3] = fmaf(f1, wa, acc[3]);
        unpack2(ua.z, f0, f1); acc[4] = fmaf(f0, wa, acc[4]); acc[5] = fmaf(f1, wa, acc[5]);
        unpack2(ua.w, f0, f1); acc[6] = fmaf(f0, wa, acc[6]); acc[7] = fmaf(f1, wa, acc[7]);
    }
    __shared__ float red[8][16][8];
#pragma unroll
    for (int j = 0; j < 8; j += 4)
        *(float4*)&red[s][l][j] = make_float4(acc[j], acc[j + 1], acc[j + 2], acc[j + 3]);
    __syncthreads();
    if (threadIdx.x < 16) {
        int ll = threadIdx.x;
        float rr[8];
#pragma unroll
        for (int j = 0; j < 8; j++) rr[j] = 0.f;
#pragma unroll
        for (int k = 0; k < 8; ++k)
#pragma unroll
            for (int j = 0; j < 8; j++) rr[j] += red[k][ll][j];
        float dv = dinv[v];
        uint4 uh = *(const uint4*)&h[(size_t)v * 128 + ll * 8];
        float hv[8];
        unpack2(uh.x, hv[0], hv[1]); unpack2(uh.y, hv[2], hv[3]);
        unpack2(uh.z, hv[4], hv[5]); unpack2(uh.w, hv[6], hv[7]);
        unsigned u[4];
#pragma unroll
        for (int j2 = 0; j2 < 4; j2++) {
            float o0 = dv * (rr[2 * j2 + 0] + hv[2 * j2 + 0] * dv) + bias[ll * 8 + 2 * j2 + 0];
            float o1 = dv * (rr[2 * j2 + 1] + hv[2 * j2 + 1] * dv) + bias[ll * 8 + 2 * j2 + 1];
            if (RELU) { o0 = fmaxf(o0, 0.f); o1 = fmaxf(o1, 0.f); }
            u[j2] = bfpair(o0, o1);
        }
        *(uint4*)&out[(size_t)v * 128 + ll * 8] = make_uint4(u[0], u[1], u[2], u[3]);
    }
}

__global__ __launch_bounds__(128) void k_agg64b(const unsigned short* __restrict__ h,
                                                const int* __restrict__ csr_off,
                                                const int2* __restrict__ csr_se,
                                                const float* __restrict__ coef,
                                                const float* __restrict__ dinv,
                                                const float* __restrict__ bias,
                                                float* __restrict__ out, int N) {
    const int v = blockIdx.x;
    const int l = threadIdx.x & 7;   // 8-feature group
    const int s = threadIdx.x >> 3;  // 0..15 edge slot
    const int e0 = csr_off[v];
    const int e1 = csr_off[v + 1];
    float acc[8];
#pragma unroll
    for (int j = 0; j < 8; j++) acc[j] = 0.f;
    for (int i = e0 + s; i < e1; i += 16) {
        int sa = csr_se[i].x;
        float wa = coef[i];
        uint4 ua = *(const uint4*)&h[(size_t)sa * 64 + l * 8];
        float f0, f1;
        unpack2(ua.x, f0, f1); acc[0] = fmaf(f0, wa, acc[0]); acc[1] = fmaf(f1, wa, acc[1]);
        unpack2(ua.y, f0, f1); acc[2] = fmaf(f0, wa, acc[2]); acc[3] = fmaf(f1, wa, acc[3]);
        unpack2(ua.z, f0, f1); acc[4] = fmaf(f0, wa, acc[4]); acc[5] = fmaf(f1, wa, acc[5]);
        unpack2(ua.w, f0, f1); acc[6] = fmaf(f0, wa, acc[6]); acc[7] = fmaf(f1, wa, acc[7]);
    }
    __shared__ float red[16][8][8];
#pragma unroll
    for (int j = 0; j < 8; j += 4)
        *(float4*)&red[s][l][j] = make_float4(acc[j], acc[j + 1], acc[j + 2], acc[j + 3]);
    __syncthreads();
    if (threadIdx.x < 8) {
        int ll = threadIdx.x;
        float rr[8];
#pragma unroll
        for (int j = 0; j < 8; j++) rr[j] = 0.f;
#pragma unroll
        for (int k = 0; k < 16; ++k)
#pragma unroll
            for (int j = 0; j < 8; j++) rr[j] += red[k][ll][j];
        float dv = dinv[v];
        uint4 uh = *(const uint4*)&h[(size_t)v * 64 + ll * 8];
        float hv[8];
        unpack2(uh.x, hv[0], hv[1]); unpack2(uh.y, hv[2], hv[3]);
        unpack2(uh.z, hv[4], hv[5]); unpack2(uh.w, hv[6], hv[7]);
        float o[8];
#pragma unroll
        for (int j = 0; j < 8; j++) o[j] = dv * (rr[j] + hv[j] * dv) + bias[ll * 8 + j];
        *(float4*)&out[(size_t)v * 64 + ll * 8 + 0] = make_float4(o[0], o[1], o[2], o[3]);
        *(float4*)&out[(size_t)v * 64 + ll * 8 + 4] = make_float4(o[4], o[5], o[6], o[7]);
    }
}

extern "C" void kernel_launch(void* const* d_in, const int* in_sizes, int n_in,
                              void* d_out, int out_size, void* d_ws, size_t ws_size,
                              hipStream_t stream) {
    const float* x  = (const float*)d_in[0];
    const int*   ei = (const int*)d_in[1];
    const float* er = (const float*)d_in[2];
    const float* w0 = (const float*)d_in[3];
    const float* b0 = (const float*)d_in[4];
    const float* w1 = (const float*)d_in[5];
    const float* b1 = (const float*)d_in[6];
    const float* w2 = (const float*)d_in[7];
    const float* b2 = (const float*)d_in[8];
    const int N = in_sizes[0] / 128;
    const int E = in_sizes[2];
    const int* src  = ei;
    const int* dstv = ei + E;
    float* out = (float*)d_out;

    // workspace carve
    char* p = (char*)d_ws;
    auto alloc = [&](size_t bytes) {
        char* r = p;
        p += (bytes + 255) & ~(size_t)255;
        return r;
    };
    int* indeg     = (int*)alloc((size_t)N * 4);
    int* degm      = (int*)alloc((size_t)N * 4);
    int* csr_off   = (int*)alloc((size_t)(N + 1) * 4);
    int* bsums     = (int*)alloc(1024);
    int* bcnt      = (int*)alloc((size_t)65536 * 4);
    int* sbase     = (int*)alloc((size_t)65537 * 4);
    int2* csr_se   = (int2*)alloc((size_t)E * 8);
    int2* stg      = (int2*)alloc((size_t)E * 8);   // staging; later aliased
    float* coefF   = (float*)alloc((size_t)E * 4);
    float* dinvF   = (float*)alloc((size_t)N * 4);
    float* dinvM   = (float*)alloc((size_t)N * 4);
    float* hx      = (float*)alloc((size_t)N * 128 * 4);  // x@w0 f32 (pass1)
    unsigned short* hxb = (unsigned short*)alloc((size_t)N * 128 * 2);  // x@w0 bf16 (pass2)
    float* wk1     = (float*)alloc((size_t)N * 128 * 4);
    float* wk2     = (float*)alloc((size_t)N * 128 * 4);
    float* tz      = (float*)alloc((size_t)N * 64 * 4);
    unsigned short* w0p3 = (unsigned short*)alloc((size_t)3 * 128 * 128 * 2);
    unsigned short* w1p3 = (unsigned short*)alloc((size_t)3 * 128 * 128 * 2);
    unsigned short* w2p3 = (unsigned short*)alloc((size_t)3 * 128 * 64 * 2);
    unsigned short* wk1b = (unsigned short*)wk1;  // pass2 alias
    unsigned short* wk2b = (unsigned short*)wk2;  // pass2 alias
    float* coefM   = (float*)stg;                 // stg dead after k_bfill
    float* survive = (float*)stg + E;

    const int TB = 256;
    const int ebk = (E + TB - 1) / TB;
    const int nbk = (N + TB - 1) / TB;
    const int nb = (N + 255) / 256;
    const int chunk = (E + 63) / 64;

    // weight packs (plane 0 doubles as the pass-2 single-plane pack)
    k_packw3<<<8, 256, 0, stream>>>(w0, w0p3, 128, 2048);
    k_packw3<<<8, 256, 0, stream>>>(w1, w1p3, 128, 2048);
    k_packw3<<<4, 256, 0, stream>>>(w2, w2p3, 64, 1024);

    // ---- bucket-radix CSR build (no global atomics) ----
    k_bcount<<<64, 256, 0, stream>>>(dstv, bcnt, E, chunk);
    k_scan1<<<256, 256, 0, stream>>>(bcnt, sbase, bsums, 65536);
    k_scan2<<<1, 256, 0, stream>>>(bsums, 256);
    k_scan3<<<256, 256, 0, stream>>>(sbase, bsums, 65536, E);
    k_bscatter<<<64, 256, 0, stream>>>(src, dstv, er, sbase, stg, E, chunk);
    k_bindeg<<<1024, 256, 0, stream>>>(stg, sbase, indeg, N);
    k_scan1<<<nb, 256, 0, stream>>>(indeg, csr_off, bsums, N);
    k_scan2<<<1, 256, 0, stream>>>(bsums, nb);
    k_scan3<<<nb, 256, 0, stream>>>(csr_off, bsums, N, E);
    k_dinv<<<nbk, TB, 0, stream>>>(indeg, dinvF, N);
    k_bfill<<<1024, 256, 0, stream>>>(stg, sbase, csr_off, dinvF, csr_se, coefF, N);

    const int gbm = (N + 63) / 64;

    // shared first GEMM: f32 (pass1) + bf16 copy (pass2)
    k_gemm_split<128, true><<<gbm, 256, 0, stream>>>(x, w0p3, hx, hxb, N);

    // pass 1 (full graph, near-exact -> tz -> mask)
    k_agg128<true><<<N, 128, 0, stream>>>(hx, csr_off, csr_se, coefF, dinvF, b0, wk1, N);
    k_gemm_split<128, false><<<gbm, 256, 0, stream>>>(wk1, w1p3, wk2, nullptr, N);
    k_agg128<true><<<N, 128, 0, stream>>>(wk2, csr_off, csr_se, coefF, dinvF, b1, wk1, N);
    k_gemm_split<64, false><<<gbm, 256, 0, stream>>>(wk1, w2p3, wk2, nullptr, N);
    k_agg64<<<N, 128, 0, stream>>>(wk2, csr_off, csr_se, coefF, dinvF, b2, tz, N);

    // edge sampling in CSR order (no atomics, sequential survive writes)
    k_surv<<<N, 128, 0, stream>>>(tz, csr_off, csr_se, survive, degm, N);
    k_dinv<<<nbk, TB, 0, stream>>>(degm, dinvM, N);
    k_coef_mask<<<ebk, TB, 0, stream>>>(csr_se, dinvM, survive, coefM, E);

    // pass 2 (post-mask: bf16 gathers + bf16 MFMA GEMMs, plane-0 weights)
    k_agg128b<true><<<N, 128, 0, stream>>>(hxb, csr_off, csr_se, coefM, dinvM, b0, wk1b, N);
    k_gemm_mfma<128><<<gbm, 256, 0, stream>>>(wk1b, w1p3, wk2b, N);
    k_agg128b<true><<<N, 128, 0, stream>>>(wk2b, csr_off, csr_se, coefM, dinvM, b1, wk1b, N);
    k_gemm_mfma<64><<<gbm, 256, 0, stream>>>(wk1b, w2p3, wk2b, N);
    k_agg64b<<<N, 128, 0, stream>>>(wk2b, csr_off, csr_se, coefF, dinvF, b2, out, N);
}

// Round 8
// 491.966 us; speedup vs baseline: 1.3042x; 1.0326x over previous
//
#include <hip/hip_runtime.h>

// ---------------------------------------------------------------------------
// GCN with edge sampling.
//  Pass 1 (-> tz -> mask) uses split-bf16 MFMA GEMMs (3-plane Ozaki split,
//  6 cross terms, error ~2^-26) + exact f32 aggs -> mask bit-stable.
//  Pass 2 (post-mask) is bf16 end-to-end.
//  CSR build: bucket-radix (bucket = dst>>6), LDS atomics only.
//  No coef arrays: aggs read dinv tables (L2-resident) inline.
// conv: out[v] = dinv[v]*(sum_e h[src]*dinv[src]*m[e] + h[v]*dinv[v]) + b
// ---------------------------------------------------------------------------

typedef __attribute__((ext_vector_type(8))) short bf16x8;
typedef __attribute__((ext_vector_type(4))) float f32x4;

__device__ inline unsigned bfpair(float lo, float hi) {   // pack 2 f32 -> bf16x2 RNE
    unsigned a = __float_as_uint(lo), b = __float_as_uint(hi);
    a = (a + 0x7FFFu + ((a >> 16) & 1u)) >> 16;
    b = (b + 0x7FFFu + ((b >> 16) & 1u)) & 0xFFFF0000u;
    return a | b;
}
__device__ inline unsigned short bf1(float v) {
    unsigned u = __float_as_uint(v);
    return (unsigned short)((u + 0x7FFFu + ((u >> 16) & 1u)) >> 16);
}
__device__ inline void unpack2(unsigned u, float& f0, float& f1) {
    f0 = __uint_as_float(u << 16);
    f1 = __uint_as_float(u & 0xFFFF0000u);
}

// ---------------- scans (generic, 256-wide) ----------------
__global__ void k_scan1(const int* __restrict__ in, int* __restrict__ out,
                        int* __restrict__ bsums, int N) {
    __shared__ int tmp[256];
    int i = blockIdx.x * 256 + threadIdx.x;
    int v = (i < N) ? in[i] : 0;
    tmp[threadIdx.x] = v;
    __syncthreads();
    for (int off = 1; off < 256; off <<= 1) {
        int t = (threadIdx.x >= off) ? tmp[threadIdx.x - off] : 0;
        __syncthreads();
        tmp[threadIdx.x] += t;
        __syncthreads();
    }
    if (i < N) out[i] = tmp[threadIdx.x] - v;   // exclusive
    if (threadIdx.x == 255) bsums[blockIdx.x] = tmp[255];
}

__global__ void k_scan2(int* __restrict__ bsums, int nb) {
    __shared__ int tmp[256];
    int v = (threadIdx.x < nb) ? bsums[threadIdx.x] : 0;
    tmp[threadIdx.x] = v;
    __syncthreads();
    for (int off = 1; off < 256; off <<= 1) {
        int t = (threadIdx.x >= off) ? tmp[threadIdx.x - off] : 0;
        __syncthreads();
        tmp[threadIdx.x] += t;
        __syncthreads();
    }
    if (threadIdx.x < nb) bsums[threadIdx.x] = tmp[threadIdx.x] - v;  // exclusive
}

__global__ void k_scan3(int* __restrict__ out, const int* __restrict__ bsums, int N, int E) {
    int i = blockIdx.x * 256 + threadIdx.x;
    if (i < N) out[i] += bsums[blockIdx.x];
    if (i == 0) out[N] = E;
}

// ---------------- bucket-radix CSR build (no global atomics) ----------------
__global__ __launch_bounds__(256) void k_bcount(const int* __restrict__ dst,
                                                int* __restrict__ cnt, int E, int chunk) {
    __shared__ int h[1024];
    for (int i = threadIdx.x; i < 1024; i += 256) h[i] = 0;
    __syncthreads();
    int beg = blockIdx.x * chunk, end = min(E, beg + chunk);
    for (int e = beg + threadIdx.x; e < end; e += 256)
        atomicAdd(&h[dst[e] >> 6], 1);
    __syncthreads();
    for (int b = threadIdx.x; b < 1024; b += 256)
        cnt[b * 64 + blockIdx.x] = h[b];
}

// staging payload: .x = src | (dst&63)<<16  (src < 65536), .y = er bits
__global__ __launch_bounds__(256) void k_bscatter(const int* __restrict__ src,
                                                  const int* __restrict__ dst,
                                                  const float* __restrict__ er,
                                                  const int* __restrict__ sbase,
                                                  int2* __restrict__ stg, int E, int chunk) {
    __shared__ int cur[1024];
    for (int i = threadIdx.x; i < 1024; i += 256) cur[i] = 0;
    __syncthreads();
    int beg = blockIdx.x * chunk, end = min(E, beg + chunk);
    for (int e = beg + threadIdx.x; e < end; e += 256) {
        int d = dst[e];
        int b = d >> 6;
        int loc = atomicAdd(&cur[b], 1);
        int pos = sbase[b * 64 + blockIdx.x] + loc;
        stg[pos] = make_int2(src[e] | ((d & 63) << 16), (int)__float_as_uint(er[e]));
    }
}

// per-bucket indeg + dinvF (k_dinv folded in)
__global__ __launch_bounds__(256) void k_bindeg(const int2* __restrict__ stg,
                                                const int* __restrict__ sbase,
                                                int* __restrict__ indeg,
                                                float* __restrict__ dinvF, int N) {
    __shared__ int cnt[64];
    if (threadIdx.x < 64) cnt[threadIdx.x] = 0;
    __syncthreads();
    int b = blockIdx.x;
    int beg = sbase[b * 64], end = sbase[(b + 1) * 64];
    for (int i = beg + threadIdx.x; i < end; i += 256)
        atomicAdd(&cnt[(stg[i].x >> 16) & 63], 1);
    __syncthreads();
    if (threadIdx.x < 64) {
        int node = b * 64 + threadIdx.x;
        if (node < N) {
            int c = cnt[threadIdx.x];
            indeg[node] = c;
            dinvF[node] = 1.0f / sqrtf((float)c + 1.0f);
        }
    }
}

// bucket owns its 64 dst nodes exclusively -> LDS cursors give unique slots.
__global__ __launch_bounds__(256) void k_bfill(const int2* __restrict__ stg,
                                               const int* __restrict__ sbase,
                                               const int* __restrict__ csr_off,
                                               int2* __restrict__ csr_se, int N) {
    __shared__ int cur[64];
    int b = blockIdx.x;
    if (threadIdx.x < 64) {
        int node = b * 64 + threadIdx.x;
        cur[threadIdx.x] = (node < N) ? csr_off[node] : 0;
    }
    __syncthreads();
    int beg = sbase[b * 64], end = sbase[(b + 1) * 64];
    for (int i = beg + threadIdx.x; i < end; i += 256) {
        int2 se = stg[i];
        int j = (se.x >> 16) & 63;
        int pos = atomicAdd(&cur[j], 1);
        csr_se[pos] = make_int2(se.x & 0xFFFF, se.y);
    }
}

// mask in CSR order: block per node; also writes dinvM (k_dinv folded in).
__global__ __launch_bounds__(128) void k_surv(const float* __restrict__ tz,
                                              const int* __restrict__ csr_off,
                                              const int2* __restrict__ csr_se,
                                              float* __restrict__ survive,
                                              float* __restrict__ dinvM, int N) {
    const int v = blockIdx.x;
    const int l = threadIdx.x & 15;
    const int s = threadIdx.x >> 4;
    const int e0 = csr_off[v];
    const int e1 = csr_off[v + 1];
    const float4 tv = *(const float4*)&tz[(size_t)v * 64 + l * 4];
    int cnt = 0;
    for (int i = e0 + s; i < e1; i += 8) {
        int2 se = csr_se[i];
        const float4 a = *(const float4*)&tz[(size_t)se.x * 64 + l * 4];
        float p = a.x * tv.x + a.y * tv.y + a.z * tv.z + a.w * tv.w;
        p += __shfl_xor(p, 1, 16);
        p += __shfl_xor(p, 2, 16);
        p += __shfl_xor(p, 4, 16);
        p += __shfl_xor(p, 8, 16);
        float sg = 1.0f / (1.0f + expf(-p));
        float m = (sg > __uint_as_float((unsigned)se.y)) ? 1.0f : 0.0f;
        if (l == 0) {
            survive[i] = m;
            cnt += (m != 0.0f) ? 1 : 0;
        }
    }
    __shared__ int sc[8];
    if (l == 0) sc[s] = cnt;
    __syncthreads();
    if (threadIdx.x == 0) {
        int t = 0;
#pragma unroll
        for (int k = 0; k < 8; k++) t += sc[k];
        dinvM[v] = 1.0f / sqrtf((float)t + 1.0f);
    }
}

// pack W -> 3 bf16 split planes (plane 0 = bf16(W), reused by pass-2 GEMMs)
__device__ inline void packw3_one(const float* __restrict__ W, unsigned short* __restrict__ Wp,
                                  int OUTC, int idx) {
    int l = idx & 63;
    int tk = idx >> 6;
    int kb = tk & 3;
    int ct = tk >> 2;
    size_t PL = (size_t)(OUTC / 16) * 4 * 64 * 8;
    unsigned short v0[8], v1[8], v2[8];
#pragma unroll
    for (int i = 0; i < 8; i++) {
        float wv = W[(kb * 32 + ((l >> 4) * 8) + i) * OUTC + ct * 16 + (l & 15)];
        unsigned short h0 = bf1(wv);
        float f0 = __uint_as_float((unsigned)h0 << 16);
        float r1 = wv - f0;
        unsigned short h1 = bf1(r1);
        float f1 = __uint_as_float((unsigned)h1 << 16);
        unsigned short h2 = bf1(r1 - f1);
        v0[i] = h0; v1[i] = h1; v2[i] = h2;
    }
    auto st = [](unsigned short* dst, unsigned short* v) {
        uint4 u;
        u.x = v[0] | ((unsigned)v[1] << 16);
        u.y = v[2] | ((unsigned)v[3] << 16);
        u.z = v[4] | ((unsigned)v[5] << 16);
        u.w = v[6] | ((unsigned)v[7] << 16);
        *(uint4*)dst = u;
    };
    st(&Wp[(size_t)idx * 8], v0);
    st(&Wp[PL + (size_t)idx * 8], v1);
    st(&Wp[2 * PL + (size_t)idx * 8], v2);
}

__global__ void k_packw3_all(const float* __restrict__ w0, const float* __restrict__ w1,
                             const float* __restrict__ w2,
                             unsigned short* __restrict__ w0p, unsigned short* __restrict__ w1p,
                             unsigned short* __restrict__ w2p) {
    int b = blockIdx.x;
    if (b < 8) packw3_one(w0, w0p, 128, b * 256 + threadIdx.x);
    else if (b < 16) packw3_one(w1, w1p, 128, (b - 8) * 256 + threadIdx.x);
    else packw3_one(w2, w2p, 64, (b - 16) * 256 + threadIdx.x);
}

// split-bf16 MFMA GEMM (pass 1): 6 cross terms (00,10,20 | 01,11,02),
// error ~2^-26. f32 out (+ optional bf16 copy).
template <int OUTC, bool WB16>
__global__ __launch_bounds__(256) void k_gemm_split(const float* __restrict__ A,
                                                    const unsigned short* __restrict__ Wp,
                                                    float* __restrict__ Cout,
                                                    unsigned short* __restrict__ Cb, int N) {
    constexpr int CT = OUTC / 16;
    constexpr int PL = CT * 4 * 64 * 8;
    constexpr int LDW = OUTC + 4;
    __shared__ float eps[64 * LDW];
    const int w = threadIdx.x >> 6;
    const int l = threadIdx.x & 63;
    int row = blockIdx.x * 64 + w * 16 + (l & 15);
    int rowc = (row < N) ? row : (N - 1);

    bf16x8 a0[4], a1[4], a2[4];
#pragma unroll
    for (int kb = 0; kb < 4; kb++) {
        const float* pa = &A[(size_t)rowc * 128 + kb * 32 + ((l >> 4) * 8)];
        float4 x0 = *(const float4*)pa;
        float4 x1 = *(const float4*)(pa + 4);
        float xa[8] = {x0.x, x0.y, x0.z, x0.w, x1.x, x1.y, x1.z, x1.w};
#pragma unroll
        for (int i = 0; i < 8; i++) {
            unsigned short h0 = bf1(xa[i]);
            float f0 = __uint_as_float((unsigned)h0 << 16);
            float r1 = xa[i] - f0;
            unsigned short h1 = bf1(r1);
            float f1 = __uint_as_float((unsigned)h1 << 16);
            unsigned short h2 = bf1(r1 - f1);
            a0[kb][i] = (short)h0;
            a1[kb][i] = (short)h1;
            a2[kb][i] = (short)h2;
        }
    }
#pragma unroll
    for (int ct = 0; ct < CT; ct++) {
        f32x4 accA = {0.f, 0.f, 0.f, 0.f};
        f32x4 accB = {0.f, 0.f, 0.f, 0.f};
#pragma unroll
        for (int kb = 0; kb < 4; kb++) {
            const size_t bo = ((size_t)(ct * 4 + kb) * 64 + l) * 8;
            bf16x8 b0 = *(const bf16x8*)&Wp[bo];
            bf16x8 b1 = *(const bf16x8*)&Wp[PL + bo];
            bf16x8 b2 = *(const bf16x8*)&Wp[2 * PL + bo];
            accA = __builtin_amdgcn_mfma_f32_16x16x32_bf16(a0[kb], b0, accA, 0, 0, 0);
            accB = __builtin_amdgcn_mfma_f32_16x16x32_bf16(a0[kb], b1, accB, 0, 0, 0);
            accA = __builtin_amdgcn_mfma_f32_16x16x32_bf16(a1[kb], b0, accA, 0, 0, 0);
            accB = __builtin_amdgcn_mfma_f32_16x16x32_bf16(a1[kb], b1, accB, 0, 0, 0);
            accA = __builtin_amdgcn_mfma_f32_16x16x32_bf16(a2[kb], b0, accA, 0, 0, 0);
            accB = __builtin_amdgcn_mfma_f32_16x16x32_bf16(a0[kb], b2, accB, 0, 0, 0);
        }
        // C/D map: col = lane&15, row = (lane>>4)*4 + r  [HW-verified]
#pragma unroll
        for (int r = 0; r < 4; r++) {
            int rr = w * 16 + (l >> 4) * 4 + r;
            eps[rr * LDW + ct * 16 + (l & 15)] = accA[r] + accB[r];
        }
    }
    __syncthreads();
    constexpr int NF4 = 64 * OUTC / 4;
    for (int idx = threadIdx.x; idx < NF4; idx += 256) {
        int rl = idx / (OUTC / 4);
        int cg = idx % (OUTC / 4);
        int grow = blockIdx.x * 64 + rl;
        if (grow < N) {
            const float* sp = &eps[rl * LDW + cg * 4];
            float4 vv = make_float4(sp[0], sp[1], sp[2], sp[3]);
            *(float4*)&Cout[(size_t)grow * OUTC + cg * 4] = vv;
            if (WB16)
                *(uint2*)&Cb[(size_t)grow * OUTC + cg * 4] =
                    make_uint2(bfpair(vv.x, vv.y), bfpair(vv.z, vv.w));
        }
    }
}

// plain bf16 MFMA GEMM (pass 2): A bf16, Wpk = plane 0 of packw3, bf16 out.
template <int OUTC>
__global__ __launch_bounds__(256) void k_gemm_mfma(const unsigned short* __restrict__ A,
                                                   const unsigned short* __restrict__ Wpk,
                                                   unsigned short* __restrict__ C, int N) {
    constexpr int CT = OUTC / 16;
    __shared__ unsigned short eps[64 * OUTC];
    const int w = threadIdx.x >> 6;
    const int l = threadIdx.x & 63;
    const int rowl = (w * 16) + (l & 15);
    int row = blockIdx.x * 64 + rowl;
    int rowc = (row < N) ? row : (N - 1);

    bf16x8 a[4];
#pragma unroll
    for (int kb = 0; kb < 4; kb++)
        a[kb] = *(const bf16x8*)&A[(size_t)rowc * 128 + kb * 32 + ((l >> 4) * 8)];

#pragma unroll
    for (int ct = 0; ct < CT; ct++) {
        f32x4 acc = {0.f, 0.f, 0.f, 0.f};
#pragma unroll
        for (int kb = 0; kb < 4; kb++) {
            bf16x8 b = *(const bf16x8*)&Wpk[((size_t)(ct * 4 + kb) * 64 + l) * 8];
            acc = __builtin_amdgcn_mfma_f32_16x16x32_bf16(a[kb], b, acc, 0, 0, 0);
        }
#pragma unroll
        for (int r = 0; r < 4; r++) {
            int rr = w * 16 + (l >> 4) * 4 + r;
            eps[rr * OUTC + ct * 16 + (l & 15)] = bf1(acc[r]);
        }
    }
    __syncthreads();
    constexpr int NU4 = 64 * OUTC / 8;
    for (int idx = threadIdx.x; idx < NU4; idx += 256) {
        int rl = idx / (OUTC / 8);
        int cg = idx % (OUTC / 8);
        int grow = blockIdx.x * 64 + rl;
        if (grow < N)
            *(uint4*)&C[(size_t)grow * OUTC + cg * 8] = *(const uint4*)&eps[rl * OUTC + cg * 8];
    }
}

// ---------------- fp32 aggregations (pass 1, mask-critical) ----------------
// edge coef = dinv[src], read inline (bit-identical to old coefF).
template <bool RELU>
__global__ __launch_bounds__(128) void k_agg128(const float* __restrict__ h,
                                                const int* __restrict__ csr_off,
                                                const int2* __restrict__ csr_se,
                                                const float* __restrict__ dinv,
                                                const float* __restrict__ bias,
                                                float* __restrict__ out, int N) {
    const int v = blockIdx.x;
    const int l = threadIdx.x & 31;
    const int s = threadIdx.x >> 5;  // 0..3
    const int e0 = csr_off[v];
    const int e1 = csr_off[v + 1];
    float4 acc = make_float4(0.f, 0.f, 0.f, 0.f);
    int i = e0 + s;
    for (; i + 4 < e1; i += 8) {
        int sa = csr_se[i].x;      float wa = dinv[sa];
        int sb = csr_se[i + 4].x;  float wb = dinv[sb];
        float4 a = *(const float4*)&h[(size_t)sa * 128 + l * 4];
        float4 b = *(const float4*)&h[(size_t)sb * 128 + l * 4];
        acc.x = fmaf(a.x, wa, acc.x); acc.y = fmaf(a.y, wa, acc.y);
        acc.z = fmaf(a.z, wa, acc.z); acc.w = fmaf(a.w, wa, acc.w);
        acc.x = fmaf(b.x, wb, acc.x); acc.y = fmaf(b.y, wb, acc.y);
        acc.z = fmaf(b.z, wb, acc.z); acc.w = fmaf(b.w, wb, acc.w);
    }
    if (i < e1) {
        int sa = csr_se[i].x;
        float wa = dinv[sa];
        float4 a = *(const float4*)&h[(size_t)sa * 128 + l * 4];
        acc.x = fmaf(a.x, wa, acc.x); acc.y = fmaf(a.y, wa, acc.y);
        acc.z = fmaf(a.z, wa, acc.z); acc.w = fmaf(a.w, wa, acc.w);
    }
    __shared__ float4 red[4][32];
    red[s][l] = acc;
    __syncthreads();
    if (threadIdx.x < 32) {
        float4 r0 = red[0][l], r1 = red[1][l], r2 = red[2][l], r3 = red[3][l];
        float dv = dinv[v];
        float4 hv = *(const float4*)&h[(size_t)v * 128 + l * 4];
        float4 bb = *(const float4*)&bias[l * 4];
        float4 o;
        o.x = dv * ((r0.x + r1.x + r2.x + r3.x) + hv.x * dv) + bb.x;
        o.y = dv * ((r0.y + r1.y + r2.y + r3.y) + hv.y * dv) + bb.y;
        o.z = dv * ((r0.z + r1.z + r2.z + r3.z) + hv.z * dv) + bb.z;
        o.w = dv * ((r0.w + r1.w + r2.w + r3.w) + hv.w * dv) + bb.w;
        if (RELU) {
            o.x = fmaxf(o.x, 0.f); o.y = fmaxf(o.y, 0.f);
            o.z = fmaxf(o.z, 0.f); o.w = fmaxf(o.w, 0.f);
        }
        *(float4*)&out[(size_t)v * 128 + l * 4] = o;
    }
}

__global__ __launch_bounds__(128) void k_agg64(const float* __restrict__ h,
                                               const int* __restrict__ csr_off,
                                               const int2* __restrict__ csr_se,
                                               const float* __restrict__ dinv,
                                               const float* __restrict__ bias,
                                               float* __restrict__ out, int N) {
    const int v = blockIdx.x;
    const int l = threadIdx.x & 15;
    const int s = threadIdx.x >> 4;  // 0..7
    const int e0 = csr_off[v];
    const int e1 = csr_off[v + 1];
    float4 acc = make_float4(0.f, 0.f, 0.f, 0.f);
    int i = e0 + s;
    for (; i + 8 < e1; i += 16) {
        int sa = csr_se[i].x;      float wa = dinv[sa];
        int sb = csr_se[i + 8].x;  float wb = dinv[sb];
        float4 a = *(const float4*)&h[(size_t)sa * 64 + l * 4];
        float4 b = *(const float4*)&h[(size_t)sb * 64 + l * 4];
        acc.x = fmaf(a.x, wa, acc.x); acc.y = fmaf(a.y, wa, acc.y);
        acc.z = fmaf(a.z, wa, acc.z); acc.w = fmaf(a.w, wa, acc.w);
        acc.x = fmaf(b.x, wb, acc.x); acc.y = fmaf(b.y, wb, acc.y);
        acc.z = fmaf(b.z, wb, acc.z); acc.w = fmaf(b.w, wb, acc.w);
    }
    if (i < e1) {
        int sa = csr_se[i].x;
        float wa = dinv[sa];
        float4 a = *(const float4*)&h[(size_t)sa * 64 + l * 4];
        acc.x = fmaf(a.x, wa, acc.x); acc.y = fmaf(a.y, wa, acc.y);
        acc.z = fmaf(a.z, wa, acc.z); acc.w = fmaf(a.w, wa, acc.w);
    }
    __shared__ float4 red[8][16];
    red[s][l] = acc;
    __syncthreads();
    if (threadIdx.x < 16) {
        float4 aa = make_float4(0.f, 0.f, 0.f, 0.f);
#pragma unroll
        for (int k = 0; k < 8; ++k) {
            float4 r = red[k][l];
            aa.x += r.x; aa.y += r.y; aa.z += r.z; aa.w += r.w;
        }
        float dv = dinv[v];
        float4 hv = *(const float4*)&h[(size_t)v * 64 + l * 4];
        float4 bb = *(const float4*)&bias[l * 4];
        float4 o;
        o.x = dv * (aa.x + hv.x * dv) + bb.x;
        o.y = dv * (aa.y + hv.y * dv) + bb.y;
        o.z = dv * (aa.z + hv.z * dv) + bb.z;
        o.w = dv * (aa.w + hv.w * dv) + bb.w;
        *(float4*)&out[(size_t)v * 64 + l * 4] = o;
    }
}

// ---------------- bf16-gather aggregations (pass 2, post-mask) -------------
// MASKED: coef = dinv[src]*survive[i]; else coef = dinv[src].
template <bool RELU, bool MASKED>
__global__ __launch_bounds__(128) void k_agg128b(const unsigned short* __restrict__ h,
                                                 const int* __restrict__ csr_off,
                                                 const int2* __restrict__ csr_se,
                                                 const float* __restrict__ survive,
                                                 const float* __restrict__ dinv,
                                                 const float* __restrict__ bias,
                                                 unsigned short* __restrict__ out, int N) {
    const int v = blockIdx.x;
    const int l = threadIdx.x & 15;  // 8-feature group
    const int s = threadIdx.x >> 4;  // 0..7 edge slot
    const int e0 = csr_off[v];
    const int e1 = csr_off[v + 1];
    float acc[8];
#pragma unroll
    for (int j = 0; j < 8; j++) acc[j] = 0.f;
    int i = e0 + s;
    for (; i + 8 < e1; i += 16) {
        int sa = csr_se[i].x;
        int sb = csr_se[i + 8].x;
        float wa = MASKED ? dinv[sa] * survive[i] : dinv[sa];
        float wb = MASKED ? dinv[sb] * survive[i + 8] : dinv[sb];
        uint4 ua = *(const uint4*)&h[(size_t)sa * 128 + l * 8];
        uint4 ub = *(const uint4*)&h[(size_t)sb * 128 + l * 8];
        float f0, f1;
        unpack2(ua.x, f0, f1); acc[0] = fmaf(f0, wa, acc[0]); acc[1] = fmaf(f1, wa, acc[1]);
        unpack2(ua.y, f0, f1); acc[2] = fmaf(f0, wa, acc[2]); acc[3] = fmaf(f1, wa, acc[3]);
        unpack2(ua.z, f0, f1); acc[4] = fmaf(f0, wa, acc[4]); acc[5] = fmaf(f1, wa, acc[5]);
        unpack2(ua.w, f0, f1); acc[6] = fmaf(f0, wa, acc[6]); acc[7] = fmaf(f1, wa, acc[7]);
        unpack2(ub.x, f0, f1); acc[0] = fmaf(f0, wb, acc[0]); acc[1] = fmaf(f1, wb, acc[1]);
        unpack2(ub.y, f0, f1); acc[2] = fmaf(f0, wb, acc[2]); acc[3] = fmaf(f1, wb, acc[3]);
        unpack2(ub.z, f0, f1); acc[4] = fmaf(f0, wb, acc[4]); acc[5] = fmaf(f1, wb, acc[5]);
        unpack2(ub.w, f0, f1); acc[6] = fmaf(f0, wb, acc[6]); acc[7] = fmaf(f1, wb, acc[7]);
    }
    if (i < e1) {
        int sa = csr_se[i].x;
        float wa = MASKED ? dinv[sa] * survive[i] : dinv[sa];
        uint4 ua = *(const uint4*)&h[(size_t)sa * 128 + l * 8];
        float f0, f1;
        unpack2(ua.x, f0, f1); acc[0] = fmaf(f0, wa, acc[0]); acc[1] = fmaf(f1, wa, acc[1]);
        unpack2(ua.y, f0, f1); acc[2] = fmaf(f0, wa, acc[2]); acc[3] = fmaf(f1, wa, acc[3]);
        unpack2(ua.z, f0, f1); acc[4] = fmaf(f0, wa, acc[4]); acc[5] = fmaf(f1, wa, acc[5]);
        unpack2(ua.w, f0, f1); acc[6] = fmaf(f0, wa, acc[6]); acc[7] = fmaf(f1, wa, acc[7]);
    }
    __shared__ float red[8][16][8];
#pragma unroll
    for (int j = 0; j < 8; j += 4)
        *(float4*)&red[s][l][j] = make_float4(acc[j], acc[j + 1], acc[j + 2], acc[j + 3]);
    __syncthreads();
    if (threadIdx.x < 16) {
        int ll = threadIdx.x;
        float rr[8];
#pragma unroll
        for (int j = 0; j < 8; j++) rr[j] = 0.f;
#pragma unroll
        for (int k = 0; k < 8; ++k)
#pragma unroll
            for (int j = 0; j < 8; j++) rr[j] += red[k][ll][j];
        float dv = dinv[v];
        uint4 uh = *(const uint4*)&h[(size_t)v * 128 + ll * 8];
        float hv[8];
        unpack2(uh.x, hv[0], hv[1]); unpack2(uh.y, hv[2], hv[3]);
        unpack2(uh.z, hv[4], hv[5]); unpack2(uh.w, hv[6], hv[7]);
        unsigned u[4];
#pragma unroll
        for (int j2 = 0; j2 < 4; j2++) {
            float o0 = dv * (rr[2 * j2 + 0] + hv[2 * j2 + 0] * dv) + bias[ll * 8 + 2 * j2 + 0];
            float o1 = dv * (rr[2 * j2 + 1] + hv[2 * j2 + 1] * dv) + bias[ll * 8 + 2 * j2 + 1];
            if (RELU) { o0 = fmaxf(o0, 0.f); o1 = fmaxf(o1, 0.f); }
            u[j2] = bfpair(o0, o1);
        }
        *(uint4*)&out[(size_t)v * 128 + ll * 8] = make_uint4(u[0], u[1], u[2], u[3]);
    }
}

// final layer: full edges, coef = dinvF[src], f32 out.
__global__ __launch_bounds__(128) void k_agg64b(const unsigned short* __restrict__ h,
                                                const int* __restrict__ csr_off,
                                                const int2* __restrict__ csr_se,
                                                const float* __restrict__ dinv,
                                                const float* __restrict__ bias,
                                                float* __restrict__ out, int N) {
    const int v = blockIdx.x;
    const int l = threadIdx.x & 7;   // 8-feature group
    const int s = threadIdx.x >> 3;  // 0..15 edge slot
    const int e0 = csr_off[v];
    const int e1 = csr_off[v + 1];
    float acc[8];
#pragma unroll
    for (int j = 0; j < 8; j++) acc[j] = 0.f;
    for (int i = e0 + s; i < e1; i += 16) {
        int sa = csr_se[i].x;
        float wa = dinv[sa];
        uint4 ua = *(const uint4*)&h[(size_t)sa * 64 + l * 8];
        float f0, f1;
        unpack2(ua.x, f0, f1); acc[0] = fmaf(f0, wa, acc[0]); acc[1] = fmaf(f1, wa, acc[1]);
        unpack2(ua.y, f0, f1); acc[2] = fmaf(f0, wa, acc[2]); acc[3] = fmaf(f1, wa, acc[3]);
        unpack2(ua.z, f0, f1); acc[4] = fmaf(f0, wa, acc[4]); acc[5] = fmaf(f1, wa, acc[5]);
        unpack2(ua.w, f0, f1); acc[6] = fmaf(f0, wa, acc[6]); acc[7] = fmaf(f1, wa, acc[7]);
    }
    __shared__ float red[16][8][8];
#pragma unroll
    for (int j = 0; j < 8; j += 4)
        *(float4*)&red[s][l][j] = make_float4(acc[j], acc[j + 1], acc[j + 2], acc[j + 3]);
    __syncthreads();
    if (threadIdx.x < 8) {
        int ll = threadIdx.x;
        float rr[8];
#pragma unroll
        for (int j = 0; j < 8; j++) rr[j] = 0.f;
#pragma unroll
        for (int k = 0; k < 16; ++k)
#pragma unroll
            for (int j = 0; j < 8; j++) rr[j] += red[k][ll][j];
        float dv = dinv[v];
        uint4 uh = *(const uint4*)&h[(size_t)v * 64 + ll * 8];
        float hv[8];
        unpack2(uh.x, hv[0], hv[1]); unpack2(uh.y, hv[2], hv[3]);
        unpack2(uh.z, hv[4], hv[5]); unpack2(uh.w, hv[6], hv[7]);
        float o[8];
#pragma unroll
        for (int j = 0; j < 8; j++) o[j] = dv * (rr[j] + hv[j] * dv) + bias[ll * 8 + j];
        *(float4*)&out[(size_t)v * 64 + ll * 8 + 0] = make_float4(o[0], o[1], o[2], o[3]);
        *(float4*)&out[(size_t)v * 64 + ll * 8 + 4] = make_float4(o[4], o[5], o[6], o[7]);
    }
}

extern "C" void kernel_launch(void* const* d_in, const int* in_sizes, int n_in,
                              void* d_out, int out_size, void* d_ws, size_t ws_size,
                              hipStream_t stream) {
    const float* x  = (const float*)d_in[0];
    const int*   ei = (const int*)d_in[1];
    const float* er = (const float*)d_in[2];
    const float* w0 = (const float*)d_in[3];
    const float* b0 = (const float*)d_in[4];
    const float* w1 = (const float*)d_in[5];
    const float* b1 = (const float*)d_in[6];
    const float* w2 = (const float*)d_in[7];
    const float* b2 = (const float*)d_in[8];
    const int N = in_sizes[0] / 128;
    const int E = in_sizes[2];
    const int* src  = ei;
    const int* dstv = ei + E;
    float* out = (float*)d_out;

    // workspace carve
    char* p = (char*)d_ws;
    auto alloc = [&](size_t bytes) {
        char* r = p;
        p += (bytes + 255) & ~(size_t)255;
        return r;
    };
    int* indeg     = (int*)alloc((size_t)N * 4);
    int* csr_off   = (int*)alloc((size_t)(N + 1) * 4);
    int* bsums     = (int*)alloc(1024);
    int* bcnt      = (int*)alloc((size_t)65536 * 4);
    int* sbase     = (int*)alloc((size_t)65537 * 4);
    int2* csr_se   = (int2*)alloc((size_t)E * 8);
    int2* stg      = (int2*)alloc((size_t)E * 8);   // staging; survive aliases
    float* dinvF   = (float*)alloc((size_t)N * 4);
    float* dinvM   = (float*)alloc((size_t)N * 4);
    float* hx      = (float*)alloc((size_t)N * 128 * 4);
    unsigned short* hxb = (unsigned short*)alloc((size_t)N * 128 * 2);
    float* wk1     = (float*)alloc((size_t)N * 128 * 4);
    float* wk2     = (float*)alloc((size_t)N * 128 * 4);
    float* tz      = (float*)alloc((size_t)N * 64 * 4);
    unsigned short* w0p3 = (unsigned short*)alloc((size_t)3 * 128 * 128 * 2);
    unsigned short* w1p3 = (unsigned short*)alloc((size_t)3 * 128 * 128 * 2);
    unsigned short* w2p3 = (unsigned short*)alloc((size_t)3 * 128 * 64 * 2);
    unsigned short* wk1b = (unsigned short*)wk1;
    unsigned short* wk2b = (unsigned short*)wk2;
    float* survive = (float*)stg;                 // stg dead after k_bfill

    const int nb = (N + 255) / 256;
    const int chunk = (E + 63) / 64;

    // weight packs (single launch)
    k_packw3_all<<<20, 256, 0, stream>>>(w0, w1, w2, w0p3, w1p3, w2p3);

    // ---- bucket-radix CSR build (no global atomics) ----
    k_bcount<<<64, 256, 0, stream>>>(dstv, bcnt, E, chunk);
    k_scan1<<<256, 256, 0, stream>>>(bcnt, sbase, bsums, 65536);
    k_scan2<<<1, 256, 0, stream>>>(bsums, 256);
    k_scan3<<<256, 256, 0, stream>>>(sbase, bsums, 65536, E);
    k_bscatter<<<64, 256, 0, stream>>>(src, dstv, er, sbase, stg, E, chunk);
    k_bindeg<<<1024, 256, 0, stream>>>(stg, sbase, indeg, dinvF, N);
    k_scan1<<<nb, 256, 0, stream>>>(indeg, csr_off, bsums, N);
    k_scan2<<<1, 256, 0, stream>>>(bsums, nb);
    k_scan3<<<nb, 256, 0, stream>>>(csr_off, bsums, N, E);
    k_bfill<<<1024, 256, 0, stream>>>(stg, sbase, csr_off, csr_se, N);

    const int gbm = (N + 63) / 64;

    // shared first GEMM: f32 (pass1) + bf16 copy (pass2)
    k_gemm_split<128, true><<<gbm, 256, 0, stream>>>(x, w0p3, hx, hxb, N);

    // pass 1 (full graph, near-exact -> tz -> mask)
    k_agg128<true><<<N, 128, 0, stream>>>(hx, csr_off, csr_se, dinvF, b0, wk1, N);
    k_gemm_split<128, false><<<gbm, 256, 0, stream>>>(wk1, w1p3, wk2, nullptr, N);
    k_agg128<true><<<N, 128, 0, stream>>>(wk2, csr_off, csr_se, dinvF, b1, wk1, N);
    k_gemm_split<64, false><<<gbm, 256, 0, stream>>>(wk1, w2p3, wk2, nullptr, N);
    k_agg64<<<N, 128, 0, stream>>>(wk2, csr_off, csr_se, dinvF, b2, tz, N);

    // edge sampling in CSR order (writes survive + dinvM)
    k_surv<<<N, 128, 0, stream>>>(tz, csr_off, csr_se, survive, dinvM, N);

    // pass 2 (post-mask: bf16 gathers + bf16 MFMA GEMMs, plane-0 weights)
    k_agg128b<true, true><<<N, 128, 0, stream>>>(hxb, csr_off, csr_se, survive, dinvM, b0, wk1b, N);
    k_gemm_mfma<128><<<gbm, 256, 0, stream>>>(wk1b, w1p3, wk2b, N);
    k_agg128b<true, true><<<N, 128, 0, stream>>>(wk2b, csr_off, csr_se, survive, dinvM, b1, wk1b, N);
    k_gemm_mfma<64><<<gbm, 256, 0, stream>>>(wk1b, w2p3, wk2b, N);
    k_agg64b<<<N, 128, 0, stream>>>(wk2b, csr_off, csr_se, dinvF, b2, out, N);
}

// Round 9
// 462.494 us; speedup vs baseline: 1.3873x; 1.0637x over previous
//
#include <hip/hip_runtime.h>

// ---------------------------------------------------------------------------
// GCN with edge sampling.
//  Pass 1 (-> tz -> mask) uses split-bf16 MFMA GEMMs (3-plane Ozaki split,
//  6 cross terms, error ~2^-26) + exact f32 aggs -> mask bit-stable.
//  Pass 2 (post-mask) is bf16 end-to-end.
//  CSR build: bucket-radix (bucket = dst>>6), LDS atomics only.
//  Aggregations: wave-per-node, no LDS, no barriers (shfl_xor reduction).
// conv: out[v] = dinv[v]*(sum_e h[src]*dinv[src]*m[e] + h[v]*dinv[v]) + b
// ---------------------------------------------------------------------------

typedef __attribute__((ext_vector_type(8))) short bf16x8;
typedef __attribute__((ext_vector_type(4))) float f32x4;

__device__ inline unsigned bfpair(float lo, float hi) {   // pack 2 f32 -> bf16x2 RNE
    unsigned a = __float_as_uint(lo), b = __float_as_uint(hi);
    a = (a + 0x7FFFu + ((a >> 16) & 1u)) >> 16;
    b = (b + 0x7FFFu + ((b >> 16) & 1u)) & 0xFFFF0000u;
    return a | b;
}
__device__ inline unsigned short bf1(float v) {
    unsigned u = __float_as_uint(v);
    return (unsigned short)((u + 0x7FFFu + ((u >> 16) & 1u)) >> 16);
}
__device__ inline void unpack2(unsigned u, float& f0, float& f1) {
    f0 = __uint_as_float(u << 16);
    f1 = __uint_as_float(u & 0xFFFF0000u);
}

// ---------------- scans (generic, 256-wide) ----------------
__global__ void k_scan1(const int* __restrict__ in, int* __restrict__ out,
                        int* __restrict__ bsums, int N) {
    __shared__ int tmp[256];
    int i = blockIdx.x * 256 + threadIdx.x;
    int v = (i < N) ? in[i] : 0;
    tmp[threadIdx.x] = v;
    __syncthreads();
    for (int off = 1; off < 256; off <<= 1) {
        int t = (threadIdx.x >= off) ? tmp[threadIdx.x - off] : 0;
        __syncthreads();
        tmp[threadIdx.x] += t;
        __syncthreads();
    }
    if (i < N) out[i] = tmp[threadIdx.x] - v;   // exclusive
    if (threadIdx.x == 255) bsums[blockIdx.x] = tmp[255];
}

__global__ void k_scan2(int* __restrict__ bsums, int nb) {
    __shared__ int tmp[256];
    int v = (threadIdx.x < nb) ? bsums[threadIdx.x] : 0;
    tmp[threadIdx.x] = v;
    __syncthreads();
    for (int off = 1; off < 256; off <<= 1) {
        int t = (threadIdx.x >= off) ? tmp[threadIdx.x - off] : 0;
        __syncthreads();
        tmp[threadIdx.x] += t;
        __syncthreads();
    }
    if (threadIdx.x < nb) bsums[threadIdx.x] = tmp[threadIdx.x] - v;  // exclusive
}

__global__ void k_scan3(int* __restrict__ out, const int* __restrict__ bsums, int N, int E) {
    int i = blockIdx.x * 256 + threadIdx.x;
    if (i < N) out[i] += bsums[blockIdx.x];
    if (i == 0) out[N] = E;
}

// ---------------- bucket-radix CSR build (no global atomics) ----------------
__global__ __launch_bounds__(256) void k_bcount(const int* __restrict__ dst,
                                                int* __restrict__ cnt, int E, int chunk) {
    __shared__ int h[1024];
    for (int i = threadIdx.x; i < 1024; i += 256) h[i] = 0;
    __syncthreads();
    int beg = blockIdx.x * chunk, end = min(E, beg + chunk);
    for (int e = beg + threadIdx.x; e < end; e += 256)
        atomicAdd(&h[dst[e] >> 6], 1);
    __syncthreads();
    for (int b = threadIdx.x; b < 1024; b += 256)
        cnt[b * 64 + blockIdx.x] = h[b];
}

// staging payload: .x = src | (dst&63)<<16  (src < 65536), .y = er bits
__global__ __launch_bounds__(256) void k_bscatter(const int* __restrict__ src,
                                                  const int* __restrict__ dst,
                                                  const float* __restrict__ er,
                                                  const int* __restrict__ sbase,
                                                  int2* __restrict__ stg, int E, int chunk) {
    __shared__ int cur[1024];
    for (int i = threadIdx.x; i < 1024; i += 256) cur[i] = 0;
    __syncthreads();
    int beg = blockIdx.x * chunk, end = min(E, beg + chunk);
    for (int e = beg + threadIdx.x; e < end; e += 256) {
        int d = dst[e];
        int b = d >> 6;
        int loc = atomicAdd(&cur[b], 1);
        int pos = sbase[b * 64 + blockIdx.x] + loc;
        stg[pos] = make_int2(src[e] | ((d & 63) << 16), (int)__float_as_uint(er[e]));
    }
}

// per-bucket indeg + dinvF (k_dinv folded in)
__global__ __launch_bounds__(256) void k_bindeg(const int2* __restrict__ stg,
                                                const int* __restrict__ sbase,
                                                int* __restrict__ indeg,
                                                float* __restrict__ dinvF, int N) {
    __shared__ int cnt[64];
    if (threadIdx.x < 64) cnt[threadIdx.x] = 0;
    __syncthreads();
    int b = blockIdx.x;
    int beg = sbase[b * 64], end = sbase[(b + 1) * 64];
    for (int i = beg + threadIdx.x; i < end; i += 256)
        atomicAdd(&cnt[(stg[i].x >> 16) & 63], 1);
    __syncthreads();
    if (threadIdx.x < 64) {
        int node = b * 64 + threadIdx.x;
        if (node < N) {
            int c = cnt[threadIdx.x];
            indeg[node] = c;
            dinvF[node] = 1.0f / sqrtf((float)c + 1.0f);
        }
    }
}

// bucket owns its 64 dst nodes exclusively -> LDS cursors give unique slots.
__global__ __launch_bounds__(256) void k_bfill(const int2* __restrict__ stg,
                                               const int* __restrict__ sbase,
                                               const int* __restrict__ csr_off,
                                               int2* __restrict__ csr_se, int N) {
    __shared__ int cur[64];
    int b = blockIdx.x;
    if (threadIdx.x < 64) {
        int node = b * 64 + threadIdx.x;
        cur[threadIdx.x] = (node < N) ? csr_off[node] : 0;
    }
    __syncthreads();
    int beg = sbase[b * 64], end = sbase[(b + 1) * 64];
    for (int i = beg + threadIdx.x; i < end; i += 256) {
        int2 se = stg[i];
        int j = (se.x >> 16) & 63;
        int pos = atomicAdd(&cur[j], 1);
        csr_se[pos] = make_int2(se.x & 0xFFFF, se.y);
    }
}

// mask in CSR order: block per node; also writes dinvM (k_dinv folded in).
__global__ __launch_bounds__(128) void k_surv(const float* __restrict__ tz,
                                              const int* __restrict__ csr_off,
                                              const int2* __restrict__ csr_se,
                                              float* __restrict__ survive,
                                              float* __restrict__ dinvM, int N) {
    const int v = blockIdx.x;
    const int l = threadIdx.x & 15;
    const int s = threadIdx.x >> 4;
    const int e0 = csr_off[v];
    const int e1 = csr_off[v + 1];
    const float4 tv = *(const float4*)&tz[(size_t)v * 64 + l * 4];
    int cnt = 0;
    for (int i = e0 + s; i < e1; i += 8) {
        int2 se = csr_se[i];
        const float4 a = *(const float4*)&tz[(size_t)se.x * 64 + l * 4];
        float p = a.x * tv.x + a.y * tv.y + a.z * tv.z + a.w * tv.w;
        p += __shfl_xor(p, 1, 16);
        p += __shfl_xor(p, 2, 16);
        p += __shfl_xor(p, 4, 16);
        p += __shfl_xor(p, 8, 16);
        float sg = 1.0f / (1.0f + expf(-p));
        float m = (sg > __uint_as_float((unsigned)se.y)) ? 1.0f : 0.0f;
        if (l == 0) {
            survive[i] = m;
            cnt += (m != 0.0f) ? 1 : 0;
        }
    }
    __shared__ int sc[8];
    if (l == 0) sc[s] = cnt;
    __syncthreads();
    if (threadIdx.x == 0) {
        int t = 0;
#pragma unroll
        for (int k = 0; k < 8; k++) t += sc[k];
        dinvM[v] = 1.0f / sqrtf((float)t + 1.0f);
    }
}

// pack W -> 3 bf16 split planes (plane 0 = bf16(W), reused by pass-2 GEMMs)
__device__ inline void packw3_one(const float* __restrict__ W, unsigned short* __restrict__ Wp,
                                  int OUTC, int idx) {
    int l = idx & 63;
    int tk = idx >> 6;
    int kb = tk & 3;
    int ct = tk >> 2;
    size_t PL = (size_t)(OUTC / 16) * 4 * 64 * 8;
    unsigned short v0[8], v1[8], v2[8];
#pragma unroll
    for (int i = 0; i < 8; i++) {
        float wv = W[(kb * 32 + ((l >> 4) * 8) + i) * OUTC + ct * 16 + (l & 15)];
        unsigned short h0 = bf1(wv);
        float f0 = __uint_as_float((unsigned)h0 << 16);
        float r1 = wv - f0;
        unsigned short h1 = bf1(r1);
        float f1 = __uint_as_float((unsigned)h1 << 16);
        unsigned short h2 = bf1(r1 - f1);
        v0[i] = h0; v1[i] = h1; v2[i] = h2;
    }
    auto st = [](unsigned short* dst, unsigned short* v) {
        uint4 u;
        u.x = v[0] | ((unsigned)v[1] << 16);
        u.y = v[2] | ((unsigned)v[3] << 16);
        u.z = v[4] | ((unsigned)v[5] << 16);
        u.w = v[6] | ((unsigned)v[7] << 16);
        *(uint4*)dst = u;
    };
    st(&Wp[(size_t)idx * 8], v0);
    st(&Wp[PL + (size_t)idx * 8], v1);
    st(&Wp[2 * PL + (size_t)idx * 8], v2);
}

__global__ void k_packw3_all(const float* __restrict__ w0, const float* __restrict__ w1,
                             const float* __restrict__ w2,
                             unsigned short* __restrict__ w0p, unsigned short* __restrict__ w1p,
                             unsigned short* __restrict__ w2p) {
    int b = blockIdx.x;
    if (b < 8) packw3_one(w0, w0p, 128, b * 256 + threadIdx.x);
    else if (b < 16) packw3_one(w1, w1p, 128, (b - 8) * 256 + threadIdx.x);
    else packw3_one(w2, w2p, 64, (b - 16) * 256 + threadIdx.x);
}

// split-bf16 MFMA GEMM (pass 1): 6 cross terms (00,10,20 | 01,11,02),
// error ~2^-26. f32 out (+ optional bf16 copy).
template <int OUTC, bool WB16>
__global__ __launch_bounds__(256) void k_gemm_split(const float* __restrict__ A,
                                                    const unsigned short* __restrict__ Wp,
                                                    float* __restrict__ Cout,
                                                    unsigned short* __restrict__ Cb, int N) {
    constexpr int CT = OUTC / 16;
    constexpr int PL = CT * 4 * 64 * 8;
    constexpr int LDW = OUTC + 4;
    __shared__ float eps[64 * LDW];
    const int w = threadIdx.x >> 6;
    const int l = threadIdx.x & 63;
    int row = blockIdx.x * 64 + w * 16 + (l & 15);
    int rowc = (row < N) ? row : (N - 1);

    bf16x8 a0[4], a1[4], a2[4];
#pragma unroll
    for (int kb = 0; kb < 4; kb++) {
        const float* pa = &A[(size_t)rowc * 128 + kb * 32 + ((l >> 4) * 8)];
        float4 x0 = *(const float4*)pa;
        float4 x1 = *(const float4*)(pa + 4);
        float xa[8] = {x0.x, x0.y, x0.z, x0.w, x1.x, x1.y, x1.z, x1.w};
#pragma unroll
        for (int i = 0; i < 8; i++) {
            unsigned short h0 = bf1(xa[i]);
            float f0 = __uint_as_float((unsigned)h0 << 16);
            float r1 = xa[i] - f0;
            unsigned short h1 = bf1(r1);
            float f1 = __uint_as_float((unsigned)h1 << 16);
            unsigned short h2 = bf1(r1 - f1);
            a0[kb][i] = (short)h0;
            a1[kb][i] = (short)h1;
            a2[kb][i] = (short)h2;
        }
    }
#pragma unroll
    for (int ct = 0; ct < CT; ct++) {
        f32x4 accA = {0.f, 0.f, 0.f, 0.f};
        f32x4 accB = {0.f, 0.f, 0.f, 0.f};
#pragma unroll
        for (int kb = 0; kb < 4; kb++) {
            const size_t bo = ((size_t)(ct * 4 + kb) * 64 + l) * 8;
            bf16x8 b0 = *(const bf16x8*)&Wp[bo];
            bf16x8 b1 = *(const bf16x8*)&Wp[PL + bo];
            bf16x8 b2 = *(const bf16x8*)&Wp[2 * PL + bo];
            accA = __builtin_amdgcn_mfma_f32_16x16x32_bf16(a0[kb], b0, accA, 0, 0, 0);
            accB = __builtin_amdgcn_mfma_f32_16x16x32_bf16(a0[kb], b1, accB, 0, 0, 0);
            accA = __builtin_amdgcn_mfma_f32_16x16x32_bf16(a1[kb], b0, accA, 0, 0, 0);
            accB = __builtin_amdgcn_mfma_f32_16x16x32_bf16(a1[kb], b1, accB, 0, 0, 0);
            accA = __builtin_amdgcn_mfma_f32_16x16x32_bf16(a2[kb], b0, accA, 0, 0, 0);
            accB = __builtin_amdgcn_mfma_f32_16x16x32_bf16(a0[kb], b2, accB, 0, 0, 0);
        }
        // C/D map: col = lane&15, row = (lane>>4)*4 + r  [HW-verified]
#pragma unroll
        for (int r = 0; r < 4; r++) {
            int rr = w * 16 + (l >> 4) * 4 + r;
            eps[rr * LDW + ct * 16 + (l & 15)] = accA[r] + accB[r];
        }
    }
    __syncthreads();
    constexpr int NF4 = 64 * OUTC / 4;
    for (int idx = threadIdx.x; idx < NF4; idx += 256) {
        int rl = idx / (OUTC / 4);
        int cg = idx % (OUTC / 4);
        int grow = blockIdx.x * 64 + rl;
        if (grow < N) {
            const float* sp = &eps[rl * LDW + cg * 4];
            float4 vv = make_float4(sp[0], sp[1], sp[2], sp[3]);
            *(float4*)&Cout[(size_t)grow * OUTC + cg * 4] = vv;
            if (WB16)
                *(uint2*)&Cb[(size_t)grow * OUTC + cg * 4] =
                    make_uint2(bfpair(vv.x, vv.y), bfpair(vv.z, vv.w));
        }
    }
}

// plain bf16 MFMA GEMM (pass 2): A bf16, Wpk = plane 0 of packw3, bf16 out.
template <int OUTC>
__global__ __launch_bounds__(256) void k_gemm_mfma(const unsigned short* __restrict__ A,
                                                   const unsigned short* __restrict__ Wpk,
                                                   unsigned short* __restrict__ C, int N) {
    constexpr int CT = OUTC / 16;
    __shared__ unsigned short eps[64 * OUTC];
    const int w = threadIdx.x >> 6;
    const int l = threadIdx.x & 63;
    const int rowl = (w * 16) + (l & 15);
    int row = blockIdx.x * 64 + rowl;
    int rowc = (row < N) ? row : (N - 1);

    bf16x8 a[4];
#pragma unroll
    for (int kb = 0; kb < 4; kb++)
        a[kb] = *(const bf16x8*)&A[(size_t)rowc * 128 + kb * 32 + ((l >> 4) * 8)];

#pragma unroll
    for (int ct = 0; ct < CT; ct++) {
        f32x4 acc = {0.f, 0.f, 0.f, 0.f};
#pragma unroll
        for (int kb = 0; kb < 4; kb++) {
            bf16x8 b = *(const bf16x8*)&Wpk[((size_t)(ct * 4 + kb) * 64 + l) * 8];
            acc = __builtin_amdgcn_mfma_f32_16x16x32_bf16(a[kb], b, acc, 0, 0, 0);
        }
#pragma unroll
        for (int r = 0; r < 4; r++) {
            int rr = w * 16 + (l >> 4) * 4 + r;
            eps[rr * OUTC + ct * 16 + (l & 15)] = bf1(acc[r]);
        }
    }
    __syncthreads();
    constexpr int NU4 = 64 * OUTC / 8;
    for (int idx = threadIdx.x; idx < NU4; idx += 256) {
        int rl = idx / (OUTC / 8);
        int cg = idx % (OUTC / 8);
        int grow = blockIdx.x * 64 + rl;
        if (grow < N)
            *(uint4*)&C[(size_t)grow * OUTC + cg * 8] = *(const uint4*)&eps[rl * OUTC + cg * 8];
    }
}

// -------- fp32 aggregations (pass 1, mask-critical), wave-per-node ---------
// block = 256 thr = 4 waves; wave handles node v; 32 lanes x float4 = row,
// 2 edge slots; shfl_xor(32) reduction; no LDS, no barriers.
template <bool RELU>
__global__ __launch_bounds__(256) void k_agg128(const float* __restrict__ h,
                                                const int* __restrict__ csr_off,
                                                const int2* __restrict__ csr_se,
                                                const float* __restrict__ dinv,
                                                const float* __restrict__ bias,
                                                float* __restrict__ out, int N) {
    const int v = blockIdx.x * 4 + (threadIdx.x >> 6);
    if (v >= N) return;
    const int lane = threadIdx.x & 63;
    const int l = lane & 31;        // feature float4 group
    const int s = lane >> 5;        // 0..1 edge slot
    const int e0 = csr_off[v];
    const int e1 = csr_off[v + 1];
    float4 acc = make_float4(0.f, 0.f, 0.f, 0.f);
    int i = e0 + s;
    for (; i + 2 < e1; i += 4) {
        int sa = csr_se[i].x;      float wa = dinv[sa];
        int sb = csr_se[i + 2].x;  float wb = dinv[sb];
        float4 a = *(const float4*)&h[(size_t)sa * 128 + l * 4];
        float4 b = *(const float4*)&h[(size_t)sb * 128 + l * 4];
        acc.x = fmaf(a.x, wa, acc.x); acc.y = fmaf(a.y, wa, acc.y);
        acc.z = fmaf(a.z, wa, acc.z); acc.w = fmaf(a.w, wa, acc.w);
        acc.x = fmaf(b.x, wb, acc.x); acc.y = fmaf(b.y, wb, acc.y);
        acc.z = fmaf(b.z, wb, acc.z); acc.w = fmaf(b.w, wb, acc.w);
    }
    if (i < e1) {
        int sa = csr_se[i].x;
        float wa = dinv[sa];
        float4 a = *(const float4*)&h[(size_t)sa * 128 + l * 4];
        acc.x = fmaf(a.x, wa, acc.x); acc.y = fmaf(a.y, wa, acc.y);
        acc.z = fmaf(a.z, wa, acc.z); acc.w = fmaf(a.w, wa, acc.w);
    }
    acc.x += __shfl_xor(acc.x, 32);
    acc.y += __shfl_xor(acc.y, 32);
    acc.z += __shfl_xor(acc.z, 32);
    acc.w += __shfl_xor(acc.w, 32);
    if (s == 0) {
        float dv = dinv[v];
        float4 hv = *(const float4*)&h[(size_t)v * 128 + l * 4];
        float4 bb = *(const float4*)&bias[l * 4];
        float4 o;
        o.x = dv * (acc.x + hv.x * dv) + bb.x;
        o.y = dv * (acc.y + hv.y * dv) + bb.y;
        o.z = dv * (acc.z + hv.z * dv) + bb.z;
        o.w = dv * (acc.w + hv.w * dv) + bb.w;
        if (RELU) {
            o.x = fmaxf(o.x, 0.f); o.y = fmaxf(o.y, 0.f);
            o.z = fmaxf(o.z, 0.f); o.w = fmaxf(o.w, 0.f);
        }
        *(float4*)&out[(size_t)v * 128 + l * 4] = o;
    }
}

// 64-feat f32: 16 lanes x float4 = row, 4 slots; xor32+xor16 reduction.
__global__ __launch_bounds__(256) void k_agg64(const float* __restrict__ h,
                                               const int* __restrict__ csr_off,
                                               const int2* __restrict__ csr_se,
                                               const float* __restrict__ dinv,
                                               const float* __restrict__ bias,
                                               float* __restrict__ out, int N) {
    const int v = blockIdx.x * 4 + (threadIdx.x >> 6);
    if (v >= N) return;
    const int lane = threadIdx.x & 63;
    const int l = lane & 15;
    const int s = lane >> 4;        // 0..3
    const int e0 = csr_off[v];
    const int e1 = csr_off[v + 1];
    float4 acc = make_float4(0.f, 0.f, 0.f, 0.f);
    int i = e0 + s;
    for (; i + 4 < e1; i += 8) {
        int sa = csr_se[i].x;      float wa = dinv[sa];
        int sb = csr_se[i + 4].x;  float wb = dinv[sb];
        float4 a = *(const float4*)&h[(size_t)sa * 64 + l * 4];
        float4 b = *(const float4*)&h[(size_t)sb * 64 + l * 4];
        acc.x = fmaf(a.x, wa, acc.x); acc.y = fmaf(a.y, wa, acc.y);
        acc.z = fmaf(a.z, wa, acc.z); acc.w = fmaf(a.w, wa, acc.w);
        acc.x = fmaf(b.x, wb, acc.x); acc.y = fmaf(b.y, wb, acc.y);
        acc.z = fmaf(b.z, wb, acc.z); acc.w = fmaf(b.w, wb, acc.w);
    }
    if (i < e1) {
        int sa = csr_se[i].x;
        float wa = dinv[sa];
        float4 a = *(const float4*)&h[(size_t)sa * 64 + l * 4];
        acc.x = fmaf(a.x, wa, acc.x); acc.y = fmaf(a.y, wa, acc.y);
        acc.z = fmaf(a.z, wa, acc.z); acc.w = fmaf(a.w, wa, acc.w);
    }
    acc.x += __shfl_xor(acc.x, 32); acc.y += __shfl_xor(acc.y, 32);
    acc.z += __shfl_xor(acc.z, 32); acc.w += __shfl_xor(acc.w, 32);
    acc.x += __shfl_xor(acc.x, 16); acc.y += __shfl_xor(acc.y, 16);
    acc.z += __shfl_xor(acc.z, 16); acc.w += __shfl_xor(acc.w, 16);
    if (s == 0) {
        float dv = dinv[v];
        float4 hv = *(const float4*)&h[(size_t)v * 64 + l * 4];
        float4 bb = *(const float4*)&bias[l * 4];
        float4 o;
        o.x = dv * (acc.x + hv.x * dv) + bb.x;
        o.y = dv * (acc.y + hv.y * dv) + bb.y;
        o.z = dv * (acc.z + hv.z * dv) + bb.z;
        o.w = dv * (acc.w + hv.w * dv) + bb.w;
        *(float4*)&out[(size_t)v * 64 + l * 4] = o;
    }
}

// ----- bf16-gather aggregations (pass 2, post-mask), wave-per-node ---------
// 16 lanes x uint4 (8 bf16) = row, 4 slots; xor32+xor16; bf16 out.
template <bool RELU>
__global__ __launch_bounds__(256) void k_agg128b(const unsigned short* __restrict__ h,
                                                 const int* __restrict__ csr_off,
                                                 const int2* __restrict__ csr_se,
                                                 const float* __restrict__ survive,
                                                 const float* __restrict__ dinv,
                                                 const float* __restrict__ bias,
                                                 unsigned short* __restrict__ out, int N) {
    const int v = blockIdx.x * 4 + (threadIdx.x >> 6);
    if (v >= N) return;
    const int lane = threadIdx.x & 63;
    const int l = lane & 15;        // 8-feature group
    const int s = lane >> 4;        // 0..3 edge slot
    const int e0 = csr_off[v];
    const int e1 = csr_off[v + 1];
    float acc[8];
#pragma unroll
    for (int j = 0; j < 8; j++) acc[j] = 0.f;
    int i = e0 + s;
    for (; i + 4 < e1; i += 8) {
        int sa = csr_se[i].x;
        int sb = csr_se[i + 4].x;
        float wa = dinv[sa] * survive[i];
        float wb = dinv[sb] * survive[i + 4];
        uint4 ua = *(const uint4*)&h[(size_t)sa * 128 + l * 8];
        uint4 ub = *(const uint4*)&h[(size_t)sb * 128 + l * 8];
        float f0, f1;
        unpack2(ua.x, f0, f1); acc[0] = fmaf(f0, wa, acc[0]); acc[1] = fmaf(f1, wa, acc[1]);
        unpack2(ua.y, f0, f1); acc[2] = fmaf(f0, wa, acc[2]); acc[3] = fmaf(f1, wa, acc[3]);
        unpack2(ua.z, f0, f1); acc[4] = fmaf(f0, wa, acc[4]); acc[5] = fmaf(f1, wa, acc[5]);
        unpack2(ua.w, f0, f1); acc[6] = fmaf(f0, wa, acc[6]); acc[7] = fmaf(f1, wa, acc[7]);
        unpack2(ub.x, f0, f1); acc[0] = fmaf(f0, wb, acc[0]); acc[1] = fmaf(f1, wb, acc[1]);
        unpack2(ub.y, f0, f1); acc[2] = fmaf(f0, wb, acc[2]); acc[3] = fmaf(f1, wb, acc[3]);
        unpack2(ub.z, f0, f1); acc[4] = fmaf(f0, wb, acc[4]); acc[5] = fmaf(f1, wb, acc[5]);
        unpack2(ub.w, f0, f1); acc[6] = fmaf(f0, wb, acc[6]); acc[7] = fmaf(f1, wb, acc[7]);
    }
    if (i < e1) {
        int sa = csr_se[i].x;
        float wa = dinv[sa] * survive[i];
        uint4 ua = *(const uint4*)&h[(size_t)sa * 128 + l * 8];
        float f0, f1;
        unpack2(ua.x, f0, f1); acc[0] = fmaf(f0, wa, acc[0]); acc[1] = fmaf(f1, wa, acc[1]);
        unpack2(ua.y, f0, f1); acc[2] = fmaf(f0, wa, acc[2]); acc[3] = fmaf(f1, wa, acc[3]);
        unpack2(ua.z, f0, f1); acc[4] = fmaf(f0, wa, acc[4]); acc[5] = fmaf(f1, wa, acc[5]);
        unpack2(ua.w, f0, f1); acc[6] = fmaf(f0, wa, acc[6]); acc[7] = fmaf(f1, wa, acc[7]);
    }
#pragma unroll
    for (int j = 0; j < 8; j++) acc[j] += __shfl_xor(acc[j], 32);
#pragma unroll
    for (int j = 0; j < 8; j++) acc[j] += __shfl_xor(acc[j], 16);
    if (s == 0) {
        float dv = dinv[v];
        uint4 uh = *(const uint4*)&h[(size_t)v * 128 + l * 8];
        float hv[8];
        unpack2(uh.x, hv[0], hv[1]); unpack2(uh.y, hv[2], hv[3]);
        unpack2(uh.z, hv[4], hv[5]); unpack2(uh.w, hv[6], hv[7]);
        unsigned u[4];
#pragma unroll
        for (int j2 = 0; j2 < 4; j2++) {
            float o0 = dv * (acc[2 * j2 + 0] + hv[2 * j2 + 0] * dv) + bias[l * 8 + 2 * j2 + 0];
            float o1 = dv * (acc[2 * j2 + 1] + hv[2 * j2 + 1] * dv) + bias[l * 8 + 2 * j2 + 1];
            if (RELU) { o0 = fmaxf(o0, 0.f); o1 = fmaxf(o1, 0.f); }
            u[j2] = bfpair(o0, o1);
        }
        *(uint4*)&out[(size_t)v * 128 + l * 8] = make_uint4(u[0], u[1], u[2], u[3]);
    }
}

// final layer: full edges, coef = dinvF[src], f32 out; 8 lanes x uint4, 8 slots.
__global__ __launch_bounds__(256) void k_agg64b(const unsigned short* __restrict__ h,
                                                const int* __restrict__ csr_off,
                                                const int2* __restrict__ csr_se,
                                                const float* __restrict__ dinv,
                                                const float* __restrict__ bias,
                                                float* __restrict__ out, int N) {
    const int v = blockIdx.x * 4 + (threadIdx.x >> 6);
    if (v >= N) return;
    const int lane = threadIdx.x & 63;
    const int l = lane & 7;         // 8-feature group
    const int s = lane >> 3;        // 0..7 edge slot
    const int e0 = csr_off[v];
    const int e1 = csr_off[v + 1];
    float acc[8];
#pragma unroll
    for (int j = 0; j < 8; j++) acc[j] = 0.f;
    for (int i = e0 + s; i < e1; i += 8) {
        int sa = csr_se[i].x;
        float wa = dinv[sa];
        uint4 ua = *(const uint4*)&h[(size_t)sa * 64 + l * 8];
        float f0, f1;
        unpack2(ua.x, f0, f1); acc[0] = fmaf(f0, wa, acc[0]); acc[1] = fmaf(f1, wa, acc[1]);
        unpack2(ua.y, f0, f1); acc[2] = fmaf(f0, wa, acc[2]); acc[3] = fmaf(f1, wa, acc[3]);
        unpack2(ua.z, f0, f1); acc[4] = fmaf(f0, wa, acc[4]); acc[5] = fmaf(f1, wa, acc[5]);
        unpack2(ua.w, f0, f1); acc[6] = fmaf(f0, wa, acc[6]); acc[7] = fmaf(f1, wa, acc[7]);
    }
#pragma unroll
    for (int j = 0; j < 8; j++) acc[j] += __shfl_xor(acc[j], 32);
#pragma unroll
    for (int j = 0; j < 8; j++) acc[j] += __shfl_xor(acc[j], 16);
#pragma unroll
    for (int j = 0; j < 8; j++) acc[j] += __shfl_xor(acc[j], 8);
    if (s == 0) {
        float dv = dinv[v];
        uint4 uh = *(const uint4*)&h[(size_t)v * 64 + l * 8];
        float hv[8];
        unpack2(uh.x, hv[0], hv[1]); unpack2(uh.y, hv[2], hv[3]);
        unpack2(uh.z, hv[4], hv[5]); unpack2(uh.w, hv[6], hv[7]);
        float o[8];
#pragma unroll
        for (int j = 0; j < 8; j++) o[j] = dv * (acc[j] + hv[j] * dv) + bias[l * 8 + j];
        *(float4*)&out[(size_t)v * 64 + l * 8 + 0] = make_float4(o[0], o[1], o[2], o[3]);
        *(float4*)&out[(size_t)v * 64 + l * 8 + 4] = make_float4(o[4], o[5], o[6], o[7]);
    }
}

extern "C" void kernel_launch(void* const* d_in, const int* in_sizes, int n_in,
                              void* d_out, int out_size, void* d_ws, size_t ws_size,
                              hipStream_t stream) {
    const float* x  = (const float*)d_in[0];
    const int*   ei = (const int*)d_in[1];
    const float* er = (const float*)d_in[2];
    const float* w0 = (const float*)d_in[3];
    const float* b0 = (const float*)d_in[4];
    const float* w1 = (const float*)d_in[5];
    const float* b1 = (const float*)d_in[6];
    const float* w2 = (const float*)d_in[7];
    const float* b2 = (const float*)d_in[8];
    const int N = in_sizes[0] / 128;
    const int E = in_sizes[2];
    const int* src  = ei;
    const int* dstv = ei + E;
    float* out = (float*)d_out;

    // workspace carve
    char* p = (char*)d_ws;
    auto alloc = [&](size_t bytes) {
        char* r = p;
        p += (bytes + 255) & ~(size_t)255;
        return r;
    };
    int* indeg     = (int*)alloc((size_t)N * 4);
    int* csr_off   = (int*)alloc((size_t)(N + 1) * 4);
    int* bsums     = (int*)alloc(1024);
    int* bcnt      = (int*)alloc((size_t)65536 * 4);
    int* sbase     = (int*)alloc((size_t)65537 * 4);
    int2* csr_se   = (int2*)alloc((size_t)E * 8);
    int2* stg      = (int2*)alloc((size_t)E * 8);   // staging; survive aliases
    float* dinvF   = (float*)alloc((size_t)N * 4);
    float* dinvM   = (float*)alloc((size_t)N * 4);
    float* hx      = (float*)alloc((size_t)N * 128 * 4);
    unsigned short* hxb = (unsigned short*)alloc((size_t)N * 128 * 2);
    float* wk1     = (float*)alloc((size_t)N * 128 * 4);
    float* wk2     = (float*)alloc((size_t)N * 128 * 4);
    float* tz      = (float*)alloc((size_t)N * 64 * 4);
    unsigned short* w0p3 = (unsigned short*)alloc((size_t)3 * 128 * 128 * 2);
    unsigned short* w1p3 = (unsigned short*)alloc((size_t)3 * 128 * 128 * 2);
    unsigned short* w2p3 = (unsigned short*)alloc((size_t)3 * 128 * 64 * 2);
    unsigned short* wk1b = (unsigned short*)wk1;
    unsigned short* wk2b = (unsigned short*)wk2;
    float* survive = (float*)stg;                 // stg dead after k_bfill

    const int nb = (N + 255) / 256;
    const int chunk = (E + 63) / 64;

    // weight packs (single launch)
    k_packw3_all<<<20, 256, 0, stream>>>(w0, w1, w2, w0p3, w1p3, w2p3);

    // ---- bucket-radix CSR build (no global atomics) ----
    k_bcount<<<64, 256, 0, stream>>>(dstv, bcnt, E, chunk);
    k_scan1<<<256, 256, 0, stream>>>(bcnt, sbase, bsums, 65536);
    k_scan2<<<1, 256, 0, stream>>>(bsums, 256);
    k_scan3<<<256, 256, 0, stream>>>(sbase, bsums, 65536, E);
    k_bscatter<<<64, 256, 0, stream>>>(src, dstv, er, sbase, stg, E, chunk);
    k_bindeg<<<1024, 256, 0, stream>>>(stg, sbase, indeg, dinvF, N);
    k_scan1<<<nb, 256, 0, stream>>>(indeg, csr_off, bsums, N);
    k_scan2<<<1, 256, 0, stream>>>(bsums, nb);
    k_scan3<<<nb, 256, 0, stream>>>(csr_off, bsums, N, E);
    k_bfill<<<1024, 256, 0, stream>>>(stg, sbase, csr_off, csr_se, N);

    const int gbm = (N + 63) / 64;
    const int ga = (N + 3) / 4;

    // shared first GEMM: f32 (pass1) + bf16 copy (pass2)
    k_gemm_split<128, true><<<gbm, 256, 0, stream>>>(x, w0p3, hx, hxb, N);

    // pass 1 (full graph, near-exact -> tz -> mask)
    k_agg128<true><<<ga, 256, 0, stream>>>(hx, csr_off, csr_se, dinvF, b0, wk1, N);
    k_gemm_split<128, false><<<gbm, 256, 0, stream>>>(wk1, w1p3, wk2, nullptr, N);
    k_agg128<true><<<ga, 256, 0, stream>>>(wk2, csr_off, csr_se, dinvF, b1, wk1, N);
    k_gemm_split<64, false><<<gbm, 256, 0, stream>>>(wk1, w2p3, wk2, nullptr, N);
    k_agg64<<<ga, 256, 0, stream>>>(wk2, csr_off, csr_se, dinvF, b2, tz, N);

    // edge sampling in CSR order (writes survive + dinvM)
    k_surv<<<N, 128, 0, stream>>>(tz, csr_off, csr_se, survive, dinvM, N);

    // pass 2 (post-mask: bf16 gathers + bf16 MFMA GEMMs, plane-0 weights)
    k_agg128b<true><<<ga, 256, 0, stream>>>(hxb, csr_off, csr_se, survive, dinvM, b0, wk1b, N);
    k_gemm_mfma<128><<<gbm, 256, 0, stream>>>(wk1b, w1p3, wk2b, N);
    k_agg128b<true><<<ga, 256, 0, stream>>>(wk2b, csr_off, csr_se, survive, dinvM, b1, wk1b, N);
    k_gemm_mfma<64><<<gbm, 256, 0, stream>>>(wk1b, w2p3, wk2b, N);
    k_agg64b<<<ga, 256, 0, stream>>>(wk2b, csr_off, csr_se, dinvF, b2, out, N);
}